// Round 1
// baseline (1370.224 us; speedup 1.0000x reference)
//
#include <hip/hip_runtime.h>
#include <math.h>

#define NBATCH 8
#define LMAX   215
#define NND    36
#define NE     1296
#define NK     648
#define CW     860      // C = LMAX*4
#define DPE    16
#define DTR    160
#define NHEADS 4
#define DH     40
#define NHID2  256
#define SORTN  2048

// output layout (floats)
#define OUT_TYPE (NBATCH*LMAX*DTR)              // 275200
#define OUT_TIME (OUT_TYPE + NBATCH*LMAX*NND)   // 337120
#define OUT_DIST (OUT_TIME + NBATCH*LMAX)       // 338840

// workspace layout (float offsets)
#define OFF_PE    0
#define OFF_RR    (OFF_PE + NBATCH*LMAX*DPE)
#define OFF_EW    (OFF_RR + 144)
#define OFF_BETA  (OFF_EW + NE)
#define OFF_MEANB (OFF_BETA + NBATCH*NND*LMAX)
#define OFF_ALPHA (OFF_MEANB + NBATCH*NND)
#define OFF_H1    (OFF_ALPHA + NBATCH*NK)
#define OFF_H2    (OFF_H1 + NBATCH*NND*CW)
#define OFF_X     (OFF_H2 + NBATCH*NND*CW)
#define OFF_X2    (OFF_X + NBATCH*LMAX*DTR)
#define OFF_QKV   (OFF_X2 + NBATCH*LMAX*DTR)
#define OFF_CTX   (OFF_QKV + NBATCH*LMAX*480)
#define OFF_PROJ  (OFF_CTX + NBATCH*LMAX*DTR)
#define OFF_FF1   (OFF_PROJ + NBATCH*LMAX*DTR)
#define OFF_FF2   (OFF_FF1 + NBATCH*LMAX*NHID2)
#define OFF_TOPI  (OFF_FF2 + NBATCH*LMAX*DTR)
#define OFF_IDX   (OFF_TOPI + NBATCH*NK)
#define OFF_LENS  (OFF_IDX + NBATCH*LMAX)

// ---------------------------------------------------------------- prep
__global__ void k_prep(const int* __restrict__ et, const float* __restrict__ etime,
                       const float* __restrict__ Ru, const float* __restrict__ gs,
                       float* pe, float* rr, float* ew, int* idxarr, int* lens) {
    int tid = threadIdx.x;  // 256
    __shared__ float sts[8];
    if (tid < 8) sts[tid] = (float)pow(215.0, (double)tid / 7.0);
    for (int c = tid; c < 144; c += 256) rr[c] = fmaxf(Ru[c], 0.f);
    for (int e = tid; e < NE; e += 256) {
        int r = e / NND, cc = e % NND;
        ew[e] = (r == cc) ? 1.0f : gs[e];
    }
    if (tid < NBATCH) {
        int cnt = 0;
        for (int l = 0; l < LMAX; ++l) {
            int v = et[tid * LMAX + l];
            cnt += (v != 0);
            idxarr[tid * LMAX + l] = max(v - 1, 0);
        }
        lens[tid] = cnt;
    }
    __syncthreads();
    for (int i = tid; i < NBATCH * LMAX * DPE; i += 256) {
        int s = i & 15; int bl = i >> 4;
        float t = etime[bl];  // bl == b*LMAX+l
        float sc = t / sts[s & 7];
        pe[i] = (s < 8) ? sinf(sc) : cosf(sc);
    }
}

// ---------------------------------------------------------------- beta
// beta[b,n,t] = (1/32)[ sum_{s<16} mapw[n,s]*hWd(32t+s) + sum_{s<16} pe[b,t,s]*hWd(32t+16+s) ]
// hWd(j) = binc[j] + sum_{l: idx[b,l]==n} dot(rr4[n], Winc[j, 4l:4l+4])
__global__ void k_beta(const float* __restrict__ Winc, const float* __restrict__ binc,
                       const float* __restrict__ mapw, const float* __restrict__ pe,
                       const float* __restrict__ rr, const int* __restrict__ idxarr,
                       float* beta, float* meanb) {
    int b = blockIdx.x / NND, n = blockIdx.x % NND;
    int t = threadIdx.x;  // 256
    __shared__ float s_mw[16];
    __shared__ float s_rr[4];
    __shared__ int s_idx[LMAX];
    __shared__ float s_red[256];
    if (t < 16) s_mw[t] = mapw[n * 16 + t];
    if (t < 4) s_rr[t] = rr[n * 4 + t];
    for (int l = t; l < LMAX; l += 256) s_idx[l] = idxarr[b * LMAX + l];
    __syncthreads();
    float val = 0.f;
    if (t < LMAX) {
        float pev[16];
        const float* pr = pe + (b * LMAX + t) * DPE;
#pragma unroll
        for (int s = 0; s < 16; ++s) pev[s] = pr[s];
        float acc = 0.f;
        const float* bi = binc + 32 * t;
#pragma unroll
        for (int s = 0; s < 16; ++s) acc += s_mw[s] * bi[s] + pev[s] * bi[16 + s];
        float r0 = s_rr[0], r1 = s_rr[1], r2 = s_rr[2], r3 = s_rr[3];
        const float* wbase0 = Winc + (size_t)(32 * t) * CW;
        for (int l = 0; l < LMAX; ++l) {
            if (s_idx[l] == n) {
                const float* wb = wbase0 + 4 * l;
#pragma unroll 4
                for (int s = 0; s < 16; ++s) {
                    float4 w1 = *(const float4*)(wb + (size_t)s * CW);
                    float4 w2 = *(const float4*)(wb + (size_t)(s + 16) * CW);
                    float d1 = r0 * w1.x + r1 * w1.y + r2 * w1.z + r3 * w1.w;
                    float d2 = r0 * w2.x + r1 * w2.y + r2 * w2.z + r3 * w2.w;
                    acc += s_mw[s] * d1 + pev[s] * d2;
                }
            }
        }
        val = acc * (1.0f / 32.0f);
        beta[((size_t)b * NND + n) * LMAX + t] = val;
    }
    s_red[t] = (t < LMAX) ? val : 0.f;
    __syncthreads();
    for (int st = 128; st > 0; st >>= 1) {
        if (t < st) s_red[t] += s_red[t + st];
        __syncthreads();
    }
    if (t == 0) meanb[b * NND + n] = s_red[0] / (float)LMAX;
}

// ---------------------------------------------------------------- stable top-K (descending, tie -> lower idx)
__global__ void k_topk(const float* __restrict__ ew, const float* __restrict__ meanb,
                       int* topi, float* alpha) {
    int b = blockIdx.x;
    __shared__ float sv[SORTN];
    __shared__ int si[SORTN];
    int tid = threadIdx.x;  // 256
    for (int i = tid; i < SORTN; i += 256) {
        if (i < NE) { sv[i] = ew[i] * meanb[b * NND + (i % NND)]; si[i] = i; }
        else        { sv[i] = -INFINITY; si[i] = NE + i; }
    }
    __syncthreads();
    for (int k2 = 2; k2 <= SORTN; k2 <<= 1) {
        for (int j = k2 >> 1; j > 0; j >>= 1) {
            for (int i = tid; i < SORTN; i += 256) {
                int ixj = i ^ j;
                if (ixj > i) {
                    float vi = sv[i], vj = sv[ixj];
                    int ii = si[i], ij = si[ixj];
                    bool ipre = (vi > vj) || (vi == vj && ii < ij);
                    bool asc = ((i & k2) == 0);
                    bool sw = asc ? (!ipre) : ipre;
                    if (sw) { sv[i] = vj; sv[ixj] = vi; si[i] = ij; si[ixj] = ii; }
                }
            }
            __syncthreads();
        }
    }
    for (int k = tid; k < NK; k += 256) {
        topi[b * NK + k] = si[k];
        alpha[b * NK + k] = sv[k];
    }
}

// ---------------------------------------------------------------- message passing layer 1
__global__ void k_h1(const int* __restrict__ topi, const float* __restrict__ ew,
                     const float* __restrict__ beta, const int* __restrict__ idxarr,
                     const float* __restrict__ rr, float* h1) {
    int b = blockIdx.x / NND, n = blockIdx.x % NND;
    __shared__ int cnt;
    __shared__ int lsrc[40];
    __shared__ float lew[40];
    int tid = threadIdx.x;  // 256
    if (tid == 0) cnt = 0;
    __syncthreads();
    for (int k = tid; k < NK; k += 256) {
        int e = topi[b * NK + k];
        if (e % NND == n) {
            int p = atomicAdd(&cnt, 1);
            lsrc[p] = e / NND;
            lew[p] = ew[e];
        }
    }
    __syncthreads();
    int m = cnt;
    const float* bb = beta + ((size_t)b * NND + n) * LMAX;
    for (int c = tid; c < CW; c += 256) {
        int t = c >> 2, o = c & 3;
        float bt = bb[t];
        int id = idxarr[b * LMAX + t];
        float x = rr[id * 4 + o];  // sd value if src matches
        float acc = 0.f;
        for (int j = 0; j < m; ++j) {
            float g = bt * lew[j];
            if (g > 0.f && lsrc[j] == id) acc += x * g;
        }
        h1[((size_t)b * NND + n) * CW + c] = acc;
    }
}

// ---------------------------------------------------------------- message passing layer 2
__global__ void k_h2(const int* __restrict__ topi, const float* __restrict__ alpha,
                     const float* __restrict__ h1, float* h2) {
    int b = blockIdx.x / NND, n = blockIdx.x % NND;
    __shared__ int cnt;
    __shared__ int lsrc[40];
    __shared__ float lal[40];
    int tid = threadIdx.x;
    if (tid == 0) cnt = 0;
    __syncthreads();
    for (int k = tid; k < NK; k += 256) {
        int e = topi[b * NK + k];
        if (e % NND == n) {
            int p = atomicAdd(&cnt, 1);
            lsrc[p] = e / NND;
            lal[p] = fmaxf(alpha[b * NK + k], 0.f);
        }
    }
    __syncthreads();
    int m = cnt;
    for (int c = tid; c < CW; c += 256) {
        float acc = 0.f;
        for (int j = 0; j < m; ++j)
            acc += fmaxf(h1[((size_t)b * NND + lsrc[j]) * CW + c], 0.f) * lal[j];
        h2[((size_t)b * NND + n) * CW + c] = acc;
    }
}

// ---------------------------------------------------------------- assemble transformer input
__global__ void k_x0(const float* __restrict__ h2, const float* __restrict__ pe, float* x) {
    int i = blockIdx.x * 256 + threadIdx.x;
    if (i >= NBATCH * LMAX * DTR) return;
    int ch = i % DTR; int bl = i / DTR; int l = bl % LMAX; int b = bl / LMAX;
    float v;
    if (ch < 144) {
        int n = ch >> 2, o = ch & 3;
        v = h2[((size_t)b * NND + n) * CW + 4 * l + o];
    } else {
        v = pe[(b * LMAX + l) * DPE + (ch - 144)];
    }
    x[i] = v;
}

// ---------------------------------------------------------------- distance
__global__ void k_dist(const float* __restrict__ alpha, float* outd) {
    __shared__ float s[64];
    int tid = threadIdx.x;  // 64
    int i = tid / 8, j = tid % 8;
    float d2 = 0.f;
    for (int k = 0; k < NK; ++k) {
        float d = alpha[i * NK + k] - alpha[j * NK + k];
        d2 += d * d;
    }
    s[tid] = (d2 > 0.f) ? sqrtf(d2) : 0.f;
    __syncthreads();
    for (int st = 32; st > 0; st >>= 1) { if (tid < st) s[tid] += s[tid + st]; __syncthreads(); }
    if (tid == 0) *outd = s[0] / 64.0f;
}

// ---------------------------------------------------------------- generic row GEMM: Y[m,n] = X[m,:]·W[n,:] + b[n]
template <int KD>
__global__ void k_gemm(const float* __restrict__ X, const float* __restrict__ W,
                       const float* __restrict__ bias, float* __restrict__ Y,
                       int N, int relu) {
    int m = blockIdx.x;
    int n = blockIdx.y * 128 + threadIdx.x;
    __shared__ float xs[KD];
    for (int d = threadIdx.x; d < KD; d += 128) xs[d] = X[(size_t)m * KD + d];
    __syncthreads();
    if (n >= N) return;
    const float* wr = W + (size_t)n * KD;
    float acc = bias[n];
#pragma unroll 8
    for (int d = 0; d < KD; d += 4) {
        float4 w4 = *(const float4*)(wr + d);
        acc += xs[d] * w4.x + xs[d + 1] * w4.y + xs[d + 2] * w4.z + xs[d + 3] * w4.w;
    }
    if (relu) acc = fmaxf(acc, 0.f);
    Y[(size_t)m * N + n] = acc;
}

// ---------------------------------------------------------------- attention (one wave per (b,h,q))
__global__ void k_attn(const float* __restrict__ qkv, const int* __restrict__ lens,
                       float* __restrict__ ctx) {
    int gid = blockIdx.x;
    int q = gid % LMAX; int bh = gid / LMAX; int h = bh % NHEADS; int b = bh / NHEADS;
    int lane = threadIdx.x;  // 64
    __shared__ float sp[LMAX];
    __shared__ float sq[DH];
    const float* qrow = qkv + ((size_t)(b * LMAX + q) * 480) + h * DH;
    if (lane < DH) sq[lane] = qrow[lane];
    __syncthreads();
    int len = lens[b];
    const float scale = 0.15811388300841898f;  // 1/sqrt(40)
    float lmax = -INFINITY;
    for (int k = lane; k < LMAX; k += 64) {
        const float* krow = qkv + ((size_t)(b * LMAX + k) * 480) + DTR + h * DH;
        float s = 0.f;
#pragma unroll 8
        for (int d = 0; d < DH; ++d) s += sq[d] * krow[d];
        s *= scale;
        if (k >= len) s = -1e9f;
        sp[k] = s;
        lmax = fmaxf(lmax, s);
    }
    for (int off = 32; off > 0; off >>= 1) lmax = fmaxf(lmax, __shfl_xor(lmax, off));
    float lsum = 0.f;
    for (int k = lane; k < LMAX; k += 64) {
        float e = expf(sp[k] - lmax);
        sp[k] = e;
        lsum += e;
    }
    for (int off = 32; off > 0; off >>= 1) lsum += __shfl_xor(lsum, off);
    float inv = 1.0f / lsum;
    __syncthreads();
    if (lane < DH) {
        float acc = 0.f;
        for (int k = 0; k < LMAX; ++k)
            acc += sp[k] * qkv[((size_t)(b * LMAX + k) * 480) + 2 * DTR + h * DH + lane];
        ctx[((size_t)(b * LMAX + q) * DTR) + h * DH + lane] = acc * inv;
    }
}

// ---------------------------------------------------------------- residual + layernorm
__global__ void k_ln(const float* __restrict__ xres, const float* __restrict__ y,
                     const float* __restrict__ w, const float* __restrict__ bb,
                     float* __restrict__ out) {
    int m = blockIdx.x; int tid = threadIdx.x;  // 256
    __shared__ float s[256];
    float v = 0.f;
    if (tid < DTR) v = xres[(size_t)m * DTR + tid] + y[(size_t)m * DTR + tid];
    s[tid] = (tid < DTR) ? v : 0.f;
    __syncthreads();
    for (int st = 128; st > 0; st >>= 1) { if (tid < st) s[tid] += s[tid + st]; __syncthreads(); }
    float mu = s[0] / (float)DTR;
    __syncthreads();
    float d = (tid < DTR) ? (v - mu) : 0.f;
    s[tid] = d * d;
    __syncthreads();
    for (int st = 128; st > 0; st >>= 1) { if (tid < st) s[tid] += s[tid + st]; __syncthreads(); }
    float var = s[0] / (float)DTR;
    float rs = rsqrtf(var + 1e-5f);
    if (tid < DTR) out[(size_t)m * DTR + tid] = (v - mu) * rs * w[tid] + bb[tid];
}

// ---------------------------------------------------------------- final: copy output + preds
__global__ void k_pred(const float* __restrict__ x, const float* __restrict__ wty,
                       const float* __restrict__ wti, const int* __restrict__ lens,
                       float* __restrict__ out) {
    int row = blockIdx.x; int b = row / LMAX; int l = row % LMAX;
    __shared__ float xs[DTR];
    int tid = threadIdx.x;  // 64
    for (int d = tid; d < DTR; d += 64) xs[d] = x[(size_t)row * DTR + d];
    __syncthreads();
    float np = (l < lens[b]) ? 1.f : 0.f;
    if (tid < 37) {
        const float* w = (tid < 36) ? (wty + tid * DTR) : wti;
        float acc = 0.f;
#pragma unroll 8
        for (int d = 0; d < DTR; d += 4) {
            float4 w4 = *(const float4*)(w + d);
            acc += xs[d] * w4.x + xs[d + 1] * w4.y + xs[d + 2] * w4.z + xs[d + 3] * w4.w;
        }
        acc *= np;
        if (tid < 36) out[OUT_TYPE + (size_t)row * NND + tid] = acc;
        else out[OUT_TIME + row] = acc;
    }
    for (int d = tid; d < DTR; d += 64) out[(size_t)row * DTR + d] = xs[d];
}

// ---------------------------------------------------------------- launch
extern "C" void kernel_launch(void* const* d_in, const int* in_sizes, int n_in,
                              void* d_out, int out_size, void* d_ws, size_t ws_size,
                              hipStream_t stream) {
    const int* et      = (const int*)d_in[0];
    const float* etime = (const float*)d_in[1];
    const float* Ru    = (const float*)d_in[2];
    const float* gs    = (const float*)d_in[3];
    const float* Winc  = (const float*)d_in[4];
    const float* binc  = (const float*)d_in[5];
    const float* mapw  = (const float*)d_in[6];
    const float* wtime = (const float*)d_in[7];
    const float* wtype = (const float*)d_in[8];

    float* ws   = (float*)d_ws;
    float* pe   = ws + OFF_PE;
    float* rr   = ws + OFF_RR;
    float* ew   = ws + OFF_EW;
    float* beta = ws + OFF_BETA;
    float* meanb= ws + OFF_MEANB;
    float* alpha= ws + OFF_ALPHA;
    float* h1   = ws + OFF_H1;
    float* h2   = ws + OFF_H2;
    float* x    = ws + OFF_X;
    float* x2   = ws + OFF_X2;
    float* qkvb = ws + OFF_QKV;
    float* ctx  = ws + OFF_CTX;
    float* proj = ws + OFF_PROJ;
    float* ff1  = ws + OFF_FF1;
    float* ff2  = ws + OFF_FF2;
    int* topi   = (int*)(ws + OFF_TOPI);
    int* idxarr = (int*)(ws + OFF_IDX);
    int* lens   = (int*)(ws + OFF_LENS);
    float* outp = (float*)d_out;

    k_prep<<<1, 256, 0, stream>>>(et, etime, Ru, gs, pe, rr, ew, idxarr, lens);
    k_beta<<<NBATCH * NND, 256, 0, stream>>>(Winc, binc, mapw, pe, rr, idxarr, beta, meanb);
    k_topk<<<NBATCH, 256, 0, stream>>>(ew, meanb, topi, alpha);
    k_h1<<<NBATCH * NND, 256, 0, stream>>>(topi, ew, beta, idxarr, rr, h1);
    k_h2<<<NBATCH * NND, 256, 0, stream>>>(topi, alpha, h1, h2);
    k_x0<<<(NBATCH * LMAX * DTR + 255) / 256, 256, 0, stream>>>(h2, pe, x);
    k_dist<<<1, 64, 0, stream>>>(alpha, outp + OUT_DIST);

    const int M = NBATCH * LMAX;  // 1720
    for (int layer = 0; layer < 2; ++layer) {
        int base = 9 + layer * 12;
        const float* qkv_w = (const float*)d_in[base + 0];
        const float* qkv_b = (const float*)d_in[base + 1];
        const float* out_w = (const float*)d_in[base + 2];
        const float* out_b = (const float*)d_in[base + 3];
        const float* ff1_w = (const float*)d_in[base + 4];
        const float* ff1_b = (const float*)d_in[base + 5];
        const float* ff2_w = (const float*)d_in[base + 6];
        const float* ff2_b = (const float*)d_in[base + 7];
        const float* ln1_w = (const float*)d_in[base + 8];
        const float* ln1_b = (const float*)d_in[base + 9];
        const float* ln2_w = (const float*)d_in[base + 10];
        const float* ln2_b = (const float*)d_in[base + 11];

        k_gemm<DTR><<<dim3(M, 4), 128, 0, stream>>>(x, qkv_w, qkv_b, qkvb, 480, 0);
        k_attn<<<NBATCH * NHEADS * LMAX, 64, 0, stream>>>(qkvb, lens, ctx);
        k_gemm<DTR><<<dim3(M, 2), 128, 0, stream>>>(ctx, out_w, out_b, proj, DTR, 0);
        k_ln<<<M, 256, 0, stream>>>(x, proj, ln1_w, ln1_b, x2);
        k_gemm<DTR><<<dim3(M, 2), 128, 0, stream>>>(x2, ff1_w, ff1_b, ff1, NHID2, 1);
        k_gemm<NHID2><<<dim3(M, 2), 128, 0, stream>>>(ff1, ff2_w, ff2_b, ff2, DTR, 0);
        k_ln<<<M, 256, 0, stream>>>(x2, ff2, ln2_w, ln2_b, x);
    }

    k_pred<<<M, 64, 0, stream>>>(x, wtype, wtime, lens, outp);
}

// Round 2
// 814.126 us; speedup vs baseline: 1.6831x; 1.6831x over previous
//
#include <hip/hip_runtime.h>
#include <math.h>

#define NBATCH 8
#define LMAX   215
#define NND    36
#define NE     1296
#define NK     648
#define CW     860      // C = LMAX*4
#define DPE    16
#define DTR    160
#define NHEADS 4
#define DH     40
#define NHID2  256
#define SORTN  2048
#define NPAIR  (NBATCH*LMAX)   // 1720

// output layout (floats)
#define OUT_TYPE (NBATCH*LMAX*DTR)              // 275200
#define OUT_TIME (OUT_TYPE + NBATCH*LMAX*NND)   // 337120
#define OUT_DIST (OUT_TIME + NBATCH*LMAX)       // 338840

// workspace layout (float offsets)
#define OFF_PE    0
#define OFF_RR    (OFF_PE + NBATCH*LMAX*DPE)
#define OFF_EW    (OFF_RR + 144)
#define OFF_BETA  (OFF_EW + NE)
#define OFF_MEANB (OFF_BETA + NBATCH*NND*LMAX)
#define OFF_ALPHA (OFF_MEANB + NBATCH*NND)
#define OFF_H1    (OFF_ALPHA + NBATCH*NK)
#define OFF_H2    (OFF_H1 + NBATCH*NND*CW)
#define OFF_X     (OFF_H2 + NBATCH*NND*CW)
#define OFF_X2    (OFF_X + NBATCH*LMAX*DTR)
#define OFF_QKV   (OFF_X2 + NBATCH*LMAX*DTR)
#define OFF_CTX   (OFF_QKV + NBATCH*LMAX*480)
#define OFF_PROJ  (OFF_CTX + NBATCH*LMAX*DTR)
#define OFF_FF1   (OFF_PROJ + NBATCH*LMAX*DTR)
#define OFF_FF2   (OFF_FF1 + NBATCH*LMAX*NHID2)
#define OFF_TOPI  (OFF_FF2 + NBATCH*LMAX*DTR)
#define OFF_IDX   (OFF_TOPI + NBATCH*NK)
#define OFF_LENS  (OFF_IDX + NBATCH*LMAX)

// ---------------------------------------------------------------- prep
__global__ void k_prep(const int* __restrict__ et, const float* __restrict__ etime,
                       const float* __restrict__ Ru, const float* __restrict__ gs,
                       float* pe, float* rr, float* ew, int* idxarr, int* lens) {
    int tid = threadIdx.x;  // 256
    __shared__ float sts[8];
    if (tid < 8) sts[tid] = (float)pow(215.0, (double)tid / 7.0);
    for (int c = tid; c < 144; c += 256) rr[c] = fmaxf(Ru[c], 0.f);
    for (int e = tid; e < NE; e += 256) {
        int r = e / NND, cc = e % NND;
        ew[e] = (r == cc) ? 1.0f : gs[e];
    }
    if (tid < NBATCH) {
        int cnt = 0;
        for (int l = 0; l < LMAX; ++l) {
            int v = et[tid * LMAX + l];
            cnt += (v != 0);
            idxarr[tid * LMAX + l] = max(v - 1, 0);
        }
        lens[tid] = cnt;
    }
    __syncthreads();
    for (int i = tid; i < NBATCH * LMAX * DPE; i += 256) {
        int s = i & 15; int bl = i >> 4;
        float t = etime[bl];  // bl == b*LMAX+l
        float sc = t / sts[s & 7];
        pe[i] = (s < 8) ? sinf(sc) : cosf(sc);
    }
}

// ---------------------------------------------------------------- beta (v2: one block per t, Winc streamed once)
// beta[b,n,t] = (1/32)[ bias(b,n,t) + sum_{l: idx[b,l]==n} sum_{j<32} coeff(b,n,t,j) * dot(rr4[n], W[32t+j, 4l:4l+4]) ]
//   coeff = mapw[n,j] (j<16) or pe[b,t,j-16] (j>=16)
//   bias  = sum_s mapw[n,s]*binc[32t+s] + pe[b,t,s]*binc[32t+16+s]
__global__ __launch_bounds__(256) void k_beta(
        const float* __restrict__ Winc, const float* __restrict__ binc,
        const float* __restrict__ mapw, const float* __restrict__ pe,
        const float* __restrict__ rr, const int* __restrict__ idxarr,
        float* __restrict__ beta) {
    const int t = blockIdx.x;        // 0..214
    const int tid = threadIdx.x;     // 256

    __shared__ float s_rows[4 * CW];     // 4 Winc rows, 13.8 KB
    __shared__ float s_pair[NPAIR];      // per-(b,l) accumulators
    __shared__ int   s_idx[NPAIR];
    __shared__ float s_mapw[NND * 16];
    __shared__ float s_rr[144];
    __shared__ float s_pe[NBATCH * 16];
    __shared__ float s_binc[32];

    for (int i = tid; i < NPAIR; i += 256) s_idx[i] = idxarr[i];
    for (int i = tid; i < NND * 16; i += 256) s_mapw[i] = mapw[i];
    if (tid < 144) s_rr[tid] = rr[tid];
    if (tid < 128) { int b = tid >> 4, s = tid & 15; s_pe[tid] = pe[((size_t)(b * LMAX + t)) * DPE + s]; }
    if (tid < 32) s_binc[tid] = binc[32 * t + tid];
    __syncthreads();

    float acc[7];
#pragma unroll
    for (int pp = 0; pp < 7; ++pp) acc[pp] = 0.f;

    for (int jc = 0; jc < 8; ++jc) {
        // stage 4 contiguous rows of Winc: rows 32t+4jc .. +3
        const float4* src = (const float4*)(Winc + (size_t)(32 * t + 4 * jc) * CW);
        for (int i = tid; i < CW; i += 256) ((float4*)s_rows)[i] = src[i];
        __syncthreads();

#pragma unroll
        for (int pp = 0; pp < 7; ++pp) {
            int p = tid + pp * 256;
            if (p < NPAIR) {
                int b = p / LMAX, l = p - b * LMAX;
                int n = s_idx[p];
                float4 r4 = *(const float4*)&s_rr[4 * n];
                float a = acc[pp];
#pragma unroll
                for (int jj = 0; jj < 4; ++jj) {
                    int j = 4 * jc + jj;
                    float4 w4 = *(const float4*)&s_rows[jj * CW + 4 * l];
                    float dv = r4.x * w4.x + r4.y * w4.y + r4.z * w4.z + r4.w * w4.w;
                    float coeff = (j < 16) ? s_mapw[n * 16 + j] : s_pe[(b << 4) + (j - 16)];
                    a += coeff * dv;
                }
                acc[pp] = a;
            }
        }
        __syncthreads();
    }

#pragma unroll
    for (int pp = 0; pp < 7; ++pp) {
        int p = tid + pp * 256;
        if (p < NPAIR) s_pair[p] = acc[pp];
    }
    __syncthreads();

    // deterministic per-(b,n) reduction + bias
    if (tid < NBATCH * NND) {
        int b = tid / NND, n = tid - b * NND;
        int base = b * LMAX;
        float sum = 0.f;
        for (int l = 0; l < LMAX; ++l)
            if (s_idx[base + l] == n) sum += s_pair[base + l];
        float bias = 0.f;
#pragma unroll
        for (int s = 0; s < 16; ++s)
            bias += s_mapw[n * 16 + s] * s_binc[s] + s_pe[(b << 4) + s] * s_binc[16 + s];
        beta[((size_t)b * NND + n) * LMAX + t] = (sum + bias) * (1.0f / 32.0f);
    }
}

// ---------------------------------------------------------------- mean over t (deterministic)
__global__ void k_meanb(const float* __restrict__ beta, float* __restrict__ meanb) {
    int bn = blockIdx.x;       // 288
    int lane = threadIdx.x;    // 64
    const float* p = beta + (size_t)bn * LMAX;
    float s = 0.f;
    for (int t = lane; t < LMAX; t += 64) s += p[t];
    for (int off = 32; off > 0; off >>= 1) s += __shfl_xor(s, off);
    if (lane == 0) meanb[bn] = s / (float)LMAX;
}

// ---------------------------------------------------------------- stable top-K (descending, tie -> lower idx)
__global__ void k_topk(const float* __restrict__ ew, const float* __restrict__ meanb,
                       int* topi, float* alpha) {
    int b = blockIdx.x;
    __shared__ float sv[SORTN];
    __shared__ int si[SORTN];
    int tid = threadIdx.x;  // 256
    for (int i = tid; i < SORTN; i += 256) {
        if (i < NE) { sv[i] = ew[i] * meanb[b * NND + (i % NND)]; si[i] = i; }
        else        { sv[i] = -INFINITY; si[i] = NE + i; }
    }
    __syncthreads();
    for (int k2 = 2; k2 <= SORTN; k2 <<= 1) {
        for (int j = k2 >> 1; j > 0; j >>= 1) {
            for (int i = tid; i < SORTN; i += 256) {
                int ixj = i ^ j;
                if (ixj > i) {
                    float vi = sv[i], vj = sv[ixj];
                    int ii = si[i], ij = si[ixj];
                    bool ipre = (vi > vj) || (vi == vj && ii < ij);
                    bool asc = ((i & k2) == 0);
                    bool sw = asc ? (!ipre) : ipre;
                    if (sw) { sv[i] = vj; sv[ixj] = vi; si[i] = ij; si[ixj] = ii; }
                }
            }
            __syncthreads();
        }
    }
    for (int k = tid; k < NK; k += 256) {
        topi[b * NK + k] = si[k];
        alpha[b * NK + k] = sv[k];
    }
}

// ---------------------------------------------------------------- message passing layer 1
__global__ void k_h1(const int* __restrict__ topi, const float* __restrict__ ew,
                     const float* __restrict__ beta, const int* __restrict__ idxarr,
                     const float* __restrict__ rr, float* h1) {
    int b = blockIdx.x / NND, n = blockIdx.x % NND;
    __shared__ int cnt;
    __shared__ int lsrc[40];
    __shared__ float lew[40];
    int tid = threadIdx.x;  // 256
    if (tid == 0) cnt = 0;
    __syncthreads();
    for (int k = tid; k < NK; k += 256) {
        int e = topi[b * NK + k];
        if (e % NND == n) {
            int p = atomicAdd(&cnt, 1);
            lsrc[p] = e / NND;
            lew[p] = ew[e];
        }
    }
    __syncthreads();
    int m = cnt;
    const float* bb = beta + ((size_t)b * NND + n) * LMAX;
    for (int c = tid; c < CW; c += 256) {
        int t = c >> 2, o = c & 3;
        float bt = bb[t];
        int id = idxarr[b * LMAX + t];
        float x = rr[id * 4 + o];  // sd value if src matches
        float acc = 0.f;
        for (int j = 0; j < m; ++j) {
            float g = bt * lew[j];
            if (g > 0.f && lsrc[j] == id) acc += x * g;
        }
        h1[((size_t)b * NND + n) * CW + c] = acc;
    }
}

// ---------------------------------------------------------------- message passing layer 2
__global__ void k_h2(const int* __restrict__ topi, const float* __restrict__ alpha,
                     const float* __restrict__ h1, float* h2) {
    int b = blockIdx.x / NND, n = blockIdx.x % NND;
    __shared__ int cnt;
    __shared__ int lsrc[40];
    __shared__ float lal[40];
    int tid = threadIdx.x;
    if (tid == 0) cnt = 0;
    __syncthreads();
    for (int k = tid; k < NK; k += 256) {
        int e = topi[b * NK + k];
        if (e % NND == n) {
            int p = atomicAdd(&cnt, 1);
            lsrc[p] = e / NND;
            lal[p] = fmaxf(alpha[b * NK + k], 0.f);
        }
    }
    __syncthreads();
    int m = cnt;
    for (int c = tid; c < CW; c += 256) {
        float acc = 0.f;
        for (int j = 0; j < m; ++j)
            acc += fmaxf(h1[((size_t)b * NND + lsrc[j]) * CW + c], 0.f) * lal[j];
        h2[((size_t)b * NND + n) * CW + c] = acc;
    }
}

// ---------------------------------------------------------------- assemble transformer input
__global__ void k_x0(const float* __restrict__ h2, const float* __restrict__ pe, float* x) {
    int i = blockIdx.x * 256 + threadIdx.x;
    if (i >= NBATCH * LMAX * DTR) return;
    int ch = i % DTR; int bl = i / DTR; int l = bl % LMAX; int b = bl / LMAX;
    float v;
    if (ch < 144) {
        int n = ch >> 2, o = ch & 3;
        v = h2[((size_t)b * NND + n) * CW + 4 * l + o];
    } else {
        v = pe[(b * LMAX + l) * DPE + (ch - 144)];
    }
    x[i] = v;
}

// ---------------------------------------------------------------- distance
__global__ void k_dist(const float* __restrict__ alpha, float* outd) {
    __shared__ float s[64];
    int tid = threadIdx.x;  // 64
    int i = tid / 8, j = tid % 8;
    float d2 = 0.f;
    for (int k = 0; k < NK; ++k) {
        float d = alpha[i * NK + k] - alpha[j * NK + k];
        d2 += d * d;
    }
    s[tid] = (d2 > 0.f) ? sqrtf(d2) : 0.f;
    __syncthreads();
    for (int st = 32; st > 0; st >>= 1) { if (tid < st) s[tid] += s[tid + st]; __syncthreads(); }
    if (tid == 0) *outd = s[0] / 64.0f;
}

// ---------------------------------------------------------------- generic row GEMM: Y[m,n] = X[m,:]·W[n,:] + b[n]
template <int KD>
__global__ void k_gemm(const float* __restrict__ X, const float* __restrict__ W,
                       const float* __restrict__ bias, float* __restrict__ Y,
                       int N, int relu) {
    int m = blockIdx.x;
    int n = blockIdx.y * 128 + threadIdx.x;
    __shared__ float xs[KD];
    for (int d = threadIdx.x; d < KD; d += 128) xs[d] = X[(size_t)m * KD + d];
    __syncthreads();
    if (n >= N) return;
    const float* wr = W + (size_t)n * KD;
    float acc = bias[n];
#pragma unroll 8
    for (int d = 0; d < KD; d += 4) {
        float4 w4 = *(const float4*)(wr + d);
        acc += xs[d] * w4.x + xs[d + 1] * w4.y + xs[d + 2] * w4.z + xs[d + 3] * w4.w;
    }
    if (relu) acc = fmaxf(acc, 0.f);
    Y[(size_t)m * N + n] = acc;
}

// ---------------------------------------------------------------- attention (one wave per (b,h,q))
__global__ void k_attn(const float* __restrict__ qkv, const int* __restrict__ lens,
                       float* __restrict__ ctx) {
    int gid = blockIdx.x;
    int q = gid % LMAX; int bh = gid / LMAX; int h = bh % NHEADS; int b = bh / NHEADS;
    int lane = threadIdx.x;  // 64
    __shared__ float sp[LMAX];
    __shared__ float sq[DH];
    const float* qrow = qkv + ((size_t)(b * LMAX + q) * 480) + h * DH;
    if (lane < DH) sq[lane] = qrow[lane];
    __syncthreads();
    int len = lens[b];
    const float scale = 0.15811388300841898f;  // 1/sqrt(40)
    float lmax = -INFINITY;
    for (int k = lane; k < LMAX; k += 64) {
        const float* krow = qkv + ((size_t)(b * LMAX + k) * 480) + DTR + h * DH;
        float s = 0.f;
#pragma unroll 8
        for (int d = 0; d < DH; ++d) s += sq[d] * krow[d];
        s *= scale;
        if (k >= len) s = -1e9f;
        sp[k] = s;
        lmax = fmaxf(lmax, s);
    }
    for (int off = 32; off > 0; off >>= 1) lmax = fmaxf(lmax, __shfl_xor(lmax, off));
    float lsum = 0.f;
    for (int k = lane; k < LMAX; k += 64) {
        float e = expf(sp[k] - lmax);
        sp[k] = e;
        lsum += e;
    }
    for (int off = 32; off > 0; off >>= 1) lsum += __shfl_xor(lsum, off);
    float inv = 1.0f / lsum;
    __syncthreads();
    if (lane < DH) {
        float acc = 0.f;
        for (int k = 0; k < LMAX; ++k)
            acc += sp[k] * qkv[((size_t)(b * LMAX + k) * 480) + 2 * DTR + h * DH + lane];
        ctx[((size_t)(b * LMAX + q) * DTR) + h * DH + lane] = acc * inv;
    }
}

// ---------------------------------------------------------------- residual + layernorm
__global__ void k_ln(const float* __restrict__ xres, const float* __restrict__ y,
                     const float* __restrict__ w, const float* __restrict__ bb,
                     float* __restrict__ out) {
    int m = blockIdx.x; int tid = threadIdx.x;  // 256
    __shared__ float s[256];
    float v = 0.f;
    if (tid < DTR) v = xres[(size_t)m * DTR + tid] + y[(size_t)m * DTR + tid];
    s[tid] = (tid < DTR) ? v : 0.f;
    __syncthreads();
    for (int st = 128; st > 0; st >>= 1) { if (tid < st) s[tid] += s[tid + st]; __syncthreads(); }
    float mu = s[0] / (float)DTR;
    __syncthreads();
    float d = (tid < DTR) ? (v - mu) : 0.f;
    s[tid] = d * d;
    __syncthreads();
    for (int st = 128; st > 0; st >>= 1) { if (tid < st) s[tid] += s[tid + st]; __syncthreads(); }
    float var = s[0] / (float)DTR;
    float rs = rsqrtf(var + 1e-5f);
    if (tid < DTR) out[(size_t)m * DTR + tid] = (v - mu) * rs * w[tid] + bb[tid];
}

// ---------------------------------------------------------------- final: copy output + preds
__global__ void k_pred(const float* __restrict__ x, const float* __restrict__ wty,
                       const float* __restrict__ wti, const int* __restrict__ lens,
                       float* __restrict__ out) {
    int row = blockIdx.x; int b = row / LMAX; int l = row % LMAX;
    __shared__ float xs[DTR];
    int tid = threadIdx.x;  // 64
    for (int d = tid; d < DTR; d += 64) xs[d] = x[(size_t)row * DTR + d];
    __syncthreads();
    float np = (l < lens[b]) ? 1.f : 0.f;
    if (tid < 37) {
        const float* w = (tid < 36) ? (wty + tid * DTR) : wti;
        float acc = 0.f;
#pragma unroll 8
        for (int d = 0; d < DTR; d += 4) {
            float4 w4 = *(const float4*)(w + d);
            acc += xs[d] * w4.x + xs[d + 1] * w4.y + xs[d + 2] * w4.z + xs[d + 3] * w4.w;
        }
        acc *= np;
        if (tid < 36) out[OUT_TYPE + (size_t)row * NND + tid] = acc;
        else out[OUT_TIME + row] = acc;
    }
    for (int d = tid; d < DTR; d += 64) out[(size_t)row * DTR + d] = xs[d];
}

// ---------------------------------------------------------------- launch
extern "C" void kernel_launch(void* const* d_in, const int* in_sizes, int n_in,
                              void* d_out, int out_size, void* d_ws, size_t ws_size,
                              hipStream_t stream) {
    const int* et      = (const int*)d_in[0];
    const float* etime = (const float*)d_in[1];
    const float* Ru    = (const float*)d_in[2];
    const float* gs    = (const float*)d_in[3];
    const float* Winc  = (const float*)d_in[4];
    const float* binc  = (const float*)d_in[5];
    const float* mapw  = (const float*)d_in[6];
    const float* wtime = (const float*)d_in[7];
    const float* wtype = (const float*)d_in[8];

    float* ws   = (float*)d_ws;
    float* pe   = ws + OFF_PE;
    float* rr   = ws + OFF_RR;
    float* ew   = ws + OFF_EW;
    float* beta = ws + OFF_BETA;
    float* meanb= ws + OFF_MEANB;
    float* alpha= ws + OFF_ALPHA;
    float* h1   = ws + OFF_H1;
    float* h2   = ws + OFF_H2;
    float* x    = ws + OFF_X;
    float* x2   = ws + OFF_X2;
    float* qkvb = ws + OFF_QKV;
    float* ctx  = ws + OFF_CTX;
    float* proj = ws + OFF_PROJ;
    float* ff1  = ws + OFF_FF1;
    float* ff2  = ws + OFF_FF2;
    int* topi   = (int*)(ws + OFF_TOPI);
    int* idxarr = (int*)(ws + OFF_IDX);
    int* lens   = (int*)(ws + OFF_LENS);
    float* outp = (float*)d_out;

    k_prep<<<1, 256, 0, stream>>>(et, etime, Ru, gs, pe, rr, ew, idxarr, lens);
    k_beta<<<LMAX, 256, 0, stream>>>(Winc, binc, mapw, pe, rr, idxarr, beta);
    k_meanb<<<NBATCH * NND, 64, 0, stream>>>(beta, meanb);
    k_topk<<<NBATCH, 256, 0, stream>>>(ew, meanb, topi, alpha);
    k_h1<<<NBATCH * NND, 256, 0, stream>>>(topi, ew, beta, idxarr, rr, h1);
    k_h2<<<NBATCH * NND, 256, 0, stream>>>(topi, alpha, h1, h2);
    k_x0<<<(NBATCH * LMAX * DTR + 255) / 256, 256, 0, stream>>>(h2, pe, x);
    k_dist<<<1, 64, 0, stream>>>(alpha, outp + OUT_DIST);

    const int M = NBATCH * LMAX;  // 1720
    for (int layer = 0; layer < 2; ++layer) {
        int base = 9 + layer * 12;
        const float* qkv_w = (const float*)d_in[base + 0];
        const float* qkv_b = (const float*)d_in[base + 1];
        const float* out_w = (const float*)d_in[base + 2];
        const float* out_b = (const float*)d_in[base + 3];
        const float* ff1_w = (const float*)d_in[base + 4];
        const float* ff1_b = (const float*)d_in[base + 5];
        const float* ff2_w = (const float*)d_in[base + 6];
        const float* ff2_b = (const float*)d_in[base + 7];
        const float* ln1_w = (const float*)d_in[base + 8];
        const float* ln1_b = (const float*)d_in[base + 9];
        const float* ln2_w = (const float*)d_in[base + 10];
        const float* ln2_b = (const float*)d_in[base + 11];

        k_gemm<DTR><<<dim3(M, 4), 128, 0, stream>>>(x, qkv_w, qkv_b, qkvb, 480, 0);
        k_attn<<<NBATCH * NHEADS * LMAX, 64, 0, stream>>>(qkvb, lens, ctx);
        k_gemm<DTR><<<dim3(M, 2), 128, 0, stream>>>(ctx, out_w, out_b, proj, DTR, 0);
        k_ln<<<M, 256, 0, stream>>>(x, proj, ln1_w, ln1_b, x2);
        k_gemm<DTR><<<dim3(M, 2), 128, 0, stream>>>(x2, ff1_w, ff1_b, ff1, NHID2, 1);
        k_gemm<NHID2><<<dim3(M, 2), 128, 0, stream>>>(ff1, ff2_w, ff2_b, ff2, DTR, 0);
        k_ln<<<M, 256, 0, stream>>>(x2, ff2, ln2_w, ln2_b, x);
    }

    k_pred<<<M, 64, 0, stream>>>(x, wtype, wtime, lens, outp);
}

// Round 3
// 690.347 us; speedup vs baseline: 1.9848x; 1.1793x over previous
//
#include <hip/hip_runtime.h>
#include <math.h>

#define NBATCH 8
#define LMAX   215
#define NND    36
#define NE     1296
#define NK     648
#define CW     860      // C = LMAX*4
#define DPE    16
#define DTR    160
#define NHEADS 4
#define DH     40
#define NHID2  256
#define NPAIR  (NBATCH*LMAX)   // 1720

// output layout (floats)
#define OUT_TYPE (NBATCH*LMAX*DTR)              // 275200
#define OUT_TIME (OUT_TYPE + NBATCH*LMAX*NND)   // 337120
#define OUT_DIST (OUT_TIME + NBATCH*LMAX)       // 338840

// workspace layout (float offsets)
#define OFF_PE    0
#define OFF_RR    (OFF_PE + NBATCH*LMAX*DPE)
#define OFF_EW    (OFF_RR + 144)
#define OFF_BETA  (OFF_EW + NE)
#define OFF_MEANB (OFF_BETA + NBATCH*NND*LMAX)
#define OFF_ALPHA (OFF_MEANB + NBATCH*NND)
#define OFF_H1    (OFF_ALPHA + NBATCH*NK)
#define OFF_H2    (OFF_H1 + NBATCH*NND*CW)
#define OFF_X     (OFF_H2 + NBATCH*NND*CW)
#define OFF_X2    (OFF_X + NBATCH*LMAX*DTR)
#define OFF_QKV   (OFF_X2 + NBATCH*LMAX*DTR)
#define OFF_CTX   (OFF_QKV + NBATCH*LMAX*480)
#define OFF_TOPI  (OFF_CTX + NBATCH*LMAX*DTR)
#define OFF_IDX   (OFF_TOPI + NBATCH*NK)
#define OFF_LENS  (OFF_IDX + NBATCH*LMAX)

// ---------------------------------------------------------------- prep
__global__ void k_prep(const int* __restrict__ et, const float* __restrict__ etime,
                       const float* __restrict__ Ru, const float* __restrict__ gs,
                       float* pe, float* rr, float* ew, int* idxarr, int* lens) {
    int tid = threadIdx.x;  // 256
    __shared__ float sts[8];
    if (tid < 8) sts[tid] = (float)pow(215.0, (double)tid / 7.0);
    for (int c = tid; c < 144; c += 256) rr[c] = fmaxf(Ru[c], 0.f);
    for (int e = tid; e < NE; e += 256) {
        int r = e / NND, cc = e % NND;
        ew[e] = (r == cc) ? 1.0f : gs[e];
    }
    if (tid < NBATCH) {
        int cnt = 0;
        for (int l = 0; l < LMAX; ++l) {
            int v = et[tid * LMAX + l];
            cnt += (v != 0);
            idxarr[tid * LMAX + l] = max(v - 1, 0);
        }
        lens[tid] = cnt;
    }
    __syncthreads();
    for (int i = tid; i < NBATCH * LMAX * DPE; i += 256) {
        int s = i & 15; int bl = i >> 4;
        float t = etime[bl];  // bl == b*LMAX+l
        float sc = t / sts[s & 7];
        pe[i] = (s < 8) ? sinf(sc) : cosf(sc);
    }
}

// ---------------------------------------------------------------- beta (one block per t, Winc streamed once)
__global__ __launch_bounds__(256) void k_beta(
        const float* __restrict__ Winc, const float* __restrict__ binc,
        const float* __restrict__ mapw, const float* __restrict__ pe,
        const float* __restrict__ rr, const int* __restrict__ idxarr,
        float* __restrict__ beta) {
    const int t = blockIdx.x;        // 0..214
    const int tid = threadIdx.x;     // 256

    __shared__ float s_rows[4 * CW];     // 4 Winc rows, 13.8 KB
    __shared__ float s_pair[NPAIR];      // per-(b,l) accumulators
    __shared__ int   s_idx[NPAIR];
    __shared__ float s_mapw[NND * 16];
    __shared__ float s_rr[144];
    __shared__ float s_pe[NBATCH * 16];
    __shared__ float s_binc[32];

    for (int i = tid; i < NPAIR; i += 256) s_idx[i] = idxarr[i];
    for (int i = tid; i < NND * 16; i += 256) s_mapw[i] = mapw[i];
    if (tid < 144) s_rr[tid] = rr[tid];
    if (tid < 128) { int b = tid >> 4, s = tid & 15; s_pe[tid] = pe[((size_t)(b * LMAX + t)) * DPE + s]; }
    if (tid < 32) s_binc[tid] = binc[32 * t + tid];
    __syncthreads();

    float acc[7];
#pragma unroll
    for (int pp = 0; pp < 7; ++pp) acc[pp] = 0.f;

    for (int jc = 0; jc < 8; ++jc) {
        const float4* src = (const float4*)(Winc + (size_t)(32 * t + 4 * jc) * CW);
        for (int i = tid; i < CW; i += 256) ((float4*)s_rows)[i] = src[i];
        __syncthreads();

#pragma unroll
        for (int pp = 0; pp < 7; ++pp) {
            int p = tid + pp * 256;
            if (p < NPAIR) {
                int b = p / LMAX, l = p - b * LMAX;
                int n = s_idx[p];
                float4 r4 = *(const float4*)&s_rr[4 * n];
                float a = acc[pp];
#pragma unroll
                for (int jj = 0; jj < 4; ++jj) {
                    int j = 4 * jc + jj;
                    float4 w4 = *(const float4*)&s_rows[jj * CW + 4 * l];
                    float dv = r4.x * w4.x + r4.y * w4.y + r4.z * w4.z + r4.w * w4.w;
                    float coeff = (j < 16) ? s_mapw[n * 16 + j] : s_pe[(b << 4) + (j - 16)];
                    a += coeff * dv;
                }
                acc[pp] = a;
            }
        }
        __syncthreads();
    }

#pragma unroll
    for (int pp = 0; pp < 7; ++pp) {
        int p = tid + pp * 256;
        if (p < NPAIR) s_pair[p] = acc[pp];
    }
    __syncthreads();

    if (tid < NBATCH * NND) {
        int b = tid / NND, n = tid - b * NND;
        int base = b * LMAX;
        float sum = 0.f;
        for (int l = 0; l < LMAX; ++l)
            if (s_idx[base + l] == n) sum += s_pair[base + l];
        float bias = 0.f;
#pragma unroll
        for (int s = 0; s < 16; ++s)
            bias += s_mapw[n * 16 + s] * s_binc[s] + s_pe[(b << 4) + s] * s_binc[16 + s];
        beta[((size_t)b * NND + n) * LMAX + t] = (sum + bias) * (1.0f / 32.0f);
    }
}

// ---------------------------------------------------------------- mean over t (deterministic)
__global__ void k_meanb(const float* __restrict__ beta, float* __restrict__ meanb) {
    int bn = blockIdx.x;       // 288
    int lane = threadIdx.x;    // 64
    const float* p = beta + (size_t)bn * LMAX;
    float s = 0.f;
    for (int t = lane; t < LMAX; t += 64) s += p[t];
    for (int off = 32; off > 0; off >>= 1) s += __shfl_xor(s, off);
    if (lane == 0) meanb[bn] = s / (float)LMAX;
}

// ---------------------------------------------------------------- stable top-K via rank selection
// rank(e) = #{i: v_i > v_e} + #{i < e: v_i == v_e}  ==  position in stable descending argsort
__global__ __launch_bounds__(256) void k_topk(const float* __restrict__ ew,
                                              const float* __restrict__ meanb,
                                              int* __restrict__ topi, float* __restrict__ alpha) {
    int chunk = blockIdx.x;    // 0..5  (216 elements each)
    int b = blockIdx.y;        // 0..7
    int tid = threadIdx.x;     // 256
    __shared__ float sv[NE];
    __shared__ float sm[NND];
    if (tid < NND) sm[tid] = meanb[b * NND + tid];
    __syncthreads();
    for (int e = tid; e < NE; e += 256) sv[e] = ew[e] * sm[e % NND];
    __syncthreads();
    int e = chunk * 216 + tid;
    if (tid < 216) {
        float v = sv[e];
        int rank = 0;
        for (int i = 0; i < NE; ++i) {
            float u = sv[i];
            rank += (u > v) || (u == v && i < e);
        }
        if (rank < NK) {
            topi[b * NK + rank] = e;
            alpha[b * NK + rank] = v;
        }
    }
}

// ---------------------------------------------------------------- message passing layer 1
__global__ void k_h1(const int* __restrict__ topi, const float* __restrict__ ew,
                     const float* __restrict__ beta, const int* __restrict__ idxarr,
                     const float* __restrict__ rr, float* h1) {
    int b = blockIdx.x / NND, n = blockIdx.x % NND;
    __shared__ int cnt;
    __shared__ int lsrc[40];
    __shared__ float lew[40];
    int tid = threadIdx.x;  // 256
    if (tid == 0) cnt = 0;
    __syncthreads();
    for (int k = tid; k < NK; k += 256) {
        int e = topi[b * NK + k];
        if (e % NND == n) {
            int p = atomicAdd(&cnt, 1);
            lsrc[p] = e / NND;
            lew[p] = ew[e];
        }
    }
    __syncthreads();
    int m = cnt;
    const float* bb = beta + ((size_t)b * NND + n) * LMAX;
    for (int c = tid; c < CW; c += 256) {
        int t = c >> 2, o = c & 3;
        float bt = bb[t];
        int id = idxarr[b * LMAX + t];
        float x = rr[id * 4 + o];
        float acc = 0.f;
        for (int j = 0; j < m; ++j) {
            float g = bt * lew[j];
            if (g > 0.f && lsrc[j] == id) acc += x * g;
        }
        h1[((size_t)b * NND + n) * CW + c] = acc;
    }
}

// ---------------------------------------------------------------- message passing layer 2
__global__ void k_h2(const int* __restrict__ topi, const float* __restrict__ alpha,
                     const float* __restrict__ h1, float* h2) {
    int b = blockIdx.x / NND, n = blockIdx.x % NND;
    __shared__ int cnt;
    __shared__ int lsrc[40];
    __shared__ float lal[40];
    int tid = threadIdx.x;
    if (tid == 0) cnt = 0;
    __syncthreads();
    for (int k = tid; k < NK; k += 256) {
        int e = topi[b * NK + k];
        if (e % NND == n) {
            int p = atomicAdd(&cnt, 1);
            lsrc[p] = e / NND;
            lal[p] = fmaxf(alpha[b * NK + k], 0.f);
        }
    }
    __syncthreads();
    int m = cnt;
    for (int c = tid; c < CW; c += 256) {
        float acc = 0.f;
        for (int j = 0; j < m; ++j)
            acc += fmaxf(h1[((size_t)b * NND + lsrc[j]) * CW + c], 0.f) * lal[j];
        h2[((size_t)b * NND + n) * CW + c] = acc;
    }
}

// ---------------------------------------------------------------- assemble transformer input
__global__ void k_x0(const float* __restrict__ h2, const float* __restrict__ pe, float* x) {
    int i = blockIdx.x * 256 + threadIdx.x;
    if (i >= NBATCH * LMAX * DTR) return;
    int ch = i % DTR; int bl = i / DTR; int l = bl % LMAX; int b = bl / LMAX;
    float v;
    if (ch < 144) {
        int n = ch >> 2, o = ch & 3;
        v = h2[((size_t)b * NND + n) * CW + 4 * l + o];
    } else {
        v = pe[(b * LMAX + l) * DPE + (ch - 144)];
    }
    x[i] = v;
}

// ---------------------------------------------------------------- distance
__global__ void k_dist(const float* __restrict__ alpha, float* outd) {
    __shared__ float s[64];
    int tid = threadIdx.x;  // 64
    int i = tid / 8, j = tid % 8;
    float d2 = 0.f;
    for (int k = 0; k < NK; ++k) {
        float d = alpha[i * NK + k] - alpha[j * NK + k];
        d2 += d * d;
    }
    s[tid] = (d2 > 0.f) ? sqrtf(d2) : 0.f;
    __syncthreads();
    for (int st = 32; st > 0; st >>= 1) { if (tid < st) s[tid] += s[tid + st]; __syncthreads(); }
    if (tid == 0) *outd = s[0] / 64.0f;
}

// ---------------------------------------------------------------- 8-row tiled GEMM: Y[m,n] = X[m,:]·W[n,:] + b[n]
template <int KD>
__global__ __launch_bounds__(256) void k_gemm8(const float* __restrict__ X, const float* __restrict__ W,
                                               const float* __restrict__ bias, float* __restrict__ Y,
                                               int N) {
    int m0 = blockIdx.x * 8;
    int n = blockIdx.y * 256 + threadIdx.x;
    __shared__ float xs[8 * KD];
    for (int i = threadIdx.x; i < 8 * KD; i += 256) xs[i] = X[(size_t)m0 * KD + i];
    __syncthreads();
    if (n >= N) return;
    const float* wr = W + (size_t)n * KD;
    float acc[8];
    float bv = bias[n];
#pragma unroll
    for (int r = 0; r < 8; ++r) acc[r] = bv;
    for (int d = 0; d < KD; d += 4) {
        float4 w4 = *(const float4*)(wr + d);
#pragma unroll
        for (int r = 0; r < 8; ++r) {
            float4 x4 = *(const float4*)&xs[r * KD + d];
            acc[r] += x4.x * w4.x + x4.y * w4.y + x4.z * w4.z + x4.w * w4.w;
        }
    }
#pragma unroll
    for (int r = 0; r < 8; ++r) Y[(size_t)(m0 + r) * N + n] = acc[r];
}

// ---------------------------------------------------------------- attention (one wave per (b,h,q))
__global__ void k_attn(const float* __restrict__ qkv, const int* __restrict__ lens,
                       float* __restrict__ ctx) {
    int gid = blockIdx.x;
    int q = gid % LMAX; int bh = gid / LMAX; int h = bh % NHEADS; int b = bh / NHEADS;
    int lane = threadIdx.x;  // 64
    __shared__ float sp[LMAX];
    __shared__ float sq[DH];
    const float* qrow = qkv + ((size_t)(b * LMAX + q) * 480) + h * DH;
    if (lane < DH) sq[lane] = qrow[lane];
    __syncthreads();
    int len = lens[b];
    const float scale = 0.15811388300841898f;  // 1/sqrt(40)
    float lmax = -INFINITY;
    for (int k = lane; k < LMAX; k += 64) {
        const float* krow = qkv + ((size_t)(b * LMAX + k) * 480) + DTR + h * DH;
        float s = 0.f;
#pragma unroll 8
        for (int d = 0; d < DH; ++d) s += sq[d] * krow[d];
        s *= scale;
        if (k >= len) s = -1e9f;
        sp[k] = s;
        lmax = fmaxf(lmax, s);
    }
    for (int off = 32; off > 0; off >>= 1) lmax = fmaxf(lmax, __shfl_xor(lmax, off));
    float lsum = 0.f;
    for (int k = lane; k < LMAX; k += 64) {
        float e = expf(sp[k] - lmax);
        sp[k] = e;
        lsum += e;
    }
    for (int off = 32; off > 0; off >>= 1) lsum += __shfl_xor(lsum, off);
    float inv = 1.0f / lsum;
    __syncthreads();
    if (lane < DH) {
        float acc = 0.f;
        for (int k = 0; k < LMAX; ++k)
            acc += sp[k] * qkv[((size_t)(b * LMAX + k) * 480) + 2 * DTR + h * DH + lane];
        ctx[((size_t)(b * LMAX + q) * DTR) + h * DH + lane] = acc * inv;
    }
}

// ---------------------------------------------------------------- device LN helper (per-wave over one row in LDS)
__device__ __forceinline__ void wave_ln_row(const float* __restrict__ row, int lane,
                                            const float* __restrict__ lnw, const float* __restrict__ lnb,
                                            float* __restrict__ dst) {
    float s = 0.f;
    for (int d = lane; d < DTR; d += 64) s += row[d];
    for (int off = 32; off > 0; off >>= 1) s += __shfl_xor(s, off);
    float mu = s / (float)DTR;
    float v = 0.f;
    for (int d = lane; d < DTR; d += 64) { float dd = row[d] - mu; v += dd * dd; }
    for (int off = 32; off > 0; off >>= 1) v += __shfl_xor(v, off);
    float rs = rsqrtf(v / (float)DTR + 1e-5f);
    for (int d = lane; d < DTR; d += 64)
        dst[d] = (row[d] - mu) * rs * lnw[d] + lnb[d];
}

// ---------------------------------------------------------------- fused out-proj + residual + LN1 (8 rows/block)
__global__ __launch_bounds__(256) void k_projln(const float* __restrict__ ctx, const float* __restrict__ xres,
                                                const float* __restrict__ W, const float* __restrict__ bias,
                                                const float* __restrict__ lnw, const float* __restrict__ lnb,
                                                float* __restrict__ out) {
    int m0 = blockIdx.x * 8;
    int tid = threadIdx.x;  // 256
    __shared__ float xs[8 * DTR];
    __shared__ float ys[8 * DTR];
    for (int i = tid; i < 8 * DTR; i += 256) xs[i] = ctx[(size_t)m0 * DTR + i];
    __syncthreads();
    for (int o = tid; o < 8 * DTR; o += 256) {
        int r = o / DTR, n = o - r * DTR;
        const float* wr = W + (size_t)n * DTR;
        float acc = bias[n];
#pragma unroll 8
        for (int d = 0; d < DTR; d += 4) {
            float4 w4 = *(const float4*)(wr + d);
            float4 x4 = *(const float4*)&xs[r * DTR + d];
            acc += x4.x * w4.x + x4.y * w4.y + x4.z * w4.z + x4.w * w4.w;
        }
        ys[o] = acc + xres[(size_t)(m0 + r) * DTR + n];
    }
    __syncthreads();
    int wid = tid >> 6, lane = tid & 63;
    for (int r = wid; r < 8; r += 4)
        wave_ln_row(&ys[r * DTR], lane, lnw, lnb, out + (size_t)(m0 + r) * DTR);
}

// ---------------------------------------------------------------- fused FF1+relu+FF2 + residual + LN2 (8 rows/block)
__global__ __launch_bounds__(256) void k_ffln(const float* __restrict__ xin,
                                              const float* __restrict__ W1, const float* __restrict__ b1,
                                              const float* __restrict__ W2, const float* __restrict__ b2,
                                              const float* __restrict__ lnw, const float* __restrict__ lnb,
                                              float* __restrict__ out) {
    int m0 = blockIdx.x * 8;
    int tid = threadIdx.x;  // 256
    __shared__ float xs[8 * DTR];    // 5 KB
    __shared__ float hs[8 * NHID2];  // 8 KB
    __shared__ float zs[8 * DTR];    // 5 KB
    for (int i = tid; i < 8 * DTR; i += 256) xs[i] = xin[(size_t)m0 * DTR + i];
    __syncthreads();
    for (int o = tid; o < 8 * NHID2; o += 256) {
        int r = o >> 8, n = o & 255;
        const float* wr = W1 + (size_t)n * DTR;
        float acc = b1[n];
#pragma unroll 8
        for (int d = 0; d < DTR; d += 4) {
            float4 w4 = *(const float4*)(wr + d);
            float4 x4 = *(const float4*)&xs[r * DTR + d];
            acc += x4.x * w4.x + x4.y * w4.y + x4.z * w4.z + x4.w * w4.w;
        }
        hs[o] = fmaxf(acc, 0.f);
    }
    __syncthreads();
    for (int o = tid; o < 8 * DTR; o += 256) {
        int r = o / DTR, n = o - r * DTR;
        const float* wr = W2 + (size_t)n * NHID2;
        float acc = b2[n];
#pragma unroll 8
        for (int d = 0; d < NHID2; d += 4) {
            float4 w4 = *(const float4*)(wr + d);
            float4 h4 = *(const float4*)&hs[r * NHID2 + d];
            acc += h4.x * w4.x + h4.y * w4.y + h4.z * w4.z + h4.w * w4.w;
        }
        zs[o] = acc + xs[o];
    }
    __syncthreads();
    int wid = tid >> 6, lane = tid & 63;
    for (int r = wid; r < 8; r += 4)
        wave_ln_row(&zs[r * DTR], lane, lnw, lnb, out + (size_t)(m0 + r) * DTR);
}

// ---------------------------------------------------------------- final: copy output + preds
__global__ void k_pred(const float* __restrict__ x, const float* __restrict__ wty,
                       const float* __restrict__ wti, const int* __restrict__ lens,
                       float* __restrict__ out) {
    int row = blockIdx.x; int b = row / LMAX; int l = row % LMAX;
    __shared__ float xs[DTR];
    int tid = threadIdx.x;  // 64
    for (int d = tid; d < DTR; d += 64) xs[d] = x[(size_t)row * DTR + d];
    __syncthreads();
    float np = (l < lens[b]) ? 1.f : 0.f;
    if (tid < 37) {
        const float* w = (tid < 36) ? (wty + tid * DTR) : wti;
        float acc = 0.f;
#pragma unroll 8
        for (int d = 0; d < DTR; d += 4) {
            float4 w4 = *(const float4*)(w + d);
            acc += xs[d] * w4.x + xs[d + 1] * w4.y + xs[d + 2] * w4.z + xs[d + 3] * w4.w;
        }
        acc *= np;
        if (tid < 36) out[OUT_TYPE + (size_t)row * NND + tid] = acc;
        else out[OUT_TIME + row] = acc;
    }
    for (int d = tid; d < DTR; d += 64) out[(size_t)row * DTR + d] = xs[d];
}

// ---------------------------------------------------------------- launch
extern "C" void kernel_launch(void* const* d_in, const int* in_sizes, int n_in,
                              void* d_out, int out_size, void* d_ws, size_t ws_size,
                              hipStream_t stream) {
    const int* et      = (const int*)d_in[0];
    const float* etime = (const float*)d_in[1];
    const float* Ru    = (const float*)d_in[2];
    const float* gs    = (const float*)d_in[3];
    const float* Winc  = (const float*)d_in[4];
    const float* binc  = (const float*)d_in[5];
    const float* mapw  = (const float*)d_in[6];
    const float* wtime = (const float*)d_in[7];
    const float* wtype = (const float*)d_in[8];

    float* ws   = (float*)d_ws;
    float* pe   = ws + OFF_PE;
    float* rr   = ws + OFF_RR;
    float* ew   = ws + OFF_EW;
    float* beta = ws + OFF_BETA;
    float* meanb= ws + OFF_MEANB;
    float* alpha= ws + OFF_ALPHA;
    float* h1   = ws + OFF_H1;
    float* h2   = ws + OFF_H2;
    float* x    = ws + OFF_X;
    float* x2   = ws + OFF_X2;
    float* qkvb = ws + OFF_QKV;
    float* ctx  = ws + OFF_CTX;
    int* topi   = (int*)(ws + OFF_TOPI);
    int* idxarr = (int*)(ws + OFF_IDX);
    int* lens   = (int*)(ws + OFF_LENS);
    float* outp = (float*)d_out;

    k_prep<<<1, 256, 0, stream>>>(et, etime, Ru, gs, pe, rr, ew, idxarr, lens);
    k_beta<<<LMAX, 256, 0, stream>>>(Winc, binc, mapw, pe, rr, idxarr, beta);
    k_meanb<<<NBATCH * NND, 64, 0, stream>>>(beta, meanb);
    k_topk<<<dim3(6, NBATCH), 256, 0, stream>>>(ew, meanb, topi, alpha);
    k_h1<<<NBATCH * NND, 256, 0, stream>>>(topi, ew, beta, idxarr, rr, h1);
    k_h2<<<NBATCH * NND, 256, 0, stream>>>(topi, alpha, h1, h2);
    k_x0<<<(NBATCH * LMAX * DTR + 255) / 256, 256, 0, stream>>>(h2, pe, x);
    k_dist<<<1, 64, 0, stream>>>(alpha, outp + OUT_DIST);

    const int MB = NPAIR / 8;  // 215 row-tiles
    for (int layer = 0; layer < 2; ++layer) {
        int base = 9 + layer * 12;
        const float* qkv_w = (const float*)d_in[base + 0];
        const float* qkv_b = (const float*)d_in[base + 1];
        const float* out_w = (const float*)d_in[base + 2];
        const float* out_b = (const float*)d_in[base + 3];
        const float* ff1_w = (const float*)d_in[base + 4];
        const float* ff1_b = (const float*)d_in[base + 5];
        const float* ff2_w = (const float*)d_in[base + 6];
        const float* ff2_b = (const float*)d_in[base + 7];
        const float* ln1_w = (const float*)d_in[base + 8];
        const float* ln1_b = (const float*)d_in[base + 9];
        const float* ln2_w = (const float*)d_in[base + 10];
        const float* ln2_b = (const float*)d_in[base + 11];

        k_gemm8<DTR><<<dim3(MB, 2), 256, 0, stream>>>(x, qkv_w, qkv_b, qkvb, 480);
        k_attn<<<NBATCH * NHEADS * LMAX, 64, 0, stream>>>(qkvb, lens, ctx);
        k_projln<<<MB, 256, 0, stream>>>(ctx, x, out_w, out_b, ln1_w, ln1_b, x2);
        k_ffln<<<MB, 256, 0, stream>>>(x2, ff1_w, ff1_b, ff2_w, ff2_b, ln2_w, ln2_b, x);
    }

    k_pred<<<NPAIR, 64, 0, stream>>>(x, wtype, wtime, lens, outp);
}

// Round 4
// 622.400 us; speedup vs baseline: 2.2015x; 1.1092x over previous
//
#include <hip/hip_runtime.h>
#include <math.h>

#define NBATCH 8
#define LMAX   215
#define NND    36
#define NE     1296
#define NK     648
#define CW     860      // C = LMAX*4
#define DPE    16
#define DTR    160
#define NHEADS 4
#define DH     40
#define NHID2  256
#define NPAIR  (NBATCH*LMAX)   // 1720

// output layout (floats)
#define OUT_TYPE (NBATCH*LMAX*DTR)              // 275200
#define OUT_TIME (OUT_TYPE + NBATCH*LMAX*NND)   // 337120
#define OUT_DIST (OUT_TIME + NBATCH*LMAX)       // 338840

// workspace layout (float offsets)
#define OFF_PE    0
#define OFF_RR    (OFF_PE + NBATCH*LMAX*DPE)
#define OFF_EW    (OFF_RR + 144)
#define OFF_BETA  (OFF_EW + NE)
#define OFF_MEANB (OFF_BETA + NBATCH*NND*LMAX)
#define OFF_ALPHA (OFF_MEANB + NBATCH*NND)
#define OFF_H1    (OFF_ALPHA + NBATCH*NK)
#define OFF_H2    (OFF_H1 + NBATCH*NND*CW)
#define OFF_X     (OFF_H2 + NBATCH*NND*CW)
#define OFF_X2    (OFF_X + NBATCH*LMAX*DTR)
#define OFF_QKV   (OFF_X2 + NBATCH*LMAX*DTR)
#define OFF_CTX   (OFF_QKV + NBATCH*LMAX*480)
#define OFF_TOPI  (OFF_CTX + NBATCH*LMAX*DTR)
#define OFF_IDX   (OFF_TOPI + NBATCH*NK)
#define OFF_LENS  (OFF_IDX + NBATCH*LMAX)

// ---------------------------------------------------------------- prep (parallel: 73 blocks)
// blk 0: rr + ew   | blk 1..8: per-batch idx + length | blk 9..72: pe chunks (430 elems)
__global__ __launch_bounds__(256) void k_prep(
        const int* __restrict__ et, const float* __restrict__ etime,
        const float* __restrict__ Ru, const float* __restrict__ gs,
        float* pe, float* rr, float* ew, int* idxarr, int* lens) {
    int blk = blockIdx.x, tid = threadIdx.x;
    if (blk == 0) {
        for (int c = tid; c < 144; c += 256) rr[c] = fmaxf(Ru[c], 0.f);
        for (int e = tid; e < NE; e += 256) {
            int r = e / NND, cc = e % NND;
            ew[e] = (r == cc) ? 1.0f : gs[e];
        }
    } else if (blk <= 8) {
        int b = blk - 1;
        __shared__ int red[256];
        int cnt = 0;
        for (int l = tid; l < LMAX; l += 256) {
            int v = et[b * LMAX + l];
            cnt += (v != 0);
            idxarr[b * LMAX + l] = max(v - 1, 0);
        }
        red[tid] = cnt;
        __syncthreads();
        for (int st = 128; st > 0; st >>= 1) { if (tid < st) red[tid] += red[tid + st]; __syncthreads(); }
        if (tid == 0) lens[b] = red[0];
    } else {
        __shared__ float sts[8];
        if (tid < 8) sts[tid] = (float)pow(215.0, (double)tid / 7.0);
        __syncthreads();
        int i0 = (blk - 9) * 430;
        for (int i = i0 + tid; i < i0 + 430; i += 256) {
            int s = i & 15; int bl = i >> 4;
            float t = etime[bl];
            float sc = t / sts[s & 7];
            pe[i] = (s < 8) ? sinf(sc) : cosf(sc);
        }
    }
}

// ---------------------------------------------------------------- beta (block per t; double-buffered Winc tiles)
__global__ __launch_bounds__(256) void k_beta(
        const float* __restrict__ Winc, const float* __restrict__ binc,
        const float* __restrict__ mapw, const float* __restrict__ pe,
        const float* __restrict__ rr, const int* __restrict__ idxarr,
        float* __restrict__ beta) {
    const int t = blockIdx.x;        // 0..214
    const int tid = threadIdx.x;     // 256

    __shared__ float s_rows[2][4 * CW];  // 2 x 13.8 KB double buffer
    __shared__ float s_pair[NPAIR];
    __shared__ int   s_idx[NPAIR];
    __shared__ float s_mapw[NND * 16];
    __shared__ float s_rr[144];
    __shared__ float s_pe[NBATCH * 16];
    __shared__ float s_binc[32];

    for (int i = tid; i < NPAIR; i += 256) s_idx[i] = idxarr[i];
    for (int i = tid; i < NND * 16; i += 256) s_mapw[i] = mapw[i];
    if (tid < 144) s_rr[tid] = rr[tid];
    if (tid < 128) { int b = tid >> 4, s = tid & 15; s_pe[tid] = pe[((size_t)(b * LMAX + t)) * DPE + s]; }
    if (tid < 32) s_binc[tid] = binc[32 * t + tid];

    float acc[7];
#pragma unroll
    for (int pp = 0; pp < 7; ++pp) acc[pp] = 0.f;

    float4 pre[4];
    {
        const float4* src = (const float4*)(Winc + (size_t)(32 * t) * CW);
#pragma unroll
        for (int i = 0; i < 4; ++i) { int k = tid + i * 256; if (k < CW) pre[i] = src[k]; }
    }
    int p = 0;
    for (int jc = 0; jc < 8; ++jc) {
        float4* buf = (float4*)&s_rows[p][0];
#pragma unroll
        for (int i = 0; i < 4; ++i) { int k = tid + i * 256; if (k < CW) buf[k] = pre[i]; }
        __syncthreads();
        if (jc < 7) {
            const float4* src = (const float4*)(Winc + (size_t)(32 * t + 4 * (jc + 1)) * CW);
#pragma unroll
            for (int i = 0; i < 4; ++i) { int k = tid + i * 256; if (k < CW) pre[i] = src[k]; }
        }
#pragma unroll
        for (int pp = 0; pp < 7; ++pp) {
            int pr = tid + pp * 256;
            if (pr < NPAIR) {
                int b = pr / LMAX, l = pr - b * LMAX;
                int n = s_idx[pr];
                float4 r4 = *(const float4*)&s_rr[4 * n];
                float a = acc[pp];
#pragma unroll
                for (int jj = 0; jj < 4; ++jj) {
                    int j = 4 * jc + jj;
                    float4 w4 = *(const float4*)&s_rows[p][jj * CW + 4 * l];
                    float dv = r4.x * w4.x + r4.y * w4.y + r4.z * w4.z + r4.w * w4.w;
                    float coeff = (j < 16) ? s_mapw[n * 16 + j] : s_pe[(b << 4) + (j - 16)];
                    a += coeff * dv;
                }
                acc[pp] = a;
            }
        }
        p ^= 1;
    }
    __syncthreads();

#pragma unroll
    for (int pp = 0; pp < 7; ++pp) {
        int pr = tid + pp * 256;
        if (pr < NPAIR) s_pair[pr] = acc[pp];
    }
    __syncthreads();

    if (tid < NBATCH * NND) {
        int b = tid / NND, n = tid - b * NND;
        int base = b * LMAX;
        float sum = 0.f;
        for (int l = 0; l < LMAX; ++l)
            if (s_idx[base + l] == n) sum += s_pair[base + l];
        float bias = 0.f;
#pragma unroll
        for (int s = 0; s < 16; ++s)
            bias += s_mapw[n * 16 + s] * s_binc[s] + s_pe[(b << 4) + s] * s_binc[16 + s];
        beta[((size_t)b * NND + n) * LMAX + t] = (sum + bias) * (1.0f / 32.0f);
    }
}

// ---------------------------------------------------------------- mean over t (deterministic)
__global__ void k_meanb(const float* __restrict__ beta, float* __restrict__ meanb) {
    int bn = blockIdx.x;       // 288
    int lane = threadIdx.x;    // 64
    const float* p = beta + (size_t)bn * LMAX;
    float s = 0.f;
    for (int t = lane; t < LMAX; t += 64) s += p[t];
    for (int off = 32; off > 0; off >>= 1) s += __shfl_xor(s, off);
    if (lane == 0) meanb[bn] = s / (float)LMAX;
}

// ---------------------------------------------------------------- stable top-K via rank selection
__global__ __launch_bounds__(256) void k_topk(const float* __restrict__ ew,
                                              const float* __restrict__ meanb,
                                              int* __restrict__ topi, float* __restrict__ alpha) {
    int chunk = blockIdx.x;    // 0..5  (216 elements each)
    int b = blockIdx.y;        // 0..7
    int tid = threadIdx.x;     // 256
    __shared__ float sv[NE];
    __shared__ float sm[NND];
    if (tid < NND) sm[tid] = meanb[b * NND + tid];
    __syncthreads();
    for (int e = tid; e < NE; e += 256) sv[e] = ew[e] * sm[e % NND];
    __syncthreads();
    int e = chunk * 216 + tid;
    if (tid < 216) {
        float v = sv[e];
        int rank = 0;
        for (int i = 0; i < NE; ++i) {
            float u = sv[i];
            rank += (u > v) || (u == v && i < e);
        }
        if (rank < NK) {
            topi[b * NK + rank] = e;
            alpha[b * NK + rank] = v;
        }
    }
}

// ---------------------------------------------------------------- message passing layer 1
__global__ void k_h1(const int* __restrict__ topi, const float* __restrict__ ew,
                     const float* __restrict__ beta, const int* __restrict__ idxarr,
                     const float* __restrict__ rr, float* h1) {
    int b = blockIdx.x / NND, n = blockIdx.x % NND;
    __shared__ int cnt;
    __shared__ int lsrc[40];
    __shared__ float lew[40];
    int tid = threadIdx.x;  // 256
    if (tid == 0) cnt = 0;
    __syncthreads();
    for (int k = tid; k < NK; k += 256) {
        int e = topi[b * NK + k];
        if (e % NND == n) {
            int p = atomicAdd(&cnt, 1);
            lsrc[p] = e / NND;
            lew[p] = ew[e];
        }
    }
    __syncthreads();
    int m = cnt;
    const float* bb = beta + ((size_t)b * NND + n) * LMAX;
    for (int c = tid; c < CW; c += 256) {
        int t = c >> 2, o = c & 3;
        float bt = bb[t];
        int id = idxarr[b * LMAX + t];
        float x = rr[id * 4 + o];
        float acc = 0.f;
        for (int j = 0; j < m; ++j) {
            float g = bt * lew[j];
            if (g > 0.f && lsrc[j] == id) acc += x * g;
        }
        h1[((size_t)b * NND + n) * CW + c] = acc;
    }
}

// ---------------------------------------------------------------- message passing layer 2
__global__ void k_h2(const int* __restrict__ topi, const float* __restrict__ alpha,
                     const float* __restrict__ h1, float* h2) {
    int b = blockIdx.x / NND, n = blockIdx.x % NND;
    __shared__ int cnt;
    __shared__ int lsrc[40];
    __shared__ float lal[40];
    int tid = threadIdx.x;
    if (tid == 0) cnt = 0;
    __syncthreads();
    for (int k = tid; k < NK; k += 256) {
        int e = topi[b * NK + k];
        if (e % NND == n) {
            int p = atomicAdd(&cnt, 1);
            lsrc[p] = e / NND;
            lal[p] = fmaxf(alpha[b * NK + k], 0.f);
        }
    }
    __syncthreads();
    int m = cnt;
    for (int c = tid; c < CW; c += 256) {
        float acc = 0.f;
        for (int j = 0; j < m; ++j)
            acc += fmaxf(h1[((size_t)b * NND + lsrc[j]) * CW + c], 0.f) * lal[j];
        h2[((size_t)b * NND + n) * CW + c] = acc;
    }
}

// ---------------------------------------------------------------- assemble transformer input
__global__ void k_x0(const float* __restrict__ h2, const float* __restrict__ pe, float* x) {
    int i = blockIdx.x * 256 + threadIdx.x;
    if (i >= NBATCH * LMAX * DTR) return;
    int ch = i % DTR; int bl = i / DTR; int l = bl % LMAX; int b = bl / LMAX;
    float v;
    if (ch < 144) {
        int n = ch >> 2, o = ch & 3;
        v = h2[((size_t)b * NND + n) * CW + 4 * l + o];
    } else {
        v = pe[(b * LMAX + l) * DPE + (ch - 144)];
    }
    x[i] = v;
}

// ---------------------------------------------------------------- distance
__global__ void k_dist(const float* __restrict__ alpha, float* outd) {
    __shared__ float s[64];
    int tid = threadIdx.x;  // 64
    int i = tid / 8, j = tid % 8;
    float d2 = 0.f;
    for (int k = 0; k < NK; ++k) {
        float d = alpha[i * NK + k] - alpha[j * NK + k];
        d2 += d * d;
    }
    s[tid] = (d2 > 0.f) ? sqrtf(d2) : 0.f;
    __syncthreads();
    for (int st = 32; st > 0; st >>= 1) { if (tid < st) s[tid] += s[tid + st]; __syncthreads(); }
    if (tid == 0) *outd = s[0] / 64.0f;
}

// ---------------------------------------------------------------- 8-row tiled qkv GEMM (512 thr)
__global__ __launch_bounds__(512) void k_gemm8(const float* __restrict__ X, const float* __restrict__ W,
                                               const float* __restrict__ bias, float* __restrict__ Y) {
    int m0 = blockIdx.x * 8;
    int tid = threadIdx.x;  // 512
    __shared__ float xs[8 * DTR];
    for (int i = tid; i < 8 * DTR; i += 512) xs[i] = X[(size_t)m0 * DTR + i];
    __syncthreads();
    int n = tid;
    if (n >= 480) return;
    const float* wr = W + (size_t)n * DTR;
    float acc[8];
    float bv = bias[n];
#pragma unroll
    for (int r = 0; r < 8; ++r) acc[r] = bv;
    for (int d = 0; d < DTR; d += 4) {
        float4 w4 = *(const float4*)(wr + d);
#pragma unroll
        for (int r = 0; r < 8; ++r) {
            float4 x4 = *(const float4*)&xs[r * DTR + d];
            acc[r] += x4.x * w4.x + x4.y * w4.y + x4.z * w4.z + x4.w * w4.w;
        }
    }
#pragma unroll
    for (int r = 0; r < 8; ++r) Y[(size_t)(m0 + r) * 480 + n] = acc[r];
}

// ---------------------------------------------------------------- attention (one wave per (b,h,q))
__global__ void k_attn(const float* __restrict__ qkv, const int* __restrict__ lens,
                       float* __restrict__ ctx) {
    int gid = blockIdx.x;
    int q = gid % LMAX; int bh = gid / LMAX; int h = bh % NHEADS; int b = bh / NHEADS;
    int lane = threadIdx.x;  // 64
    __shared__ float sp[LMAX];
    __shared__ float sq[DH];
    const float* qrow = qkv + ((size_t)(b * LMAX + q) * 480) + h * DH;
    if (lane < DH) sq[lane] = qrow[lane];
    __syncthreads();
    int len = lens[b];
    const float scale = 0.15811388300841898f;  // 1/sqrt(40)
    float lmax = -INFINITY;
    for (int k = lane; k < LMAX; k += 64) {
        const float* krow = qkv + ((size_t)(b * LMAX + k) * 480) + DTR + h * DH;
        float s = 0.f;
#pragma unroll 8
        for (int d = 0; d < DH; ++d) s += sq[d] * krow[d];
        s *= scale;
        if (k >= len) s = -1e9f;
        sp[k] = s;
        lmax = fmaxf(lmax, s);
    }
    for (int off = 32; off > 0; off >>= 1) lmax = fmaxf(lmax, __shfl_xor(lmax, off));
    float lsum = 0.f;
    for (int k = lane; k < LMAX; k += 64) {
        float e = expf(sp[k] - lmax);
        sp[k] = e;
        lsum += e;
    }
    for (int off = 32; off > 0; off >>= 1) lsum += __shfl_xor(lsum, off);
    float inv = 1.0f / lsum;
    __syncthreads();
    if (lane < DH) {
        float acc = 0.f;
        for (int k = 0; k < LMAX; ++k)
            acc += sp[k] * qkv[((size_t)(b * LMAX + k) * 480) + 2 * DTR + h * DH + lane];
        ctx[((size_t)(b * LMAX + q) * DTR) + h * DH + lane] = acc * inv;
    }
}

// ---------------------------------------------------------------- device LN helper (per-wave over one row in LDS)
__device__ __forceinline__ void wave_ln_row(const float* __restrict__ row, int lane,
                                            const float* __restrict__ lnw, const float* __restrict__ lnb,
                                            float* __restrict__ dst) {
    float s = 0.f;
    for (int d = lane; d < DTR; d += 64) s += row[d];
    for (int off = 32; off > 0; off >>= 1) s += __shfl_xor(s, off);
    float mu = s / (float)DTR;
    float v = 0.f;
    for (int d = lane; d < DTR; d += 64) { float dd = row[d] - mu; v += dd * dd; }
    for (int off = 32; off > 0; off >>= 1) v += __shfl_xor(v, off);
    float rs = rsqrtf(v / (float)DTR + 1e-5f);
    for (int d = lane; d < DTR; d += 64)
        dst[d] = (row[d] - mu) * rs * lnw[d] + lnb[d];
}

// ---------------------------------------------------------------- fused out-proj + residual + LN1 (8 rows, 512 thr)
__global__ __launch_bounds__(512) void k_projln(const float* __restrict__ ctx, const float* __restrict__ xres,
                                                const float* __restrict__ W, const float* __restrict__ bias,
                                                const float* __restrict__ lnw, const float* __restrict__ lnb,
                                                float* __restrict__ out) {
    int m0 = blockIdx.x * 8;
    int tid = threadIdx.x;  // 512
    __shared__ float xs[8 * DTR];
    __shared__ float ys[8 * DTR];
    for (int i = tid; i < 8 * DTR; i += 512) xs[i] = ctx[(size_t)m0 * DTR + i];
    __syncthreads();
    for (int o = tid; o < 8 * DTR; o += 512) {
        int r = o / DTR, n = o - r * DTR;
        const float* wr = W + (size_t)n * DTR;
        float4 av = {0.f, 0.f, 0.f, 0.f};
#pragma unroll 8
        for (int d = 0; d < DTR; d += 4) {
            float4 w4 = *(const float4*)(wr + d);
            float4 x4 = *(const float4*)&xs[r * DTR + d];
            av.x += x4.x * w4.x; av.y += x4.y * w4.y; av.z += x4.z * w4.z; av.w += x4.w * w4.w;
        }
        ys[o] = bias[n] + (av.x + av.y) + (av.z + av.w) + xres[(size_t)(m0 + r) * DTR + n];
    }
    __syncthreads();
    int wid = tid >> 6, lane = tid & 63;
    if (wid < 8)
        wave_ln_row(&ys[wid * DTR], lane, lnw, lnb, out + (size_t)(m0 + wid) * DTR);
}

// ---------------------------------------------------------------- fused FF1+relu+FF2 + residual + LN2 (8 rows, 512 thr)
__global__ __launch_bounds__(512) void k_ffln(const float* __restrict__ xin,
                                              const float* __restrict__ W1, const float* __restrict__ b1,
                                              const float* __restrict__ W2, const float* __restrict__ b2,
                                              const float* __restrict__ lnw, const float* __restrict__ lnb,
                                              float* __restrict__ out) {
    int m0 = blockIdx.x * 8;
    int tid = threadIdx.x;  // 512
    __shared__ float xs[8 * DTR];    // 5 KB
    __shared__ float hs[8 * NHID2];  // 8 KB
    __shared__ float zs[8 * DTR];    // 5 KB
    for (int i = tid; i < 8 * DTR; i += 512) xs[i] = xin[(size_t)m0 * DTR + i];
    __syncthreads();
    for (int o = tid; o < 8 * NHID2; o += 512) {
        int r = o >> 8, n = o & 255;
        const float* wr = W1 + (size_t)n * DTR;
        float4 av = {0.f, 0.f, 0.f, 0.f};
#pragma unroll 8
        for (int d = 0; d < DTR; d += 4) {
            float4 w4 = *(const float4*)(wr + d);
            float4 x4 = *(const float4*)&xs[r * DTR + d];
            av.x += x4.x * w4.x; av.y += x4.y * w4.y; av.z += x4.z * w4.z; av.w += x4.w * w4.w;
        }
        hs[o] = fmaxf(b1[n] + (av.x + av.y) + (av.z + av.w), 0.f);
    }
    __syncthreads();
    for (int o = tid; o < 8 * DTR; o += 512) {
        int r = o / DTR, n = o - r * DTR;
        const float* wr = W2 + (size_t)n * NHID2;
        float4 av = {0.f, 0.f, 0.f, 0.f};
#pragma unroll 8
        for (int d = 0; d < NHID2; d += 4) {
            float4 w4 = *(const float4*)(wr + d);
            float4 h4 = *(const float4*)&hs[r * NHID2 + d];
            av.x += h4.x * w4.x; av.y += h4.y * w4.y; av.z += h4.z * w4.z; av.w += h4.w * w4.w;
        }
        zs[o] = b2[n] + (av.x + av.y) + (av.z + av.w) + xs[o];
    }
    __syncthreads();
    int wid = tid >> 6, lane = tid & 63;
    if (wid < 8)
        wave_ln_row(&zs[wid * DTR], lane, lnw, lnb, out + (size_t)(m0 + wid) * DTR);
}

// ---------------------------------------------------------------- final: copy output + preds
__global__ void k_pred(const float* __restrict__ x, const float* __restrict__ wty,
                       const float* __restrict__ wti, const int* __restrict__ lens,
                       float* __restrict__ out) {
    int row = blockIdx.x; int b = row / LMAX; int l = row % LMAX;
    __shared__ float xs[DTR];
    int tid = threadIdx.x;  // 64
    for (int d = tid; d < DTR; d += 64) xs[d] = x[(size_t)row * DTR + d];
    __syncthreads();
    float np = (l < lens[b]) ? 1.f : 0.f;
    if (tid < 37) {
        const float* w = (tid < 36) ? (wty + tid * DTR) : wti;
        float acc = 0.f;
#pragma unroll 8
        for (int d = 0; d < DTR; d += 4) {
            float4 w4 = *(const float4*)(w + d);
            acc += xs[d] * w4.x + xs[d + 1] * w4.y + xs[d + 2] * w4.z + xs[d + 3] * w4.w;
        }
        acc *= np;
        if (tid < 36) out[OUT_TYPE + (size_t)row * NND + tid] = acc;
        else out[OUT_TIME + row] = acc;
    }
    for (int d = tid; d < DTR; d += 64) out[(size_t)row * DTR + d] = xs[d];
}

// ---------------------------------------------------------------- launch
extern "C" void kernel_launch(void* const* d_in, const int* in_sizes, int n_in,
                              void* d_out, int out_size, void* d_ws, size_t ws_size,
                              hipStream_t stream) {
    const int* et      = (const int*)d_in[0];
    const float* etime = (const float*)d_in[1];
    const float* Ru    = (const float*)d_in[2];
    const float* gs    = (const float*)d_in[3];
    const float* Winc  = (const float*)d_in[4];
    const float* binc  = (const float*)d_in[5];
    const float* mapw  = (const float*)d_in[6];
    const float* wtime = (const float*)d_in[7];
    const float* wtype = (const float*)d_in[8];

    float* ws   = (float*)d_ws;
    float* pe   = ws + OFF_PE;
    float* rr   = ws + OFF_RR;
    float* ew   = ws + OFF_EW;
    float* beta = ws + OFF_BETA;
    float* meanb= ws + OFF_MEANB;
    float* alpha= ws + OFF_ALPHA;
    float* h1   = ws + OFF_H1;
    float* h2   = ws + OFF_H2;
    float* x    = ws + OFF_X;
    float* x2   = ws + OFF_X2;
    float* qkvb = ws + OFF_QKV;
    float* ctx  = ws + OFF_CTX;
    int* topi   = (int*)(ws + OFF_TOPI);
    int* idxarr = (int*)(ws + OFF_IDX);
    int* lens   = (int*)(ws + OFF_LENS);
    float* outp = (float*)d_out;

    k_prep<<<73, 256, 0, stream>>>(et, etime, Ru, gs, pe, rr, ew, idxarr, lens);
    k_beta<<<LMAX, 256, 0, stream>>>(Winc, binc, mapw, pe, rr, idxarr, beta);
    k_meanb<<<NBATCH * NND, 64, 0, stream>>>(beta, meanb);
    k_topk<<<dim3(6, NBATCH), 256, 0, stream>>>(ew, meanb, topi, alpha);
    k_h1<<<NBATCH * NND, 256, 0, stream>>>(topi, ew, beta, idxarr, rr, h1);
    k_h2<<<NBATCH * NND, 256, 0, stream>>>(topi, alpha, h1, h2);
    k_x0<<<(NBATCH * LMAX * DTR + 255) / 256, 256, 0, stream>>>(h2, pe, x);
    k_dist<<<1, 64, 0, stream>>>(alpha, outp + OUT_DIST);

    const int MB = NPAIR / 8;  // 215 row-tiles
    for (int layer = 0; layer < 2; ++layer) {
        int base = 9 + layer * 12;
        const float* qkv_w = (const float*)d_in[base + 0];
        const float* qkv_b = (const float*)d_in[base + 1];
        const float* out_w = (const float*)d_in[base + 2];
        const float* out_b = (const float*)d_in[base + 3];
        const float* ff1_w = (const float*)d_in[base + 4];
        const float* ff1_b = (const float*)d_in[base + 5];
        const float* ff2_w = (const float*)d_in[base + 6];
        const float* ff2_b = (const float*)d_in[base + 7];
        const float* ln1_w = (const float*)d_in[base + 8];
        const float* ln1_b = (const float*)d_in[base + 9];
        const float* ln2_w = (const float*)d_in[base + 10];
        const float* ln2_b = (const float*)d_in[base + 11];

        k_gemm8<<<MB, 512, 0, stream>>>(x, qkv_w, qkv_b, qkvb);
        k_attn<<<NBATCH * NHEADS * LMAX, 64, 0, stream>>>(qkvb, lens, ctx);
        k_projln<<<MB, 512, 0, stream>>>(ctx, x, out_w, out_b, ln1_w, ln1_b, x2);
        k_ffln<<<MB, 512, 0, stream>>>(x2, ff1_w, ff1_b, ff2_w, ff2_b, ln2_w, ln2_b, x);
    }

    k_pred<<<NPAIR, 64, 0, stream>>>(x, wtype, wtime, lens, outp);
}

// Round 6
// 572.364 us; speedup vs baseline: 2.3940x; 1.0874x over previous
//
#include <hip/hip_runtime.h>
#include <math.h>

#define NBATCH 8
#define LMAX   215
#define NND    36
#define NE     1296
#define NK     648
#define CW     860      // C = LMAX*4
#define DPE    16
#define DTR    160
#define NHEADS 4
#define DH     40
#define NHID2  256
#define NPAIR  (NBATCH*LMAX)   // 1720

// output layout (floats)
#define OUT_TYPE (NBATCH*LMAX*DTR)              // 275200
#define OUT_TIME (OUT_TYPE + NBATCH*LMAX*NND)   // 337120
#define OUT_DIST (OUT_TIME + NBATCH*LMAX)       // 338840

// workspace layout (float offsets)
#define OFF_PE    0
#define OFF_RR    (OFF_PE + NBATCH*LMAX*DPE)
#define OFF_EW    (OFF_RR + 144)
#define OFF_BETA  (OFF_EW + NE)
#define OFF_MEANB (OFF_BETA + NBATCH*NND*LMAX)
#define OFF_ALPHA (OFF_MEANB + NBATCH*NND)
#define OFF_H1    (OFF_ALPHA + NBATCH*NK)
#define OFF_H2    (OFF_H1 + NBATCH*NND*CW)
#define OFF_X     (OFF_H2 + NBATCH*NND*CW)
#define OFF_X2    (OFF_X + NBATCH*LMAX*DTR)
#define OFF_QKV   (OFF_X2 + NBATCH*LMAX*DTR)
#define OFF_CTX   (OFF_QKV + NBATCH*LMAX*480)
#define OFF_TOPI  (OFF_CTX + NBATCH*LMAX*DTR)
#define OFF_IDX   (OFF_TOPI + NBATCH*NK)
#define OFF_LENS  (OFF_IDX + NBATCH*LMAX)

// ---------------------------------------------------------------- prep (parallel: 73 blocks)
__global__ __launch_bounds__(256) void k_prep(
        const int* __restrict__ et, const float* __restrict__ etime,
        const float* __restrict__ Ru, const float* __restrict__ gs,
        float* pe, float* rr, float* ew, int* idxarr, int* lens) {
    int blk = blockIdx.x, tid = threadIdx.x;
    if (blk == 0) {
        for (int c = tid; c < 144; c += 256) rr[c] = fmaxf(Ru[c], 0.f);
        for (int e = tid; e < NE; e += 256) {
            int r = e / NND, cc = e % NND;
            ew[e] = (r == cc) ? 1.0f : gs[e];
        }
    } else if (blk <= 8) {
        int b = blk - 1;
        __shared__ int red[256];
        int cnt = 0;
        for (int l = tid; l < LMAX; l += 256) {
            int v = et[b * LMAX + l];
            cnt += (v != 0);
            idxarr[b * LMAX + l] = max(v - 1, 0);
        }
        red[tid] = cnt;
        __syncthreads();
        for (int st = 128; st > 0; st >>= 1) { if (tid < st) red[tid] += red[tid + st]; __syncthreads(); }
        if (tid == 0) lens[b] = red[0];
    } else {
        __shared__ float sts[8];
        if (tid < 8) sts[tid] = (float)pow(215.0, (double)tid / 7.0);
        __syncthreads();
        int i0 = (blk - 9) * 430;
        for (int i = i0 + tid; i < i0 + 430; i += 256) {
            int s = i & 15; int bl = i >> 4;
            float t = etime[bl];
            float sc = t / sts[s & 7];
            pe[i] = (s < 8) ? sinf(sc) : cosf(sc);
        }
    }
}

// ---------------------------------------------------------------- beta (block per t; double-buffered Winc tiles)
__global__ __launch_bounds__(256) void k_beta(
        const float* __restrict__ Winc, const float* __restrict__ binc,
        const float* __restrict__ mapw, const float* __restrict__ pe,
        const float* __restrict__ rr, const int* __restrict__ idxarr,
        float* __restrict__ beta) {
    const int t = blockIdx.x;        // 0..214
    const int tid = threadIdx.x;     // 256

    __shared__ float s_rows[2][4 * CW];
    __shared__ float s_pair[NPAIR];
    __shared__ int   s_idx[NPAIR];
    __shared__ float s_mapw[NND * 16];
    __shared__ float s_rr[144];
    __shared__ float s_pe[NBATCH * 16];
    __shared__ float s_binc[32];

    for (int i = tid; i < NPAIR; i += 256) s_idx[i] = idxarr[i];
    for (int i = tid; i < NND * 16; i += 256) s_mapw[i] = mapw[i];
    if (tid < 144) s_rr[tid] = rr[tid];
    if (tid < 128) { int b = tid >> 4, s = tid & 15; s_pe[tid] = pe[((size_t)(b * LMAX + t)) * DPE + s]; }
    if (tid < 32) s_binc[tid] = binc[32 * t + tid];

    float acc[7];
#pragma unroll
    for (int pp = 0; pp < 7; ++pp) acc[pp] = 0.f;

    float4 pre[4];
    {
        const float4* src = (const float4*)(Winc + (size_t)(32 * t) * CW);
#pragma unroll
        for (int i = 0; i < 4; ++i) { int k = tid + i * 256; if (k < CW) pre[i] = src[k]; }
    }
    int p = 0;
    for (int jc = 0; jc < 8; ++jc) {
        float4* buf = (float4*)&s_rows[p][0];
#pragma unroll
        for (int i = 0; i < 4; ++i) { int k = tid + i * 256; if (k < CW) buf[k] = pre[i]; }
        __syncthreads();
        if (jc < 7) {
            const float4* src = (const float4*)(Winc + (size_t)(32 * t + 4 * (jc + 1)) * CW);
#pragma unroll
            for (int i = 0; i < 4; ++i) { int k = tid + i * 256; if (k < CW) pre[i] = src[k]; }
        }
#pragma unroll
        for (int pp = 0; pp < 7; ++pp) {
            int pr = tid + pp * 256;
            if (pr < NPAIR) {
                int b = pr / LMAX, l = pr - b * LMAX;
                int n = s_idx[pr];
                float4 r4 = *(const float4*)&s_rr[4 * n];
                float a = acc[pp];
#pragma unroll
                for (int jj = 0; jj < 4; ++jj) {
                    int j = 4 * jc + jj;
                    float4 w4 = *(const float4*)&s_rows[p][jj * CW + 4 * l];
                    float dv = r4.x * w4.x + r4.y * w4.y + r4.z * w4.z + r4.w * w4.w;
                    float coeff = (j < 16) ? s_mapw[n * 16 + j] : s_pe[(b << 4) + (j - 16)];
                    a += coeff * dv;
                }
                acc[pp] = a;
            }
        }
        p ^= 1;
    }
    __syncthreads();

#pragma unroll
    for (int pp = 0; pp < 7; ++pp) {
        int pr = tid + pp * 256;
        if (pr < NPAIR) s_pair[pr] = acc[pp];
    }
    __syncthreads();

    if (tid < NBATCH * NND) {
        int b = tid / NND, n = tid - b * NND;
        int base = b * LMAX;
        float sum = 0.f;
        for (int l = 0; l < LMAX; ++l)
            if (s_idx[base + l] == n) sum += s_pair[base + l];
        float bias = 0.f;
#pragma unroll
        for (int s = 0; s < 16; ++s)
            bias += s_mapw[n * 16 + s] * s_binc[s] + s_pe[(b << 4) + s] * s_binc[16 + s];
        beta[((size_t)b * NND + n) * LMAX + t] = (sum + bias) * (1.0f / 32.0f);
    }
}

// ---------------------------------------------------------------- mean over t (deterministic)
__global__ void k_meanb(const float* __restrict__ beta, float* __restrict__ meanb) {
    int bn = blockIdx.x;       // 288
    int lane = threadIdx.x;    // 64
    const float* p = beta + (size_t)bn * LMAX;
    float s = 0.f;
    for (int t = lane; t < LMAX; t += 64) s += p[t];
    for (int off = 32; off > 0; off >>= 1) s += __shfl_xor(s, off);
    if (lane == 0) meanb[bn] = s / (float)LMAX;
}

// ---------------------------------------------------------------- stable top-K via rank selection
__global__ __launch_bounds__(256) void k_topk(const float* __restrict__ ew,
                                              const float* __restrict__ meanb,
                                              int* __restrict__ topi, float* __restrict__ alpha) {
    int chunk = blockIdx.x;    // 0..5  (216 elements each)
    int b = blockIdx.y;        // 0..7
    int tid = threadIdx.x;     // 256
    __shared__ float sv[NE];
    __shared__ float sm[NND];
    if (tid < NND) sm[tid] = meanb[b * NND + tid];
    __syncthreads();
    for (int e = tid; e < NE; e += 256) sv[e] = ew[e] * sm[e % NND];
    __syncthreads();
    int e = chunk * 216 + tid;
    if (tid < 216) {
        float v = sv[e];
        int rank = 0;
        for (int i = 0; i < NE; ++i) {
            float u = sv[i];
            rank += (u > v) || (u == v && i < e);
        }
        if (rank < NK) {
            topi[b * NK + rank] = e;
            alpha[b * NK + rank] = v;
        }
    }
}

// ---------------------------------------------------------------- message passing layer 1
__global__ void k_h1(const int* __restrict__ topi, const float* __restrict__ ew,
                     const float* __restrict__ beta, const int* __restrict__ idxarr,
                     const float* __restrict__ rr, float* h1) {
    int b = blockIdx.x / NND, n = blockIdx.x % NND;
    __shared__ int cnt;
    __shared__ int lsrc[40];
    __shared__ float lew[40];
    int tid = threadIdx.x;  // 256
    if (tid == 0) cnt = 0;
    __syncthreads();
    for (int k = tid; k < NK; k += 256) {
        int e = topi[b * NK + k];
        if (e % NND == n) {
            int p = atomicAdd(&cnt, 1);
            lsrc[p] = e / NND;
            lew[p] = ew[e];
        }
    }
    __syncthreads();
    int m = cnt;
    const float* bb = beta + ((size_t)b * NND + n) * LMAX;
    for (int c = tid; c < CW; c += 256) {
        int t = c >> 2, o = c & 3;
        float bt = bb[t];
        int id = idxarr[b * LMAX + t];
        float x = rr[id * 4 + o];
        float acc = 0.f;
        for (int j = 0; j < m; ++j) {
            float g = bt * lew[j];
            if (g > 0.f && lsrc[j] == id) acc += x * g;
        }
        h1[((size_t)b * NND + n) * CW + c] = acc;
    }
}

// ---------------------------------------------------------------- message passing layer 2
__global__ void k_h2(const int* __restrict__ topi, const float* __restrict__ alpha,
                     const float* __restrict__ h1, float* h2) {
    int b = blockIdx.x / NND, n = blockIdx.x % NND;
    __shared__ int cnt;
    __shared__ int lsrc[40];
    __shared__ float lal[40];
    int tid = threadIdx.x;
    if (tid == 0) cnt = 0;
    __syncthreads();
    for (int k = tid; k < NK; k += 256) {
        int e = topi[b * NK + k];
        if (e % NND == n) {
            int p = atomicAdd(&cnt, 1);
            lsrc[p] = e / NND;
            lal[p] = fmaxf(alpha[b * NK + k], 0.f);
        }
    }
    __syncthreads();
    int m = cnt;
    for (int c = tid; c < CW; c += 256) {
        float acc = 0.f;
        for (int j = 0; j < m; ++j)
            acc += fmaxf(h1[((size_t)b * NND + lsrc[j]) * CW + c], 0.f) * lal[j];
        h2[((size_t)b * NND + n) * CW + c] = acc;
    }
}

// ---------------------------------------------------------------- assemble transformer input
__global__ void k_x0(const float* __restrict__ h2, const float* __restrict__ pe, float* x) {
    int i = blockIdx.x * 256 + threadIdx.x;
    if (i >= NBATCH * LMAX * DTR) return;
    int ch = i % DTR; int bl = i / DTR; int l = bl % LMAX; int b = bl / LMAX;
    float v;
    if (ch < 144) {
        int n = ch >> 2, o = ch & 3;
        v = h2[((size_t)b * NND + n) * CW + 4 * l + o];
    } else {
        v = pe[(b * LMAX + l) * DPE + (ch - 144)];
    }
    x[i] = v;
}

// ---------------------------------------------------------------- distance
__global__ void k_dist(const float* __restrict__ alpha, float* outd) {
    __shared__ float s[64];
    int tid = threadIdx.x;  // 64
    int i = tid / 8, j = tid % 8;
    float d2 = 0.f;
    for (int k = 0; k < NK; ++k) {
        float d = alpha[i * NK + k] - alpha[j * NK + k];
        d2 += d * d;
    }
    s[tid] = (d2 > 0.f) ? sqrtf(d2) : 0.f;
    __syncthreads();
    for (int st = 32; st > 0; st >>= 1) { if (tid < st) s[tid] += s[tid + st]; __syncthreads(); }
    if (tid == 0) *outd = s[0] / 64.0f;
}

// ---------------------------------------------------------------- qkv GEMM: 2 rows/block, 256 thr
__global__ __launch_bounds__(256) void k_qkv(const float* __restrict__ X, const float* __restrict__ W,
                                             const float* __restrict__ bias, float* __restrict__ Y) {
    int m0 = blockIdx.x * 2;
    int tid = threadIdx.x;
    __shared__ float xs[2 * DTR];
    for (int i = tid; i < 2 * DTR; i += 256) xs[i] = X[(size_t)m0 * DTR + i];
    __syncthreads();
    for (int n = tid; n < 480; n += 256) {
        const float* wr = W + (size_t)n * DTR;
        float4 a0 = {0.f, 0.f, 0.f, 0.f};
        float4 a1 = {0.f, 0.f, 0.f, 0.f};
#pragma unroll 8
        for (int d = 0; d < DTR; d += 4) {
            float4 w4 = *(const float4*)(wr + d);
            float4 x0 = *(const float4*)&xs[d];
            float4 x1 = *(const float4*)&xs[DTR + d];
            a0.x += x0.x * w4.x; a0.y += x0.y * w4.y; a0.z += x0.z * w4.z; a0.w += x0.w * w4.w;
            a1.x += x1.x * w4.x; a1.y += x1.y * w4.y; a1.z += x1.z * w4.z; a1.w += x1.w * w4.w;
        }
        float bv = bias[n];
        Y[(size_t)m0 * 480 + n]       = bv + (a0.x + a0.y) + (a0.z + a0.w);
        Y[(size_t)(m0 + 1) * 480 + n] = bv + (a1.x + a1.y) + (a1.z + a1.w);
    }
}

// ---------------------------------------------------------------- attention (one wave per (b,h,q))
__global__ void k_attn(const float* __restrict__ qkv, const int* __restrict__ lens,
                       float* __restrict__ ctx) {
    int gid = blockIdx.x;
    int q = gid % LMAX; int bh = gid / LMAX; int h = bh % NHEADS; int b = bh / NHEADS;
    int lane = threadIdx.x;  // 64
    __shared__ float sp[LMAX];
    __shared__ float sq[DH];
    const float* qrow = qkv + ((size_t)(b * LMAX + q) * 480) + h * DH;
    if (lane < DH) sq[lane] = qrow[lane];
    __syncthreads();
    int len = lens[b];
    const float scale = 0.15811388300841898f;  // 1/sqrt(40)
    float lmax = -INFINITY;
    for (int k = lane; k < LMAX; k += 64) {
        const float* krow = qkv + ((size_t)(b * LMAX + k) * 480) + DTR + h * DH;
        float s = 0.f;
#pragma unroll 8
        for (int d = 0; d < DH; ++d) s += sq[d] * krow[d];
        s *= scale;
        if (k >= len) s = -1e9f;
        sp[k] = s;
        lmax = fmaxf(lmax, s);
    }
    for (int off = 32; off > 0; off >>= 1) lmax = fmaxf(lmax, __shfl_xor(lmax, off));
    float lsum = 0.f;
    for (int k = lane; k < LMAX; k += 64) {
        float e = expf(sp[k] - lmax);
        sp[k] = e;
        lsum += e;
    }
    for (int off = 32; off > 0; off >>= 1) lsum += __shfl_xor(lsum, off);
    float inv = 1.0f / lsum;
    __syncthreads();
    if (lane < DH) {
        float acc = 0.f;
        for (int k = 0; k < LMAX; ++k)
            acc += sp[k] * qkv[((size_t)(b * LMAX + k) * 480) + 2 * DTR + h * DH + lane];
        ctx[((size_t)(b * LMAX + q) * DTR) + h * DH + lane] = acc * inv;
    }
}

// ---------------------------------------------------------------- device LN helper (per-wave over one row in LDS)
__device__ __forceinline__ void wave_ln_row(const float* __restrict__ row, int lane,
                                            const float* __restrict__ lnw, const float* __restrict__ lnb,
                                            float* __restrict__ dst) {
    float s = 0.f;
    for (int d = lane; d < DTR; d += 64) s += row[d];
    for (int off = 32; off > 0; off >>= 1) s += __shfl_xor(s, off);
    float mu = s / (float)DTR;
    float v = 0.f;
    for (int d = lane; d < DTR; d += 64) { float dd = row[d] - mu; v += dd * dd; }
    for (int off = 32; off > 0; off >>= 1) v += __shfl_xor(v, off);
    float rs = rsqrtf(v / (float)DTR + 1e-5f);
    for (int d = lane; d < DTR; d += 64)
        dst[d] = (row[d] - mu) * rs * lnw[d] + lnb[d];
}

// ---------------------------------------------------------------- fused out-proj + residual + LN1 (2 rows, 256 thr)
__global__ __launch_bounds__(256) void k_projln(const float* __restrict__ ctx, const float* __restrict__ xres,
                                                const float* __restrict__ W, const float* __restrict__ bias,
                                                const float* __restrict__ lnw, const float* __restrict__ lnb,
                                                float* __restrict__ out) {
    int m0 = blockIdx.x * 2;
    int tid = threadIdx.x;  // 256
    __shared__ float xs[2 * DTR];
    __shared__ float ys[2 * DTR];
    for (int i = tid; i < 2 * DTR; i += 256) xs[i] = ctx[(size_t)m0 * DTR + i];
    __syncthreads();
    if (tid < DTR) {
        int n = tid;
        const float* wr = W + (size_t)n * DTR;
        float4 a0 = {0.f, 0.f, 0.f, 0.f};
        float4 a1 = {0.f, 0.f, 0.f, 0.f};
#pragma unroll 8
        for (int d = 0; d < DTR; d += 4) {
            float4 w4 = *(const float4*)(wr + d);
            float4 x0 = *(const float4*)&xs[d];
            float4 x1 = *(const float4*)&xs[DTR + d];
            a0.x += x0.x * w4.x; a0.y += x0.y * w4.y; a0.z += x0.z * w4.z; a0.w += x0.w * w4.w;
            a1.x += x1.x * w4.x; a1.y += x1.y * w4.y; a1.z += x1.z * w4.z; a1.w += x1.w * w4.w;
        }
        float bv = bias[n];
        ys[n]       = bv + (a0.x + a0.y) + (a0.z + a0.w) + xres[(size_t)m0 * DTR + n];
        ys[DTR + n] = bv + (a1.x + a1.y) + (a1.z + a1.w) + xres[(size_t)(m0 + 1) * DTR + n];
    }
    __syncthreads();
    int wid = tid >> 6, lane = tid & 63;
    if (wid < 2)
        wave_ln_row(&ys[wid * DTR], lane, lnw, lnb, out + (size_t)(m0 + wid) * DTR);
}

// ---------------------------------------------------------------- fused FF1+relu+FF2 + residual + LN2 (2 rows, 256 thr)
__global__ __launch_bounds__(256) void k_ffln(const float* __restrict__ xin,
                                              const float* __restrict__ W1, const float* __restrict__ b1,
                                              const float* __restrict__ W2, const float* __restrict__ b2,
                                              const float* __restrict__ lnw, const float* __restrict__ lnb,
                                              float* __restrict__ out) {
    int m0 = blockIdx.x * 2;
    int tid = threadIdx.x;  // 256
    __shared__ float xs[2 * DTR];
    __shared__ float hs[2 * NHID2];
    __shared__ float zs[2 * DTR];
    for (int i = tid; i < 2 * DTR; i += 256) xs[i] = xin[(size_t)m0 * DTR + i];
    __syncthreads();
    {
        int n = tid;  // all 256 active
        const float* wr = W1 + (size_t)n * DTR;
        float4 a0 = {0.f, 0.f, 0.f, 0.f};
        float4 a1 = {0.f, 0.f, 0.f, 0.f};
#pragma unroll 8
        for (int d = 0; d < DTR; d += 4) {
            float4 w4 = *(const float4*)(wr + d);
            float4 x0 = *(const float4*)&xs[d];
            float4 x1 = *(const float4*)&xs[DTR + d];
            a0.x += x0.x * w4.x; a0.y += x0.y * w4.y; a0.z += x0.z * w4.z; a0.w += x0.w * w4.w;
            a1.x += x1.x * w4.x; a1.y += x1.y * w4.y; a1.z += x1.z * w4.z; a1.w += x1.w * w4.w;
        }
        float bv = b1[n];
        hs[n]         = fmaxf(bv + (a0.x + a0.y) + (a0.z + a0.w), 0.f);
        hs[NHID2 + n] = fmaxf(bv + (a1.x + a1.y) + (a1.z + a1.w), 0.f);
    }
    __syncthreads();
    if (tid < DTR) {
        int n = tid;
        const float* wr = W2 + (size_t)n * NHID2;
        float4 a0 = {0.f, 0.f, 0.f, 0.f};
        float4 a1 = {0.f, 0.f, 0.f, 0.f};
#pragma unroll 8
        for (int d = 0; d < NHID2; d += 4) {
            float4 w4 = *(const float4*)(wr + d);
            float4 h0 = *(const float4*)&hs[d];
            float4 h1v = *(const float4*)&hs[NHID2 + d];
            a0.x += h0.x * w4.x; a0.y += h0.y * w4.y; a0.z += h0.z * w4.z; a0.w += h0.w * w4.w;
            a1.x += h1v.x * w4.x; a1.y += h1v.y * w4.y; a1.z += h1v.z * w4.z; a1.w += h1v.w * w4.w;
        }
        float bv = b2[n];
        zs[n]       = bv + (a0.x + a0.y) + (a0.z + a0.w) + xs[n];
        zs[DTR + n] = bv + (a1.x + a1.y) + (a1.z + a1.w) + xs[DTR + n];
    }
    __syncthreads();
    int wid = tid >> 6, lane = tid & 63;
    if (wid < 2)
        wave_ln_row(&zs[wid * DTR], lane, lnw, lnb, out + (size_t)(m0 + wid) * DTR);
}

// ---------------------------------------------------------------- final: copy output + preds
__global__ void k_pred(const float* __restrict__ x, const float* __restrict__ wty,
                       const float* __restrict__ wti, const int* __restrict__ lens,
                       float* __restrict__ out) {
    int row = blockIdx.x; int b = row / LMAX; int l = row % LMAX;
    __shared__ float xs[DTR];
    int tid = threadIdx.x;  // 64
    for (int d = tid; d < DTR; d += 64) xs[d] = x[(size_t)row * DTR + d];
    __syncthreads();
    float np = (l < lens[b]) ? 1.f : 0.f;
    if (tid < 37) {
        const float* w = (tid < 36) ? (wty + tid * DTR) : wti;
        float acc = 0.f;
#pragma unroll 8
        for (int d = 0; d < DTR; d += 4) {
            float4 w4 = *(const float4*)(w + d);
            acc += xs[d] * w4.x + xs[d + 1] * w4.y + xs[d + 2] * w4.z + xs[d + 3] * w4.w;
        }
        acc *= np;
        if (tid < 36) out[OUT_TYPE + (size_t)row * NND + tid] = acc;
        else out[OUT_TIME + row] = acc;
    }
    for (int d = tid; d < DTR; d += 64) out[(size_t)row * DTR + d] = xs[d];
}

// ---------------------------------------------------------------- launch
extern "C" void kernel_launch(void* const* d_in, const int* in_sizes, int n_in,
                              void* d_out, int out_size, void* d_ws, size_t ws_size,
                              hipStream_t stream) {
    const int* et      = (const int*)d_in[0];
    const float* etime = (const float*)d_in[1];
    const float* Ru    = (const float*)d_in[2];
    const float* gs    = (const float*)d_in[3];
    const float* Winc  = (const float*)d_in[4];
    const float* binc  = (const float*)d_in[5];
    const float* mapw  = (const float*)d_in[6];
    const float* wtime = (const float*)d_in[7];
    const float* wtype = (const float*)d_in[8];

    float* ws   = (float*)d_ws;
    float* pe   = ws + OFF_PE;
    float* rr   = ws + OFF_RR;
    float* ew   = ws + OFF_EW;
    float* beta = ws + OFF_BETA;
    float* meanb= ws + OFF_MEANB;
    float* alpha= ws + OFF_ALPHA;
    float* h1   = ws + OFF_H1;
    float* h2   = ws + OFF_H2;
    float* x    = ws + OFF_X;
    float* x2   = ws + OFF_X2;
    float* qkvb = ws + OFF_QKV;
    float* ctx  = ws + OFF_CTX;
    int* topi   = (int*)(ws + OFF_TOPI);
    int* idxarr = (int*)(ws + OFF_IDX);
    int* lens   = (int*)(ws + OFF_LENS);
    float* outp = (float*)d_out;

    k_prep<<<73, 256, 0, stream>>>(et, etime, Ru, gs, pe, rr, ew, idxarr, lens);
    k_beta<<<LMAX, 256, 0, stream>>>(Winc, binc, mapw, pe, rr, idxarr, beta);
    k_meanb<<<NBATCH * NND, 64, 0, stream>>>(beta, meanb);
    k_topk<<<dim3(6, NBATCH), 256, 0, stream>>>(ew, meanb, topi, alpha);
    k_h1<<<NBATCH * NND, 256, 0, stream>>>(topi, ew, beta, idxarr, rr, h1);
    k_h2<<<NBATCH * NND, 256, 0, stream>>>(topi, alpha, h1, h2);
    k_x0<<<(NBATCH * LMAX * DTR + 255) / 256, 256, 0, stream>>>(h2, pe, x);
    k_dist<<<1, 64, 0, stream>>>(alpha, outp + OUT_DIST);

    const int MB2 = NPAIR / 2;  // 860 two-row tiles
    for (int layer = 0; layer < 2; ++layer) {
        int base = 9 + layer * 12;
        const float* qkv_w = (const float*)d_in[base + 0];
        const float* qkv_b = (const float*)d_in[base + 1];
        const float* out_w = (const float*)d_in[base + 2];
        const float* out_b = (const float*)d_in[base + 3];
        const float* ff1_w = (const float*)d_in[base + 4];
        const float* ff1_b = (const float*)d_in[base + 5];
        const float* ff2_w = (const float*)d_in[base + 6];
        const float* ff2_b = (const float*)d_in[base + 7];
        const float* ln1_w = (const float*)d_in[base + 8];
        const float* ln1_b = (const float*)d_in[base + 9];
        const float* ln2_w = (const float*)d_in[base + 10];
        const float* ln2_b = (const float*)d_in[base + 11];

        k_qkv<<<MB2, 256, 0, stream>>>(x, qkv_w, qkv_b, qkvb);
        k_attn<<<NBATCH * NHEADS * LMAX, 64, 0, stream>>>(qkvb, lens, ctx);
        k_projln<<<MB2, 256, 0, stream>>>(ctx, x, out_w, out_b, ln1_w, ln1_b, x2);
        k_ffln<<<MB2, 256, 0, stream>>>(x2, ff1_w, ff1_b, ff2_w, ff2_b, ln2_w, ln2_b, x);
    }

    k_pred<<<NPAIR, 64, 0, stream>>>(x, wtype, wtime, lens, outp);
}

// Round 7
// 532.458 us; speedup vs baseline: 2.5734x; 1.0749x over previous
//
#include <hip/hip_runtime.h>
#include <math.h>

#define NBATCH 8
#define LMAX   215
#define NND    36
#define NE     1296
#define NK     648
#define CW     860      // C = LMAX*4
#define DPE    16
#define DTR    160
#define NHEADS 4
#define DH     40
#define NHID2  256
#define NPAIR  (NBATCH*LMAX)   // 1720
#define KSPLIT 4
#define KQLEN  54              // ceil(215/4)

// output layout (floats)
#define OUT_TYPE (NBATCH*LMAX*DTR)              // 275200
#define OUT_TIME (OUT_TYPE + NBATCH*LMAX*NND)   // 337120
#define OUT_DIST (OUT_TIME + NBATCH*LMAX)       // 338840

// workspace layout (float offsets)
#define OFF_PE    0
#define OFF_RR    (OFF_PE + NBATCH*LMAX*DPE)
#define OFF_EW    (OFF_RR + 144)
#define OFF_BETA  (OFF_EW + NE)
#define OFF_MEANB (OFF_BETA + NBATCH*NND*LMAX)
#define OFF_ALPHA (OFF_MEANB + NBATCH*NND)
#define OFF_H1    (OFF_ALPHA + NBATCH*NK)
#define OFF_H2    (OFF_H1 + NBATCH*NND*CW)
#define OFF_X     (OFF_H2 + NBATCH*NND*CW)
#define OFF_X2    (OFF_X + NBATCH*LMAX*DTR)
#define OFF_QKV   (OFF_X2 + NBATCH*LMAX*DTR)
#define OFF_CTX   (OFF_QKV + NBATCH*LMAX*480)
#define OFF_TOPI  (OFF_CTX + NBATCH*LMAX*DTR)
#define OFF_IDX   (OFF_TOPI + NBATCH*NK)
#define OFF_LENS  (OFF_IDX + NBATCH*LMAX)
#define OFF_PART  (OFF_LENS + NBATCH)
// part: [32 bh][4 kq][LMAX q][42]  = 1,155,840 floats (~4.6 MB)

// ---------------------------------------------------------------- prep (parallel: 73 blocks)
__global__ __launch_bounds__(256) void k_prep(
        const int* __restrict__ et, const float* __restrict__ etime,
        const float* __restrict__ Ru, const float* __restrict__ gs,
        float* pe, float* rr, float* ew, int* idxarr, int* lens) {
    int blk = blockIdx.x, tid = threadIdx.x;
    if (blk == 0) {
        for (int c = tid; c < 144; c += 256) rr[c] = fmaxf(Ru[c], 0.f);
        for (int e = tid; e < NE; e += 256) {
            int r = e / NND, cc = e % NND;
            ew[e] = (r == cc) ? 1.0f : gs[e];
        }
    } else if (blk <= 8) {
        int b = blk - 1;
        __shared__ int red[256];
        int cnt = 0;
        for (int l = tid; l < LMAX; l += 256) {
            int v = et[b * LMAX + l];
            cnt += (v != 0);
            idxarr[b * LMAX + l] = max(v - 1, 0);
        }
        red[tid] = cnt;
        __syncthreads();
        for (int st = 128; st > 0; st >>= 1) { if (tid < st) red[tid] += red[tid + st]; __syncthreads(); }
        if (tid == 0) lens[b] = red[0];
    } else {
        __shared__ float sts[8];
        if (tid < 8) sts[tid] = (float)pow(215.0, (double)tid / 7.0);
        __syncthreads();
        int i0 = (blk - 9) * 430;
        for (int i = i0 + tid; i < i0 + 430; i += 256) {
            int s = i & 15; int bl = i >> 4;
            float t = etime[bl];
            float sc = t / sts[s & 7];
            pe[i] = (s < 8) ? sinf(sc) : cosf(sc);
        }
    }
}

// ---------------------------------------------------------------- beta (block per t; double-buffered Winc tiles)
__global__ __launch_bounds__(256) void k_beta(
        const float* __restrict__ Winc, const float* __restrict__ binc,
        const float* __restrict__ mapw, const float* __restrict__ pe,
        const float* __restrict__ rr, const int* __restrict__ idxarr,
        float* __restrict__ beta) {
    const int t = blockIdx.x;        // 0..214
    const int tid = threadIdx.x;     // 256

    __shared__ float s_rows[2][4 * CW];
    __shared__ float s_pair[NPAIR];
    __shared__ int   s_idx[NPAIR];
    __shared__ float s_mapw[NND * 16];
    __shared__ float s_rr[144];
    __shared__ float s_pe[NBATCH * 16];
    __shared__ float s_binc[32];

    for (int i = tid; i < NPAIR; i += 256) s_idx[i] = idxarr[i];
    for (int i = tid; i < NND * 16; i += 256) s_mapw[i] = mapw[i];
    if (tid < 144) s_rr[tid] = rr[tid];
    if (tid < 128) { int b = tid >> 4, s = tid & 15; s_pe[tid] = pe[((size_t)(b * LMAX + t)) * DPE + s]; }
    if (tid < 32) s_binc[tid] = binc[32 * t + tid];

    float acc[7];
#pragma unroll
    for (int pp = 0; pp < 7; ++pp) acc[pp] = 0.f;

    float4 pre[4];
    {
        const float4* src = (const float4*)(Winc + (size_t)(32 * t) * CW);
#pragma unroll
        for (int i = 0; i < 4; ++i) { int k = tid + i * 256; if (k < CW) pre[i] = src[k]; }
    }
    int p = 0;
    for (int jc = 0; jc < 8; ++jc) {
        float4* buf = (float4*)&s_rows[p][0];
#pragma unroll
        for (int i = 0; i < 4; ++i) { int k = tid + i * 256; if (k < CW) buf[k] = pre[i]; }
        __syncthreads();
        if (jc < 7) {
            const float4* src = (const float4*)(Winc + (size_t)(32 * t + 4 * (jc + 1)) * CW);
#pragma unroll
            for (int i = 0; i < 4; ++i) { int k = tid + i * 256; if (k < CW) pre[i] = src[k]; }
        }
#pragma unroll
        for (int pp = 0; pp < 7; ++pp) {
            int pr = tid + pp * 256;
            if (pr < NPAIR) {
                int b = pr / LMAX, l = pr - b * LMAX;
                int n = s_idx[pr];
                float4 r4 = *(const float4*)&s_rr[4 * n];
                float a = acc[pp];
#pragma unroll
                for (int jj = 0; jj < 4; ++jj) {
                    int j = 4 * jc + jj;
                    float4 w4 = *(const float4*)&s_rows[p][jj * CW + 4 * l];
                    float dv = r4.x * w4.x + r4.y * w4.y + r4.z * w4.z + r4.w * w4.w;
                    float coeff = (j < 16) ? s_mapw[n * 16 + j] : s_pe[(b << 4) + (j - 16)];
                    a += coeff * dv;
                }
                acc[pp] = a;
            }
        }
        p ^= 1;
    }
    __syncthreads();

#pragma unroll
    for (int pp = 0; pp < 7; ++pp) {
        int pr = tid + pp * 256;
        if (pr < NPAIR) s_pair[pr] = acc[pp];
    }
    __syncthreads();

    if (tid < NBATCH * NND) {
        int b = tid / NND, n = tid - b * NND;
        int base = b * LMAX;
        float sum = 0.f;
        for (int l = 0; l < LMAX; ++l)
            if (s_idx[base + l] == n) sum += s_pair[base + l];
        float bias = 0.f;
#pragma unroll
        for (int s = 0; s < 16; ++s)
            bias += s_mapw[n * 16 + s] * s_binc[s] + s_pe[(b << 4) + s] * s_binc[16 + s];
        beta[((size_t)b * NND + n) * LMAX + t] = (sum + bias) * (1.0f / 32.0f);
    }
}

// ---------------------------------------------------------------- mean over t (deterministic)
__global__ void k_meanb(const float* __restrict__ beta, float* __restrict__ meanb) {
    int bn = blockIdx.x;       // 288
    int lane = threadIdx.x;    // 64
    const float* p = beta + (size_t)bn * LMAX;
    float s = 0.f;
    for (int t = lane; t < LMAX; t += 64) s += p[t];
    for (int off = 32; off > 0; off >>= 1) s += __shfl_xor(s, off);
    if (lane == 0) meanb[bn] = s / (float)LMAX;
}

// ---------------------------------------------------------------- stable top-K via rank selection
__global__ __launch_bounds__(256) void k_topk(const float* __restrict__ ew,
                                              const float* __restrict__ meanb,
                                              int* __restrict__ topi, float* __restrict__ alpha) {
    int chunk = blockIdx.x;    // 0..5  (216 elements each)
    int b = blockIdx.y;        // 0..7
    int tid = threadIdx.x;     // 256
    __shared__ float sv[NE];
    __shared__ float sm[NND];
    if (tid < NND) sm[tid] = meanb[b * NND + tid];
    __syncthreads();
    for (int e = tid; e < NE; e += 256) sv[e] = ew[e] * sm[e % NND];
    __syncthreads();
    int e = chunk * 216 + tid;
    if (tid < 216) {
        float v = sv[e];
        int rank = 0;
        for (int i = 0; i < NE; ++i) {
            float u = sv[i];
            rank += (u > v) || (u == v && i < e);
        }
        if (rank < NK) {
            topi[b * NK + rank] = e;
            alpha[b * NK + rank] = v;
        }
    }
}

// ---------------------------------------------------------------- message passing layer 1
__global__ void k_h1(const int* __restrict__ topi, const float* __restrict__ ew,
                     const float* __restrict__ beta, const int* __restrict__ idxarr,
                     const float* __restrict__ rr, float* h1) {
    int b = blockIdx.x / NND, n = blockIdx.x % NND;
    __shared__ int cnt;
    __shared__ int lsrc[40];
    __shared__ float lew[40];
    int tid = threadIdx.x;  // 256
    if (tid == 0) cnt = 0;
    __syncthreads();
    for (int k = tid; k < NK; k += 256) {
        int e = topi[b * NK + k];
        if (e % NND == n) {
            int p = atomicAdd(&cnt, 1);
            lsrc[p] = e / NND;
            lew[p] = ew[e];
        }
    }
    __syncthreads();
    int m = cnt;
    const float* bb = beta + ((size_t)b * NND + n) * LMAX;
    for (int c = tid; c < CW; c += 256) {
        int t = c >> 2, o = c & 3;
        float bt = bb[t];
        int id = idxarr[b * LMAX + t];
        float x = rr[id * 4 + o];
        float acc = 0.f;
        for (int j = 0; j < m; ++j) {
            float g = bt * lew[j];
            if (g > 0.f && lsrc[j] == id) acc += x * g;
        }
        h1[((size_t)b * NND + n) * CW + c] = acc;
    }
}

// ---------------------------------------------------------------- message passing layer 2
__global__ void k_h2(const int* __restrict__ topi, const float* __restrict__ alpha,
                     const float* __restrict__ h1, float* h2) {
    int b = blockIdx.x / NND, n = blockIdx.x % NND;
    __shared__ int cnt;
    __shared__ int lsrc[40];
    __shared__ float lal[40];
    int tid = threadIdx.x;
    if (tid == 0) cnt = 0;
    __syncthreads();
    for (int k = tid; k < NK; k += 256) {
        int e = topi[b * NK + k];
        if (e % NND == n) {
            int p = atomicAdd(&cnt, 1);
            lsrc[p] = e / NND;
            lal[p] = fmaxf(alpha[b * NK + k], 0.f);
        }
    }
    __syncthreads();
    int m = cnt;
    for (int c = tid; c < CW; c += 256) {
        float acc = 0.f;
        for (int j = 0; j < m; ++j)
            acc += fmaxf(h1[((size_t)b * NND + lsrc[j]) * CW + c], 0.f) * lal[j];
        h2[((size_t)b * NND + n) * CW + c] = acc;
    }
}

// ---------------------------------------------------------------- assemble transformer input
__global__ void k_x0(const float* __restrict__ h2, const float* __restrict__ pe, float* x) {
    int i = blockIdx.x * 256 + threadIdx.x;
    if (i >= NBATCH * LMAX * DTR) return;
    int ch = i % DTR; int bl = i / DTR; int l = bl % LMAX; int b = bl / LMAX;
    float v;
    if (ch < 144) {
        int n = ch >> 2, o = ch & 3;
        v = h2[((size_t)b * NND + n) * CW + 4 * l + o];
    } else {
        v = pe[(b * LMAX + l) * DPE + (ch - 144)];
    }
    x[i] = v;
}

// ---------------------------------------------------------------- distance
__global__ void k_dist(const float* __restrict__ alpha, float* outd) {
    __shared__ float s[64];
    int tid = threadIdx.x;  // 64
    int i = tid / 8, j = tid % 8;
    float d2 = 0.f;
    for (int k = 0; k < NK; ++k) {
        float d = alpha[i * NK + k] - alpha[j * NK + k];
        d2 += d * d;
    }
    s[tid] = (d2 > 0.f) ? sqrtf(d2) : 0.f;
    __syncthreads();
    for (int st = 32; st > 0; st >>= 1) { if (tid < st) s[tid] += s[tid + st]; __syncthreads(); }
    if (tid == 0) *outd = s[0] / 64.0f;
}

// ---------------------------------------------------------------- qkv GEMM: 2 rows/block, 256 thr
__global__ __launch_bounds__(256) void k_qkv(const float* __restrict__ X, const float* __restrict__ W,
                                             const float* __restrict__ bias, float* __restrict__ Y) {
    int m0 = blockIdx.x * 2;
    int tid = threadIdx.x;
    __shared__ float xs[2 * DTR];
    for (int i = tid; i < 2 * DTR; i += 256) xs[i] = X[(size_t)m0 * DTR + i];
    __syncthreads();
    for (int n = tid; n < 480; n += 256) {
        const float* wr = W + (size_t)n * DTR;
        float4 a0 = {0.f, 0.f, 0.f, 0.f};
        float4 a1 = {0.f, 0.f, 0.f, 0.f};
#pragma unroll 8
        for (int d = 0; d < DTR; d += 4) {
            float4 w4 = *(const float4*)(wr + d);
            float4 x0 = *(const float4*)&xs[d];
            float4 x1 = *(const float4*)&xs[DTR + d];
            a0.x += x0.x * w4.x; a0.y += x0.y * w4.y; a0.z += x0.z * w4.z; a0.w += x0.w * w4.w;
            a1.x += x1.x * w4.x; a1.y += x1.y * w4.y; a1.z += x1.z * w4.z; a1.w += x1.w * w4.w;
        }
        float bv = bias[n];
        Y[(size_t)m0 * 480 + n]       = bv + (a0.x + a0.y) + (a0.z + a0.w);
        Y[(size_t)(m0 + 1) * 480 + n] = bv + (a1.x + a1.y) + (a1.z + a1.w);
    }
}

// ---------------------------------------------------------------- attention partials (flash k-split)
// block = (kq in 0..3, bh in 0..31); thread = one q row; K/V quarter staged in LDS.
__global__ __launch_bounds__(256) void k_attn_part(const float* __restrict__ qkv,
                                                   const int* __restrict__ lens,
                                                   float* __restrict__ part) {
    int kq = blockIdx.x;           // 0..3
    int bh = blockIdx.y;           // 0..31
    int b = bh >> 2, h = bh & 3;
    int tid = threadIdx.x;         // 256
    int k0 = kq * KQLEN;
    int k1 = min(LMAX, k0 + KQLEN);
    int klen = k1 - k0;            // 54 or 53
    __shared__ float sK[KQLEN * DH];
    __shared__ float sV[KQLEN * DH];
    for (int i = tid; i < klen * DH; i += 256) {
        int kk = i / DH, d = i - kk * DH;
        size_t base = (size_t)(b * LMAX + k0 + kk) * 480;
        sK[i] = qkv[base + DTR + h * DH + d];
        sV[i] = qkv[base + 2 * DTR + h * DH + d];
    }
    __syncthreads();
    int q = tid;
    if (q >= LMAX) return;
    float4 qv[10];
    const float4* qr = (const float4*)(qkv + (size_t)(b * LMAX + q) * 480 + h * DH);
#pragma unroll
    for (int i = 0; i < 10; ++i) qv[i] = qr[i];
    int len = lens[b];
    const float scale = 0.15811388300841898f;  // 1/sqrt(40)
    float m = -INFINITY, l = 0.f;
    float o[DH];
#pragma unroll
    for (int d = 0; d < DH; ++d) o[d] = 0.f;
    int kend = min(k1, len);       // uniform across block
    for (int k = k0; k < kend; ++k) {
        const float4* kr = (const float4*)&sK[(k - k0) * DH];
        float s0 = 0.f, s1 = 0.f, s2 = 0.f, s3 = 0.f;
#pragma unroll
        for (int i = 0; i < 10; ++i) {
            float4 kv = kr[i];
            s0 += qv[i].x * kv.x; s1 += qv[i].y * kv.y;
            s2 += qv[i].z * kv.z; s3 += qv[i].w * kv.w;
        }
        float s = ((s0 + s1) + (s2 + s3)) * scale;
        float p;
        if (s <= m) {
            p = expf(s - m);
        } else {
            float c = expf(m - s);   // 0 on first iter (m = -inf)
            l *= c;
#pragma unroll
            for (int d = 0; d < DH; ++d) o[d] *= c;
            m = s;
            p = 1.0f;
        }
        l += p;
        const float* vr = &sV[(k - k0) * DH];
#pragma unroll
        for (int d = 0; d < DH; ++d) o[d] += p * vr[d];
    }
    float* pp = part + ((size_t)(bh * KSPLIT + kq) * LMAX + q) * 42;
#pragma unroll
    for (int d = 0; d < DH; ++d) pp[d] = o[d];
    pp[40] = l;
    pp[41] = m;
}

// ---------------------------------------------------------------- attention merge (4 partials -> ctx)
__global__ __launch_bounds__(256) void k_attn_merge(const float* __restrict__ part,
                                                    float* __restrict__ ctx) {
    int row = blockIdx.x;          // b*LMAX+q
    int b = row / LMAX, q = row - b * LMAX;
    int tid = threadIdx.x;         // 256
    int h = tid >> 6, lane = tid & 63;
    int bh = b * NHEADS + h;
    const float* p0 = part + ((size_t)(bh * KSPLIT + 0) * LMAX + q) * 42;
    const float* p1 = part + ((size_t)(bh * KSPLIT + 1) * LMAX + q) * 42;
    const float* p2 = part + ((size_t)(bh * KSPLIT + 2) * LMAX + q) * 42;
    const float* p3 = part + ((size_t)(bh * KSPLIT + 3) * LMAX + q) * 42;
    float m0 = p0[41], m1 = p1[41], m2 = p2[41], m3 = p3[41];
    float ms = fmaxf(fmaxf(m0, m1), fmaxf(m2, m3));
    float w0 = expf(m0 - ms), w1 = expf(m1 - ms), w2 = expf(m2 - ms), w3 = expf(m3 - ms);
    float lsum = w0 * p0[40] + w1 * p1[40] + w2 * p2[40] + w3 * p3[40];
    float inv = 1.0f / lsum;
    if (lane < DH) {
        float acc = w0 * p0[lane] + w1 * p1[lane] + w2 * p2[lane] + w3 * p3[lane];
        ctx[(size_t)row * DTR + h * DH + lane] = acc * inv;
    }
}

// ---------------------------------------------------------------- device LN helper (per-wave over one row in LDS)
__device__ __forceinline__ void wave_ln_row(const float* __restrict__ row, int lane,
                                            const float* __restrict__ lnw, const float* __restrict__ lnb,
                                            float* __restrict__ dst) {
    float s = 0.f;
    for (int d = lane; d < DTR; d += 64) s += row[d];
    for (int off = 32; off > 0; off >>= 1) s += __shfl_xor(s, off);
    float mu = s / (float)DTR;
    float v = 0.f;
    for (int d = lane; d < DTR; d += 64) { float dd = row[d] - mu; v += dd * dd; }
    for (int off = 32; off > 0; off >>= 1) v += __shfl_xor(v, off);
    float rs = rsqrtf(v / (float)DTR + 1e-5f);
    for (int d = lane; d < DTR; d += 64)
        dst[d] = (row[d] - mu) * rs * lnw[d] + lnb[d];
}

// ---------------------------------------------------------------- fused out-proj + residual + LN1 (2 rows, 256 thr)
__global__ __launch_bounds__(256) void k_projln(const float* __restrict__ ctx, const float* __restrict__ xres,
                                                const float* __restrict__ W, const float* __restrict__ bias,
                                                const float* __restrict__ lnw, const float* __restrict__ lnb,
                                                float* __restrict__ out) {
    int m0 = blockIdx.x * 2;
    int tid = threadIdx.x;  // 256
    __shared__ float xs[2 * DTR];
    __shared__ float ys[2 * DTR];
    for (int i = tid; i < 2 * DTR; i += 256) xs[i] = ctx[(size_t)m0 * DTR + i];
    __syncthreads();
    if (tid < DTR) {
        int n = tid;
        const float* wr = W + (size_t)n * DTR;
        float4 a0 = {0.f, 0.f, 0.f, 0.f};
        float4 a1 = {0.f, 0.f, 0.f, 0.f};
#pragma unroll 8
        for (int d = 0; d < DTR; d += 4) {
            float4 w4 = *(const float4*)(wr + d);
            float4 x0 = *(const float4*)&xs[d];
            float4 x1 = *(const float4*)&xs[DTR + d];
            a0.x += x0.x * w4.x; a0.y += x0.y * w4.y; a0.z += x0.z * w4.z; a0.w += x0.w * w4.w;
            a1.x += x1.x * w4.x; a1.y += x1.y * w4.y; a1.z += x1.z * w4.z; a1.w += x1.w * w4.w;
        }
        float bv = bias[n];
        ys[n]       = bv + (a0.x + a0.y) + (a0.z + a0.w) + xres[(size_t)m0 * DTR + n];
        ys[DTR + n] = bv + (a1.x + a1.y) + (a1.z + a1.w) + xres[(size_t)(m0 + 1) * DTR + n];
    }
    __syncthreads();
    int wid = tid >> 6, lane = tid & 63;
    if (wid < 2)
        wave_ln_row(&ys[wid * DTR], lane, lnw, lnb, out + (size_t)(m0 + wid) * DTR);
}

// ---------------------------------------------------------------- fused FF1+relu+FF2 + residual + LN2 (2 rows, 256 thr)
__global__ __launch_bounds__(256) void k_ffln(const float* __restrict__ xin,
                                              const float* __restrict__ W1, const float* __restrict__ b1,
                                              const float* __restrict__ W2, const float* __restrict__ b2,
                                              const float* __restrict__ lnw, const float* __restrict__ lnb,
                                              float* __restrict__ out) {
    int m0 = blockIdx.x * 2;
    int tid = threadIdx.x;  // 256
    __shared__ float xs[2 * DTR];
    __shared__ float hs[2 * NHID2];
    __shared__ float zs[2 * DTR];
    for (int i = tid; i < 2 * DTR; i += 256) xs[i] = xin[(size_t)m0 * DTR + i];
    __syncthreads();
    {
        int n = tid;  // all 256 active
        const float* wr = W1 + (size_t)n * DTR;
        float4 a0 = {0.f, 0.f, 0.f, 0.f};
        float4 a1 = {0.f, 0.f, 0.f, 0.f};
#pragma unroll 8
        for (int d = 0; d < DTR; d += 4) {
            float4 w4 = *(const float4*)(wr + d);
            float4 x0 = *(const float4*)&xs[d];
            float4 x1 = *(const float4*)&xs[DTR + d];
            a0.x += x0.x * w4.x; a0.y += x0.y * w4.y; a0.z += x0.z * w4.z; a0.w += x0.w * w4.w;
            a1.x += x1.x * w4.x; a1.y += x1.y * w4.y; a1.z += x1.z * w4.z; a1.w += x1.w * w4.w;
        }
        float bv = b1[n];
        hs[n]         = fmaxf(bv + (a0.x + a0.y) + (a0.z + a0.w), 0.f);
        hs[NHID2 + n] = fmaxf(bv + (a1.x + a1.y) + (a1.z + a1.w), 0.f);
    }
    __syncthreads();
    if (tid < DTR) {
        int n = tid;
        const float* wr = W2 + (size_t)n * NHID2;
        float4 a0 = {0.f, 0.f, 0.f, 0.f};
        float4 a1 = {0.f, 0.f, 0.f, 0.f};
#pragma unroll 8
        for (int d = 0; d < NHID2; d += 4) {
            float4 w4 = *(const float4*)(wr + d);
            float4 h0 = *(const float4*)&hs[d];
            float4 h1v = *(const float4*)&hs[NHID2 + d];
            a0.x += h0.x * w4.x; a0.y += h0.y * w4.y; a0.z += h0.z * w4.z; a0.w += h0.w * w4.w;
            a1.x += h1v.x * w4.x; a1.y += h1v.y * w4.y; a1.z += h1v.z * w4.z; a1.w += h1v.w * w4.w;
        }
        float bv = b2[n];
        zs[n]       = bv + (a0.x + a0.y) + (a0.z + a0.w) + xs[n];
        zs[DTR + n] = bv + (a1.x + a1.y) + (a1.z + a1.w) + xs[DTR + n];
    }
    __syncthreads();
    int wid = tid >> 6, lane = tid & 63;
    if (wid < 2)
        wave_ln_row(&zs[wid * DTR], lane, lnw, lnb, out + (size_t)(m0 + wid) * DTR);
}

// ---------------------------------------------------------------- final: copy output + preds
__global__ void k_pred(const float* __restrict__ x, const float* __restrict__ wty,
                       const float* __restrict__ wti, const int* __restrict__ lens,
                       float* __restrict__ out) {
    int row = blockIdx.x; int b = row / LMAX; int l = row % LMAX;
    __shared__ float xs[DTR];
    int tid = threadIdx.x;  // 64
    for (int d = tid; d < DTR; d += 64) xs[d] = x[(size_t)row * DTR + d];
    __syncthreads();
    float np = (l < lens[b]) ? 1.f : 0.f;
    if (tid < 37) {
        const float* w = (tid < 36) ? (wty + tid * DTR) : wti;
        float acc = 0.f;
#pragma unroll 8
        for (int d = 0; d < DTR; d += 4) {
            float4 w4 = *(const float4*)(w + d);
            acc += xs[d] * w4.x + xs[d + 1] * w4.y + xs[d + 2] * w4.z + xs[d + 3] * w4.w;
        }
        acc *= np;
        if (tid < 36) out[OUT_TYPE + (size_t)row * NND + tid] = acc;
        else out[OUT_TIME + row] = acc;
    }
    for (int d = tid; d < DTR; d += 64) out[(size_t)row * DTR + d] = xs[d];
}

// ---------------------------------------------------------------- launch
extern "C" void kernel_launch(void* const* d_in, const int* in_sizes, int n_in,
                              void* d_out, int out_size, void* d_ws, size_t ws_size,
                              hipStream_t stream) {
    const int* et      = (const int*)d_in[0];
    const float* etime = (const float*)d_in[1];
    const float* Ru    = (const float*)d_in[2];
    const float* gs    = (const float*)d_in[3];
    const float* Winc  = (const float*)d_in[4];
    const float* binc  = (const float*)d_in[5];
    const float* mapw  = (const float*)d_in[6];
    const float* wtime = (const float*)d_in[7];
    const float* wtype = (const float*)d_in[8];

    float* ws   = (float*)d_ws;
    float* pe   = ws + OFF_PE;
    float* rr   = ws + OFF_RR;
    float* ew   = ws + OFF_EW;
    float* beta = ws + OFF_BETA;
    float* meanb= ws + OFF_MEANB;
    float* alpha= ws + OFF_ALPHA;
    float* h1   = ws + OFF_H1;
    float* h2   = ws + OFF_H2;
    float* x    = ws + OFF_X;
    float* x2   = ws + OFF_X2;
    float* qkvb = ws + OFF_QKV;
    float* ctx  = ws + OFF_CTX;
    float* part = ws + OFF_PART;
    int* topi   = (int*)(ws + OFF_TOPI);
    int* idxarr = (int*)(ws + OFF_IDX);
    int* lens   = (int*)(ws + OFF_LENS);
    float* outp = (float*)d_out;

    k_prep<<<73, 256, 0, stream>>>(et, etime, Ru, gs, pe, rr, ew, idxarr, lens);
    k_beta<<<LMAX, 256, 0, stream>>>(Winc, binc, mapw, pe, rr, idxarr, beta);
    k_meanb<<<NBATCH * NND, 64, 0, stream>>>(beta, meanb);
    k_topk<<<dim3(6, NBATCH), 256, 0, stream>>>(ew, meanb, topi, alpha);
    k_h1<<<NBATCH * NND, 256, 0, stream>>>(topi, ew, beta, idxarr, rr, h1);
    k_h2<<<NBATCH * NND, 256, 0, stream>>>(topi, alpha, h1, h2);
    k_x0<<<(NBATCH * LMAX * DTR + 255) / 256, 256, 0, stream>>>(h2, pe, x);
    k_dist<<<1, 64, 0, stream>>>(alpha, outp + OUT_DIST);

    const int MB2 = NPAIR / 2;  // 860 two-row tiles
    for (int layer = 0; layer < 2; ++layer) {
        int base = 9 + layer * 12;
        const float* qkv_w = (const float*)d_in[base + 0];
        const float* qkv_b = (const float*)d_in[base + 1];
        const float* out_w = (const float*)d_in[base + 2];
        const float* out_b = (const float*)d_in[base + 3];
        const float* ff1_w = (const float*)d_in[base + 4];
        const float* ff1_b = (const float*)d_in[base + 5];
        const float* ff2_w = (const float*)d_in[base + 6];
        const float* ff2_b = (const float*)d_in[base + 7];
        const float* ln1_w = (const float*)d_in[base + 8];
        const float* ln1_b = (const float*)d_in[base + 9];
        const float* ln2_w = (const float*)d_in[base + 10];
        const float* ln2_b = (const float*)d_in[base + 11];

        k_qkv<<<MB2, 256, 0, stream>>>(x, qkv_w, qkv_b, qkvb);
        k_attn_part<<<dim3(KSPLIT, NBATCH * NHEADS), 256, 0, stream>>>(qkvb, lens, part);
        k_attn_merge<<<NPAIR, 256, 0, stream>>>(part, ctx);
        k_projln<<<MB2, 256, 0, stream>>>(ctx, x, out_w, out_b, ln1_w, ln1_b, x2);
        k_ffln<<<MB2, 256, 0, stream>>>(x2, ff1_w, ff1_b, ff2_w, ff2_b, ln2_w, ln2_b, x);
    }

    k_pred<<<NPAIR, 64, 0, stream>>>(x, wtype, wtime, lens, outp);
}

// Round 8
// 526.779 us; speedup vs baseline: 2.6011x; 1.0108x over previous
//
#include <hip/hip_runtime.h>
#include <math.h>

#define NBATCH 8
#define LMAX   215
#define NND    36
#define NE     1296
#define NK     648
#define CW     860      // C = LMAX*4
#define DPE    16
#define DTR    160
#define NHEADS 4
#define DH     40
#define NHID2  256
#define NPAIR  (NBATCH*LMAX)   // 1720
#define KSPLIT 4
#define KQLEN  54              // ceil(215/4)

// output layout (floats)
#define OUT_TYPE (NBATCH*LMAX*DTR)              // 275200
#define OUT_TIME (OUT_TYPE + NBATCH*LMAX*NND)   // 337120
#define OUT_DIST (OUT_TIME + NBATCH*LMAX)       // 338840

// workspace layout (float offsets)
#define OFF_PE    0
#define OFF_RR    (OFF_PE + NBATCH*LMAX*DPE)
#define OFF_EW    (OFF_RR + 144)
#define OFF_BETA  (OFF_EW + NE)
#define OFF_MEANB (OFF_BETA + NBATCH*NND*LMAX)
#define OFF_ALPHA (OFF_MEANB + NBATCH*NND)
#define OFF_H1    (OFF_ALPHA + NBATCH*NK)
#define OFF_H2    (OFF_H1 + NBATCH*NND*CW)
#define OFF_X     (OFF_H2 + NBATCH*NND*CW)
#define OFF_X2    (OFF_X + NBATCH*LMAX*DTR)
#define OFF_QKV   (OFF_X2 + NBATCH*LMAX*DTR)
#define OFF_CTX   (OFF_QKV + NBATCH*LMAX*480)
#define OFF_TOPI  (OFF_CTX + NBATCH*LMAX*DTR)
#define OFF_IDX   (OFF_TOPI + NBATCH*NK)
#define OFF_LENS  (OFF_IDX + NBATCH*LMAX)
#define OFF_PART  (OFF_LENS + NBATCH)
#define OFF_CSRC  (OFF_PART + 32*KSPLIT*LMAX*42)   // 288 ints
#define OFF_CSRL  (OFF_CSRC + NBATCH*NND)          // 288*215 ints

// ---------------------------------------------------------------- prep (parallel: 73 blocks)
__global__ __launch_bounds__(256) void k_prep(
        const int* __restrict__ et, const float* __restrict__ etime,
        const float* __restrict__ Ru, const float* __restrict__ gs,
        float* pe, float* rr, float* ew, int* idxarr, int* lens,
        int* csr_cnt, int* csr_list) {
    int blk = blockIdx.x, tid = threadIdx.x;
    if (blk == 0) {
        for (int c = tid; c < 144; c += 256) rr[c] = fmaxf(Ru[c], 0.f);
        for (int e = tid; e < NE; e += 256) {
            int r = e / NND, cc = e % NND;
            ew[e] = (r == cc) ? 1.0f : gs[e];
        }
    } else if (blk <= 8) {
        int b = blk - 1;
        __shared__ int red[256];
        __shared__ int sidx[LMAX];
        int cnt = 0;
        for (int l = tid; l < LMAX; l += 256) {
            int v = et[b * LMAX + l];
            cnt += (v != 0);
            int ix = max(v - 1, 0);
            idxarr[b * LMAX + l] = ix;
            sidx[l] = ix;
        }
        red[tid] = cnt;
        __syncthreads();
        for (int st = 128; st > 0; st >>= 1) { if (tid < st) red[tid] += red[tid + st]; __syncthreads(); }
        if (tid == 0) lens[b] = red[0];
        // CSR build: l's per node, ascending (preserves reference sum order)
        if (tid < NND) {
            int c = 0;
            int* lst = csr_list + (size_t)(b * NND + tid) * LMAX;
            for (int l = 0; l < LMAX; ++l)
                if (sidx[l] == tid) { lst[c] = l; ++c; }
            csr_cnt[b * NND + tid] = c;
        }
    } else {
        __shared__ float sts[8];
        if (tid < 8) sts[tid] = (float)pow(215.0, (double)tid / 7.0);
        __syncthreads();
        int i0 = (blk - 9) * 430;
        for (int i = i0 + tid; i < i0 + 430; i += 256) {
            int s = i & 15; int bl = i >> 4;
            float t = etime[bl];
            float sc = t / sts[s & 7];
            pe[i] = (s < 8) ? sinf(sc) : cosf(sc);
        }
    }
}

// ---------------------------------------------------------------- beta v3 (thread-owns-l, b-loop in regs, CSR reduce)
__global__ __launch_bounds__(256) void k_beta(
        const float* __restrict__ Winc, const float* __restrict__ binc,
        const float* __restrict__ mapw, const float* __restrict__ pe,
        const float* __restrict__ rr, const int* __restrict__ idxarr,
        const int* __restrict__ csr_cnt, const int* __restrict__ csr_list,
        float* __restrict__ beta) {
    const int t = blockIdx.x;        // 0..214
    const int tid = threadIdx.x;     // 256

    __shared__ float s_rows[2][4 * CW];   // double-buffered 4-row tiles
    __shared__ float s_pair[NBATCH * LMAX];
    __shared__ int   s_idx[NPAIR];
    __shared__ float s_mapw[NND * 16];
    __shared__ float s_rr[144];
    __shared__ float s_pe[NBATCH * 16];
    __shared__ float s_binc[32];

    for (int i = tid; i < NPAIR; i += 256) s_idx[i] = idxarr[i];
    for (int i = tid; i < NND * 16; i += 256) s_mapw[i] = mapw[i];
    if (tid < 144) s_rr[tid] = rr[tid];
    if (tid < 128) { int b = tid >> 4, s = tid & 15; s_pe[tid] = pe[((size_t)(b * LMAX + t)) * DPE + s]; }
    if (tid < 32) s_binc[tid] = binc[32 * t + tid];

    float4 pre[4];
    {
        const float4* src = (const float4*)(Winc + (size_t)(32 * t) * CW);
#pragma unroll
        for (int i = 0; i < 4; ++i) { int k = tid + i * 256; if (k < CW) pre[i] = src[k]; }
    }
    __syncthreads();   // s_idx/s_rr ready

    const int l = tid;             // thread owns one column l (215 active)
    int nb[NBATCH];
    float4 r4b[NBATCH];
    if (l < LMAX) {
#pragma unroll
        for (int b = 0; b < NBATCH; ++b) {
            nb[b] = s_idx[b * LMAX + l];
            r4b[b] = *(const float4*)&s_rr[4 * nb[b]];
        }
    }
    float acc[NBATCH];
#pragma unroll
    for (int b = 0; b < NBATCH; ++b) acc[b] = 0.f;

    int p = 0;
    for (int jc = 0; jc < 8; ++jc) {
        float4* buf = (float4*)&s_rows[p][0];
#pragma unroll
        for (int i = 0; i < 4; ++i) { int k = tid + i * 256; if (k < CW) buf[k] = pre[i]; }
        __syncthreads();
        if (jc < 7) {
            const float4* src = (const float4*)(Winc + (size_t)(32 * t + 4 * (jc + 1)) * CW);
#pragma unroll
            for (int i = 0; i < 4; ++i) { int k = tid + i * 256; if (k < CW) pre[i] = src[k]; }
        }
        if (l < LMAX) {
            if (jc < 4) {   // j = 4*jc+jj < 16 : coeff = mapw[n][j]
#pragma unroll
                for (int jj = 0; jj < 4; ++jj) {
                    int j = 4 * jc + jj;
                    float4 w4 = *(const float4*)&s_rows[p][jj * CW + 4 * l];
#pragma unroll
                    for (int b = 0; b < NBATCH; ++b) {
                        float dv = r4b[b].x * w4.x + r4b[b].y * w4.y + r4b[b].z * w4.z + r4b[b].w * w4.w;
                        acc[b] += s_mapw[nb[b] * 16 + j] * dv;
                    }
                }
            } else {        // j >= 16 : coeff = pe[b][j-16]
#pragma unroll
                for (int jj = 0; jj < 4; ++jj) {
                    int j = 4 * jc + jj;
                    float4 w4 = *(const float4*)&s_rows[p][jj * CW + 4 * l];
#pragma unroll
                    for (int b = 0; b < NBATCH; ++b) {
                        float dv = r4b[b].x * w4.x + r4b[b].y * w4.y + r4b[b].z * w4.z + r4b[b].w * w4.w;
                        acc[b] += s_pe[(b << 4) + (j - 16)] * dv;
                    }
                }
            }
        }
        __syncthreads();
        p ^= 1;
    }

    if (l < LMAX) {
#pragma unroll
        for (int b = 0; b < NBATCH; ++b) s_pair[b * LMAX + l] = acc[b];
    }
    __syncthreads();

    // per-(b,n) CSR reduction (ascending l == reference order) + bias
    for (int bn = tid; bn < NBATCH * NND; bn += 256) {
        int b = bn / NND, n = bn - b * NND;
        int cnt = csr_cnt[bn];
        const int* lst = csr_list + (size_t)bn * LMAX;
        float sum = 0.f;
        for (int i = 0; i < cnt; ++i) sum += s_pair[b * LMAX + lst[i]];
        float bias = 0.f;
#pragma unroll
        for (int s = 0; s < 16; ++s)
            bias += s_mapw[n * 16 + s] * s_binc[s] + s_pe[(b << 4) + s] * s_binc[16 + s];
        beta[(size_t)bn * LMAX + t] = (sum + bias) * (1.0f / 32.0f);
    }
}

// ---------------------------------------------------------------- mean over t (deterministic)
__global__ void k_meanb(const float* __restrict__ beta, float* __restrict__ meanb) {
    int bn = blockIdx.x;       // 288
    int lane = threadIdx.x;    // 64
    const float* p = beta + (size_t)bn * LMAX;
    float s = 0.f;
    for (int t = lane; t < LMAX; t += 64) s += p[t];
    for (int off = 32; off > 0; off >>= 1) s += __shfl_xor(s, off);
    if (lane == 0) meanb[bn] = s / (float)LMAX;
}

// ---------------------------------------------------------------- stable top-K via rank selection
__global__ __launch_bounds__(256) void k_topk(const float* __restrict__ ew,
                                              const float* __restrict__ meanb,
                                              int* __restrict__ topi, float* __restrict__ alpha) {
    int chunk = blockIdx.x;    // 0..5  (216 elements each)
    int b = blockIdx.y;        // 0..7
    int tid = threadIdx.x;     // 256
    __shared__ float sv[NE];
    __shared__ float sm[NND];
    if (tid < NND) sm[tid] = meanb[b * NND + tid];
    __syncthreads();
    for (int e = tid; e < NE; e += 256) sv[e] = ew[e] * sm[e % NND];
    __syncthreads();
    int e = chunk * 216 + tid;
    if (tid < 216) {
        float v = sv[e];
        int rank = 0;
        for (int i = 0; i < NE; ++i) {
            float u = sv[i];
            rank += (u > v) || (u == v && i < e);
        }
        if (rank < NK) {
            topi[b * NK + rank] = e;
            alpha[b * NK + rank] = v;
        }
    }
}

// ---------------------------------------------------------------- message passing layer 1
__global__ void k_h1(const int* __restrict__ topi, const float* __restrict__ ew,
                     const float* __restrict__ beta, const int* __restrict__ idxarr,
                     const float* __restrict__ rr, float* h1) {
    int b = blockIdx.x / NND, n = blockIdx.x % NND;
    __shared__ int cnt;
    __shared__ int lsrc[40];
    __shared__ float lew[40];
    int tid = threadIdx.x;  // 256
    if (tid == 0) cnt = 0;
    __syncthreads();
    for (int k = tid; k < NK; k += 256) {
        int e = topi[b * NK + k];
        if (e % NND == n) {
            int p = atomicAdd(&cnt, 1);
            lsrc[p] = e / NND;
            lew[p] = ew[e];
        }
    }
    __syncthreads();
    int m = cnt;
    const float* bb = beta + ((size_t)b * NND + n) * LMAX;
    for (int c = tid; c < CW; c += 256) {
        int t = c >> 2, o = c & 3;
        float bt = bb[t];
        int id = idxarr[b * LMAX + t];
        float x = rr[id * 4 + o];
        float acc = 0.f;
        for (int j = 0; j < m; ++j) {
            float g = bt * lew[j];
            if (g > 0.f && lsrc[j] == id) acc += x * g;
        }
        h1[((size_t)b * NND + n) * CW + c] = acc;
    }
}

// ---------------------------------------------------------------- message passing layer 2
__global__ void k_h2(const int* __restrict__ topi, const float* __restrict__ alpha,
                     const float* __restrict__ h1, float* h2) {
    int b = blockIdx.x / NND, n = blockIdx.x % NND;
    __shared__ int cnt;
    __shared__ int lsrc[40];
    __shared__ float lal[40];
    int tid = threadIdx.x;
    if (tid == 0) cnt = 0;
    __syncthreads();
    for (int k = tid; k < NK; k += 256) {
        int e = topi[b * NK + k];
        if (e % NND == n) {
            int p = atomicAdd(&cnt, 1);
            lsrc[p] = e / NND;
            lal[p] = fmaxf(alpha[b * NK + k], 0.f);
        }
    }
    __syncthreads();
    int m = cnt;
    for (int c = tid; c < CW; c += 256) {
        float acc = 0.f;
        for (int j = 0; j < m; ++j)
            acc += fmaxf(h1[((size_t)b * NND + lsrc[j]) * CW + c], 0.f) * lal[j];
        h2[((size_t)b * NND + n) * CW + c] = acc;
    }
}

// ---------------------------------------------------------------- assemble transformer input
__global__ void k_x0(const float* __restrict__ h2, const float* __restrict__ pe, float* x) {
    int i = blockIdx.x * 256 + threadIdx.x;
    if (i >= NBATCH * LMAX * DTR) return;
    int ch = i % DTR; int bl = i / DTR; int l = bl % LMAX; int b = bl / LMAX;
    float v;
    if (ch < 144) {
        int n = ch >> 2, o = ch & 3;
        v = h2[((size_t)b * NND + n) * CW + 4 * l + o];
    } else {
        v = pe[(b * LMAX + l) * DPE + (ch - 144)];
    }
    x[i] = v;
}

// ---------------------------------------------------------------- distance
__global__ void k_dist(const float* __restrict__ alpha, float* outd) {
    __shared__ float s[64];
    int tid = threadIdx.x;  // 64
    int i = tid / 8, j = tid % 8;
    float d2 = 0.f;
    for (int k = 0; k < NK; ++k) {
        float d = alpha[i * NK + k] - alpha[j * NK + k];
        d2 += d * d;
    }
    s[tid] = (d2 > 0.f) ? sqrtf(d2) : 0.f;
    __syncthreads();
    for (int st = 32; st > 0; st >>= 1) { if (tid < st) s[tid] += s[tid + st]; __syncthreads(); }
    if (tid == 0) *outd = s[0] / 64.0f;
}

// ---------------------------------------------------------------- qkv GEMM: 2 rows/block, 256 thr
__global__ __launch_bounds__(256) void k_qkv(const float* __restrict__ X, const float* __restrict__ W,
                                             const float* __restrict__ bias, float* __restrict__ Y) {
    int m0 = blockIdx.x * 2;
    int tid = threadIdx.x;
    __shared__ float xs[2 * DTR];
    for (int i = tid; i < 2 * DTR; i += 256) xs[i] = X[(size_t)m0 * DTR + i];
    __syncthreads();
    for (int n = tid; n < 480; n += 256) {
        const float* wr = W + (size_t)n * DTR;
        float4 a0 = {0.f, 0.f, 0.f, 0.f};
        float4 a1 = {0.f, 0.f, 0.f, 0.f};
#pragma unroll 8
        for (int d = 0; d < DTR; d += 4) {
            float4 w4 = *(const float4*)(wr + d);
            float4 x0 = *(const float4*)&xs[d];
            float4 x1 = *(const float4*)&xs[DTR + d];
            a0.x += x0.x * w4.x; a0.y += x0.y * w4.y; a0.z += x0.z * w4.z; a0.w += x0.w * w4.w;
            a1.x += x1.x * w4.x; a1.y += x1.y * w4.y; a1.z += x1.z * w4.z; a1.w += x1.w * w4.w;
        }
        float bv = bias[n];
        Y[(size_t)m0 * 480 + n]       = bv + (a0.x + a0.y) + (a0.z + a0.w);
        Y[(size_t)(m0 + 1) * 480 + n] = bv + (a1.x + a1.y) + (a1.z + a1.w);
    }
}

// ---------------------------------------------------------------- attention partials (flash k-split)
__global__ __launch_bounds__(256) void k_attn_part(const float* __restrict__ qkv,
                                                   const int* __restrict__ lens,
                                                   float* __restrict__ part) {
    int kq = blockIdx.x;           // 0..3
    int bh = blockIdx.y;           // 0..31
    int b = bh >> 2, h = bh & 3;
    int tid = threadIdx.x;         // 256
    int k0 = kq * KQLEN;
    int k1 = min(LMAX, k0 + KQLEN);
    int klen = k1 - k0;
    __shared__ float sK[KQLEN * DH];
    __shared__ float sV[KQLEN * DH];
    for (int i = tid; i < klen * DH; i += 256) {
        int kk = i / DH, d = i - kk * DH;
        size_t base = (size_t)(b * LMAX + k0 + kk) * 480;
        sK[i] = qkv[base + DTR + h * DH + d];
        sV[i] = qkv[base + 2 * DTR + h * DH + d];
    }
    __syncthreads();
    int q = tid;
    if (q >= LMAX) return;
    float4 qv[10];
    const float4* qr = (const float4*)(qkv + (size_t)(b * LMAX + q) * 480 + h * DH);
#pragma unroll
    for (int i = 0; i < 10; ++i) qv[i] = qr[i];
    int len = lens[b];
    const float scale = 0.15811388300841898f;
    float m = -INFINITY, l = 0.f;
    float o[DH];
#pragma unroll
    for (int d = 0; d < DH; ++d) o[d] = 0.f;
    int kend = min(k1, len);
    for (int k = k0; k < kend; ++k) {
        const float4* kr = (const float4*)&sK[(k - k0) * DH];
        float s0 = 0.f, s1 = 0.f, s2 = 0.f, s3 = 0.f;
#pragma unroll
        for (int i = 0; i < 10; ++i) {
            float4 kv = kr[i];
            s0 += qv[i].x * kv.x; s1 += qv[i].y * kv.y;
            s2 += qv[i].z * kv.z; s3 += qv[i].w * kv.w;
        }
        float s = ((s0 + s1) + (s2 + s3)) * scale;
        float p;
        if (s <= m) {
            p = expf(s - m);
        } else {
            float c = expf(m - s);
#pragma unroll
            for (int d = 0; d < DH; ++d) o[d] *= c;
            l *= c;
            m = s;
            p = 1.0f;
        }
        l += p;
        const float* vr = &sV[(k - k0) * DH];
#pragma unroll
        for (int d = 0; d < DH; ++d) o[d] += p * vr[d];
    }
    float* pp = part + ((size_t)(bh * KSPLIT + kq) * LMAX + q) * 42;
#pragma unroll
    for (int d = 0; d < DH; ++d) pp[d] = o[d];
    pp[40] = l;
    pp[41] = m;
}

// ---------------------------------------------------------------- attention merge (4 partials -> ctx)
__global__ __launch_bounds__(256) void k_attn_merge(const float* __restrict__ part,
                                                    float* __restrict__ ctx) {
    int row = blockIdx.x;          // b*LMAX+q
    int b = row / LMAX, q = row - b * LMAX;
    int tid = threadIdx.x;         // 256
    int h = tid >> 6, lane = tid & 63;
    int bh = b * NHEADS + h;
    const float* p0 = part + ((size_t)(bh * KSPLIT + 0) * LMAX + q) * 42;
    const float* p1 = part + ((size_t)(bh * KSPLIT + 1) * LMAX + q) * 42;
    const float* p2 = part + ((size_t)(bh * KSPLIT + 2) * LMAX + q) * 42;
    const float* p3 = part + ((size_t)(bh * KSPLIT + 3) * LMAX + q) * 42;
    float m0 = p0[41], m1 = p1[41], m2 = p2[41], m3 = p3[41];
    float ms = fmaxf(fmaxf(m0, m1), fmaxf(m2, m3));
    float w0 = expf(m0 - ms), w1 = expf(m1 - ms), w2 = expf(m2 - ms), w3 = expf(m3 - ms);
    float lsum = w0 * p0[40] + w1 * p1[40] + w2 * p2[40] + w3 * p3[40];
    float inv = 1.0f / lsum;
    if (lane < DH) {
        float acc = w0 * p0[lane] + w1 * p1[lane] + w2 * p2[lane] + w3 * p3[lane];
        ctx[(size_t)row * DTR + h * DH + lane] = acc * inv;
    }
}

// ---------------------------------------------------------------- device LN helper (per-wave over one row in LDS)
__device__ __forceinline__ void wave_ln_row(const float* __restrict__ row, int lane,
                                            const float* __restrict__ lnw, const float* __restrict__ lnb,
                                            float* __restrict__ dst) {
    float s = 0.f;
    for (int d = lane; d < DTR; d += 64) s += row[d];
    for (int off = 32; off > 0; off >>= 1) s += __shfl_xor(s, off);
    float mu = s / (float)DTR;
    float v = 0.f;
    for (int d = lane; d < DTR; d += 64) { float dd = row[d] - mu; v += dd * dd; }
    for (int off = 32; off > 0; off >>= 1) v += __shfl_xor(v, off);
    float rs = rsqrtf(v / (float)DTR + 1e-5f);
    for (int d = lane; d < DTR; d += 64)
        dst[d] = (row[d] - mu) * rs * lnw[d] + lnb[d];
}

// ---------------------------------------------------------------- fused out-proj + residual + LN1 (2 rows, 256 thr)
__global__ __launch_bounds__(256) void k_projln(const float* __restrict__ ctx, const float* __restrict__ xres,
                                                const float* __restrict__ W, const float* __restrict__ bias,
                                                const float* __restrict__ lnw, const float* __restrict__ lnb,
                                                float* __restrict__ out) {
    int m0 = blockIdx.x * 2;
    int tid = threadIdx.x;  // 256
    __shared__ float xs[2 * DTR];
    __shared__ float ys[2 * DTR];
    for (int i = tid; i < 2 * DTR; i += 256) xs[i] = ctx[(size_t)m0 * DTR + i];
    __syncthreads();
    if (tid < DTR) {
        int n = tid;
        const float* wr = W + (size_t)n * DTR;
        float4 a0 = {0.f, 0.f, 0.f, 0.f};
        float4 a1 = {0.f, 0.f, 0.f, 0.f};
#pragma unroll 8
        for (int d = 0; d < DTR; d += 4) {
            float4 w4 = *(const float4*)(wr + d);
            float4 x0 = *(const float4*)&xs[d];
            float4 x1 = *(const float4*)&xs[DTR + d];
            a0.x += x0.x * w4.x; a0.y += x0.y * w4.y; a0.z += x0.z * w4.z; a0.w += x0.w * w4.w;
            a1.x += x1.x * w4.x; a1.y += x1.y * w4.y; a1.z += x1.z * w4.z; a1.w += x1.w * w4.w;
        }
        float bv = bias[n];
        ys[n]       = bv + (a0.x + a0.y) + (a0.z + a0.w) + xres[(size_t)m0 * DTR + n];
        ys[DTR + n] = bv + (a1.x + a1.y) + (a1.z + a1.w) + xres[(size_t)(m0 + 1) * DTR + n];
    }
    __syncthreads();
    int wid = tid >> 6, lane = tid & 63;
    if (wid < 2)
        wave_ln_row(&ys[wid * DTR], lane, lnw, lnb, out + (size_t)(m0 + wid) * DTR);
}

// ---------------------------------------------------------------- fused FF1+relu+FF2 + residual + LN2 (2 rows, 256 thr)
__global__ __launch_bounds__(256) void k_ffln(const float* __restrict__ xin,
                                              const float* __restrict__ W1, const float* __restrict__ b1,
                                              const float* __restrict__ W2, const float* __restrict__ b2,
                                              const float* __restrict__ lnw, const float* __restrict__ lnb,
                                              float* __restrict__ out) {
    int m0 = blockIdx.x * 2;
    int tid = threadIdx.x;  // 256
    __shared__ float xs[2 * DTR];
    __shared__ float hs[2 * NHID2];
    __shared__ float zs[2 * DTR];
    for (int i = tid; i < 2 * DTR; i += 256) xs[i] = xin[(size_t)m0 * DTR + i];
    __syncthreads();
    {
        int n = tid;  // all 256 active
        const float* wr = W1 + (size_t)n * DTR;
        float4 a0 = {0.f, 0.f, 0.f, 0.f};
        float4 a1 = {0.f, 0.f, 0.f, 0.f};
#pragma unroll 8
        for (int d = 0; d < DTR; d += 4) {
            float4 w4 = *(const float4*)(wr + d);
            float4 x0 = *(const float4*)&xs[d];
            float4 x1 = *(const float4*)&xs[DTR + d];
            a0.x += x0.x * w4.x; a0.y += x0.y * w4.y; a0.z += x0.z * w4.z; a0.w += x0.w * w4.w;
            a1.x += x1.x * w4.x; a1.y += x1.y * w4.y; a1.z += x1.z * w4.z; a1.w += x1.w * w4.w;
        }
        float bv = b1[n];
        hs[n]         = fmaxf(bv + (a0.x + a0.y) + (a0.z + a0.w), 0.f);
        hs[NHID2 + n] = fmaxf(bv + (a1.x + a1.y) + (a1.z + a1.w), 0.f);
    }
    __syncthreads();
    if (tid < DTR) {
        int n = tid;
        const float* wr = W2 + (size_t)n * NHID2;
        float4 a0 = {0.f, 0.f, 0.f, 0.f};
        float4 a1 = {0.f, 0.f, 0.f, 0.f};
#pragma unroll 8
        for (int d = 0; d < NHID2; d += 4) {
            float4 w4 = *(const float4*)(wr + d);
            float4 h0 = *(const float4*)&hs[d];
            float4 h1v = *(const float4*)&hs[NHID2 + d];
            a0.x += h0.x * w4.x; a0.y += h0.y * w4.y; a0.z += h0.z * w4.z; a0.w += h0.w * w4.w;
            a1.x += h1v.x * w4.x; a1.y += h1v.y * w4.y; a1.z += h1v.z * w4.z; a1.w += h1v.w * w4.w;
        }
        float bv = b2[n];
        zs[n]       = bv + (a0.x + a0.y) + (a0.z + a0.w) + xs[n];
        zs[DTR + n] = bv + (a1.x + a1.y) + (a1.z + a1.w) + xs[DTR + n];
    }
    __syncthreads();
    int wid = tid >> 6, lane = tid & 63;
    if (wid < 2)
        wave_ln_row(&zs[wid * DTR], lane, lnw, lnb, out + (size_t)(m0 + wid) * DTR);
}

// ---------------------------------------------------------------- final: copy output + preds
__global__ void k_pred(const float* __restrict__ x, const float* __restrict__ wty,
                       const float* __restrict__ wti, const int* __restrict__ lens,
                       float* __restrict__ out) {
    int row = blockIdx.x; int b = row / LMAX; int l = row % LMAX;
    __shared__ float xs[DTR];
    int tid = threadIdx.x;  // 64
    for (int d = tid; d < DTR; d += 64) xs[d] = x[(size_t)row * DTR + d];
    __syncthreads();
    float np = (l < lens[b]) ? 1.f : 0.f;
    if (tid < 37) {
        const float* w = (tid < 36) ? (wty + tid * DTR) : wti;
        float acc = 0.f;
#pragma unroll 8
        for (int d = 0; d < DTR; d += 4) {
            float4 w4 = *(const float4*)(w + d);
            acc += xs[d] * w4.x + xs[d + 1] * w4.y + xs[d + 2] * w4.z + xs[d + 3] * w4.w;
        }
        acc *= np;
        if (tid < 36) out[OUT_TYPE + (size_t)row * NND + tid] = acc;
        else out[OUT_TIME + row] = acc;
    }
    for (int d = tid; d < DTR; d += 64) out[(size_t)row * DTR + d] = xs[d];
}

// ---------------------------------------------------------------- launch
extern "C" void kernel_launch(void* const* d_in, const int* in_sizes, int n_in,
                              void* d_out, int out_size, void* d_ws, size_t ws_size,
                              hipStream_t stream) {
    const int* et      = (const int*)d_in[0];
    const float* etime = (const float*)d_in[1];
    const float* Ru    = (const float*)d_in[2];
    const float* gs    = (const float*)d_in[3];
    const float* Winc  = (const float*)d_in[4];
    const float* binc  = (const float*)d_in[5];
    const float* mapw  = (const float*)d_in[6];
    const float* wtime = (const float*)d_in[7];
    const float* wtype = (const float*)d_in[8];

    float* ws   = (float*)d_ws;
    float* pe   = ws + OFF_PE;
    float* rr   = ws + OFF_RR;
    float* ew   = ws + OFF_EW;
    float* beta = ws + OFF_BETA;
    float* meanb= ws + OFF_MEANB;
    float* alpha= ws + OFF_ALPHA;
    float* h1   = ws + OFF_H1;
    float* h2   = ws + OFF_H2;
    float* x    = ws + OFF_X;
    float* x2   = ws + OFF_X2;
    float* qkvb = ws + OFF_QKV;
    float* ctx  = ws + OFF_CTX;
    float* part = ws + OFF_PART;
    int* topi   = (int*)(ws + OFF_TOPI);
    int* idxarr = (int*)(ws + OFF_IDX);
    int* lens   = (int*)(ws + OFF_LENS);
    int* csrc   = (int*)(ws + OFF_CSRC);
    int* csrl   = (int*)(ws + OFF_CSRL);
    float* outp = (float*)d_out;

    k_prep<<<73, 256, 0, stream>>>(et, etime, Ru, gs, pe, rr, ew, idxarr, lens, csrc, csrl);
    k_beta<<<LMAX, 256, 0, stream>>>(Winc, binc, mapw, pe, rr, idxarr, csrc, csrl, beta);
    k_meanb<<<NBATCH * NND, 64, 0, stream>>>(beta, meanb);
    k_topk<<<dim3(6, NBATCH), 256, 0, stream>>>(ew, meanb, topi, alpha);
    k_h1<<<NBATCH * NND, 256, 0, stream>>>(topi, ew, beta, idxarr, rr, h1);
    k_h2<<<NBATCH * NND, 256, 0, stream>>>(topi, alpha, h1, h2);
    k_x0<<<(NBATCH * LMAX * DTR + 255) / 256, 256, 0, stream>>>(h2, pe, x);
    k_dist<<<1, 64, 0, stream>>>(alpha, outp + OUT_DIST);

    const int MB2 = NPAIR / 2;  // 860 two-row tiles
    for (int layer = 0; layer < 2; ++layer) {
        int base = 9 + layer * 12;
        const float* qkv_w = (const float*)d_in[base + 0];
        const float* qkv_b = (const float*)d_in[base + 1];
        const float* out_w = (const float*)d_in[base + 2];
        const float* out_b = (const float*)d_in[base + 3];
        const float* ff1_w = (const float*)d_in[base + 4];
        const float* ff1_b = (const float*)d_in[base + 5];
        const float* ff2_w = (const float*)d_in[base + 6];
        const float* ff2_b = (const float*)d_in[base + 7];
        const float* ln1_w = (const float*)d_in[base + 8];
        const float* ln1_b = (const float*)d_in[base + 9];
        const float* ln2_w = (const float*)d_in[base + 10];
        const float* ln2_b = (const float*)d_in[base + 11];

        k_qkv<<<MB2, 256, 0, stream>>>(x, qkv_w, qkv_b, qkvb);
        k_attn_part<<<dim3(KSPLIT, NBATCH * NHEADS), 256, 0, stream>>>(qkvb, lens, part);
        k_attn_merge<<<NPAIR, 256, 0, stream>>>(part, ctx);
        k_projln<<<MB2, 256, 0, stream>>>(ctx, x, out_w, out_b, ln1_w, ln1_b, x2);
        k_ffln<<<MB2, 256, 0, stream>>>(x2, ff1_w, ff1_b, ff2_w, ff2_b, ln2_w, ln2_b, x);
    }

    k_pred<<<NPAIR, 64, 0, stream>>>(x, wtype, wtime, lens, outp);
}

// Round 10
// 509.673 us; speedup vs baseline: 2.6884x; 1.0336x over previous
//
#include <hip/hip_runtime.h>
#include <math.h>

#define NBATCH 8
#define LMAX   215
#define NND    36
#define NE     1296
#define NK     648
#define CW     860      // C = LMAX*4
#define DPE    16
#define DTR    160
#define NHEADS 4
#define DH     40
#define NHID2  256
#define NPAIR  (NBATCH*LMAX)   // 1720
#define KSPLIT 8
#define KQLEN  27              // ceil(215/8)

// output layout (floats)
#define OUT_TYPE (NBATCH*LMAX*DTR)              // 275200
#define OUT_TIME (OUT_TYPE + NBATCH*LMAX*NND)   // 337120
#define OUT_DIST (OUT_TIME + NBATCH*LMAX)       // 338840

// workspace layout (float offsets)
#define OFF_PE    0
#define OFF_RR    (OFF_PE + NBATCH*LMAX*DPE)
#define OFF_EW    (OFF_RR + 144)
#define OFF_BETA  (OFF_EW + NE)
#define OFF_MEANB (OFF_BETA + NBATCH*NND*LMAX)
#define OFF_ALPHA (OFF_MEANB + NBATCH*NND)
#define OFF_H1    (OFF_ALPHA + NBATCH*NK)
#define OFF_X     (OFF_H1 + NBATCH*NND*CW)
#define OFF_X2    (OFF_X + NBATCH*LMAX*DTR)
#define OFF_QKV   (OFF_X2 + NBATCH*LMAX*DTR)
#define OFF_TOPI  (OFF_QKV + NBATCH*LMAX*480)
#define OFF_IDX   (OFF_TOPI + NBATCH*NK)
#define OFF_LENS  (OFF_IDX + NBATCH*LMAX)
#define OFF_PART  (OFF_LENS + NBATCH)
#define OFF_CSRC  (OFF_PART + 32*KSPLIT*LMAX*42)
#define OFF_CSRL  (OFF_CSRC + NBATCH*NND)

// ---------------------------------------------------------------- prep (parallel: 73 blocks)
__global__ __launch_bounds__(256) void k_prep(
        const int* __restrict__ et, const float* __restrict__ etime,
        const float* __restrict__ Ru, const float* __restrict__ gs,
        float* pe, float* rr, float* ew, int* idxarr, int* lens,
        int* csr_cnt, int* csr_list, float* __restrict__ x) {
    int blk = blockIdx.x, tid = threadIdx.x;
    if (blk == 0) {
        for (int c = tid; c < 144; c += 256) rr[c] = fmaxf(Ru[c], 0.f);
        for (int e = tid; e < NE; e += 256) {
            int r = e / NND, cc = e % NND;
            ew[e] = (r == cc) ? 1.0f : gs[e];
        }
    } else if (blk <= 8) {
        int b = blk - 1;
        __shared__ int red[256];
        __shared__ int sidx[LMAX];
        int cnt = 0;
        for (int l = tid; l < LMAX; l += 256) {
            int v = et[b * LMAX + l];
            cnt += (v != 0);
            int ix = max(v - 1, 0);
            idxarr[b * LMAX + l] = ix;
            sidx[l] = ix;
        }
        red[tid] = cnt;
        __syncthreads();
        for (int st = 128; st > 0; st >>= 1) { if (tid < st) red[tid] += red[tid + st]; __syncthreads(); }
        if (tid == 0) lens[b] = red[0];
        if (tid < NND) {
            int c = 0;
            int* lst = csr_list + (size_t)(b * NND + tid) * LMAX;
            for (int l = 0; l < LMAX; ++l)
                if (sidx[l] == tid) { lst[c] = l; ++c; }
            csr_cnt[b * NND + tid] = c;
        }
    } else {
        __shared__ float sts[8];
        if (tid < 8) sts[tid] = (float)pow(215.0, (double)tid / 7.0);
        __syncthreads();
        int i0 = (blk - 9) * 430;
        for (int i = i0 + tid; i < i0 + 430; i += 256) {
            int s = i & 15; int bl = i >> 4;
            float t = etime[bl];
            float sc = t / sts[s & 7];
            float v = (s < 8) ? sinf(sc) : cosf(sc);
            pe[i] = v;
            x[(size_t)bl * DTR + 144 + s] = v;   // PE columns of transformer input
        }
    }
}

// ---------------------------------------------------------------- beta (thread-owns-l, b-loop in regs, CSR reduce)
__global__ __launch_bounds__(256) void k_beta(
        const float* __restrict__ Winc, const float* __restrict__ binc,
        const float* __restrict__ mapw, const float* __restrict__ pe,
        const float* __restrict__ rr, const int* __restrict__ idxarr,
        const int* __restrict__ csr_cnt, const int* __restrict__ csr_list,
        float* __restrict__ beta) {
    const int t = blockIdx.x;        // 0..214
    const int tid = threadIdx.x;     // 256

    __shared__ float s_rows[2][4 * CW];
    __shared__ float s_pair[NBATCH * LMAX];
    __shared__ int   s_idx[NPAIR];
    __shared__ float s_mapw[NND * 16];
    __shared__ float s_rr[144];
    __shared__ float s_pe[NBATCH * 16];
    __shared__ float s_binc[32];

    for (int i = tid; i < NPAIR; i += 256) s_idx[i] = idxarr[i];
    for (int i = tid; i < NND * 16; i += 256) s_mapw[i] = mapw[i];
    if (tid < 144) s_rr[tid] = rr[tid];
    if (tid < 128) { int b = tid >> 4, s = tid & 15; s_pe[tid] = pe[((size_t)(b * LMAX + t)) * DPE + s]; }
    if (tid < 32) s_binc[tid] = binc[32 * t + tid];

    float4 pre[4];
    {
        const float4* src = (const float4*)(Winc + (size_t)(32 * t) * CW);
#pragma unroll
        for (int i = 0; i < 4; ++i) { int k = tid + i * 256; if (k < CW) pre[i] = src[k]; }
    }
    __syncthreads();

    const int l = tid;
    int nb[NBATCH];
    float4 r4b[NBATCH];
    if (l < LMAX) {
#pragma unroll
        for (int b = 0; b < NBATCH; ++b) {
            nb[b] = s_idx[b * LMAX + l];
            r4b[b] = *(const float4*)&s_rr[4 * nb[b]];
        }
    }
    float acc[NBATCH];
#pragma unroll
    for (int b = 0; b < NBATCH; ++b) acc[b] = 0.f;

    int p = 0;
    for (int jc = 0; jc < 8; ++jc) {
        float4* buf = (float4*)&s_rows[p][0];
#pragma unroll
        for (int i = 0; i < 4; ++i) { int k = tid + i * 256; if (k < CW) buf[k] = pre[i]; }
        __syncthreads();
        if (jc < 7) {
            const float4* src = (const float4*)(Winc + (size_t)(32 * t + 4 * (jc + 1)) * CW);
#pragma unroll
            for (int i = 0; i < 4; ++i) { int k = tid + i * 256; if (k < CW) pre[i] = src[k]; }
        }
        if (l < LMAX) {
            if (jc < 4) {
#pragma unroll
                for (int jj = 0; jj < 4; ++jj) {
                    int j = 4 * jc + jj;
                    float4 w4 = *(const float4*)&s_rows[p][jj * CW + 4 * l];
#pragma unroll
                    for (int b = 0; b < NBATCH; ++b) {
                        float dv = r4b[b].x * w4.x + r4b[b].y * w4.y + r4b[b].z * w4.z + r4b[b].w * w4.w;
                        acc[b] += s_mapw[nb[b] * 16 + j] * dv;
                    }
                }
            } else {
#pragma unroll
                for (int jj = 0; jj < 4; ++jj) {
                    int j = 4 * jc + jj;
                    float4 w4 = *(const float4*)&s_rows[p][jj * CW + 4 * l];
#pragma unroll
                    for (int b = 0; b < NBATCH; ++b) {
                        float dv = r4b[b].x * w4.x + r4b[b].y * w4.y + r4b[b].z * w4.z + r4b[b].w * w4.w;
                        acc[b] += s_pe[(b << 4) + (j - 16)] * dv;
                    }
                }
            }
        }
        __syncthreads();
        p ^= 1;
    }

    if (l < LMAX) {
#pragma unroll
        for (int b = 0; b < NBATCH; ++b) s_pair[b * LMAX + l] = acc[b];
    }
    __syncthreads();

    for (int bn = tid; bn < NBATCH * NND; bn += 256) {
        int b = bn / NND, n = bn - b * NND;
        int cnt = csr_cnt[bn];
        const int* lst = csr_list + (size_t)bn * LMAX;
        float sum = 0.f;
        for (int i = 0; i < cnt; ++i) sum += s_pair[b * LMAX + lst[i]];
        float bias = 0.f;
#pragma unroll
        for (int s = 0; s < 16; ++s)
            bias += s_mapw[n * 16 + s] * s_binc[s] + s_pe[(b << 4) + s] * s_binc[16 + s];
        beta[(size_t)bn * LMAX + t] = (sum + bias) * (1.0f / 32.0f);
    }
}

// ---------------------------------------------------------------- top-K with fused meanb (bitwise-identical reduce)
__global__ __launch_bounds__(256) void k_topk(const float* __restrict__ ew,
                                              const float* __restrict__ beta,
                                              int* __restrict__ topi, float* __restrict__ alpha) {
    int chunk = blockIdx.x;    // 0..5  (216 elements each)
    int b = blockIdx.y;        // 0..7
    int tid = threadIdx.x;     // 256
    __shared__ float sv[NE];
    __shared__ float sm[NND];
    int wv = tid >> 6, lane = tid & 63;
    for (int n = wv; n < NND; n += 4) {            // same order as old k_meanb -> bitwise identical
        const float* p = beta + (size_t)(b * NND + n) * LMAX;
        float s = 0.f;
        for (int t = lane; t < LMAX; t += 64) s += p[t];
        for (int off = 32; off > 0; off >>= 1) s += __shfl_xor(s, off);
        if (lane == 0) sm[n] = s / (float)LMAX;
    }
    __syncthreads();
    for (int e = tid; e < NE; e += 256) sv[e] = ew[e] * sm[e % NND];
    __syncthreads();
    int e = chunk * 216 + tid;
    if (tid < 216) {
        float v = sv[e];
        int rank = 0;
        for (int i = 0; i < NE; ++i) {
            float u = sv[i];
            rank += (u > v) || (u == v && i < e);
        }
        if (rank < NK) {
            topi[b * NK + rank] = e;
            alpha[b * NK + rank] = v;
        }
    }
}

// ---------------------------------------------------------------- message passing layer 1 (+ fused distance in block 0)
__global__ void k_h1(const int* __restrict__ topi, const float* __restrict__ ew,
                     const float* __restrict__ beta, const int* __restrict__ idxarr,
                     const float* __restrict__ rr, const float* __restrict__ alpha,
                     float* h1, float* __restrict__ outd) {
    int b = blockIdx.x / NND, n = blockIdx.x % NND;
    __shared__ int cnt;
    __shared__ int lsrc[40];
    __shared__ float lew[40];
    int tid = threadIdx.x;  // 256
    if (tid == 0) cnt = 0;
    __syncthreads();
    for (int k = tid; k < NK; k += 256) {
        int e = topi[b * NK + k];
        if (e % NND == n) {
            int p = atomicAdd(&cnt, 1);
            lsrc[p] = e / NND;
            lew[p] = ew[e];
        }
    }
    __syncthreads();
    int m = cnt;
    const float* bb = beta + ((size_t)b * NND + n) * LMAX;
    for (int c = tid; c < CW; c += 256) {
        int t = c >> 2, o = c & 3;
        float bt = bb[t];
        int id = idxarr[b * LMAX + t];
        float x = rr[id * 4 + o];
        float acc = 0.f;
        for (int j = 0; j < m; ++j) {
            float g = bt * lew[j];
            if (g > 0.f && lsrc[j] == id) acc += x * g;
        }
        h1[((size_t)b * NND + n) * CW + c] = acc;
    }
    if (blockIdx.x == 0) {   // fused distance (uniform branch per block)
        __shared__ float sd[64];
        if (tid < 64) {
            int i = tid / 8, j = tid % 8;
            float d2 = 0.f;
            for (int k = 0; k < NK; ++k) {
                float d = alpha[i * NK + k] - alpha[j * NK + k];
                d2 += d * d;
            }
            sd[tid] = (d2 > 0.f) ? sqrtf(d2) : 0.f;
        }
        __syncthreads();
        for (int st = 32; st > 0; st >>= 1) { if (tid < st) sd[tid] += sd[tid + st]; __syncthreads(); }
        if (tid == 0) *outd = sd[0] / 64.0f;
    }
}

// ---------------------------------------------------------------- message passing layer 2 -> writes x directly
__global__ void k_h2(const int* __restrict__ topi, const float* __restrict__ alpha,
                     const float* __restrict__ h1, float* __restrict__ x) {
    int b = blockIdx.x / NND, n = blockIdx.x % NND;
    __shared__ int cnt;
    __shared__ int lsrc[40];
    __shared__ float lal[40];
    int tid = threadIdx.x;
    if (tid == 0) cnt = 0;
    __syncthreads();
    for (int k = tid; k < NK; k += 256) {
        int e = topi[b * NK + k];
        if (e % NND == n) {
            int p = atomicAdd(&cnt, 1);
            lsrc[p] = e / NND;
            lal[p] = fmaxf(alpha[b * NK + k], 0.f);
        }
    }
    __syncthreads();
    int m = cnt;
    for (int c = tid; c < CW; c += 256) {
        float acc = 0.f;
        for (int j = 0; j < m; ++j)
            acc += fmaxf(h1[((size_t)b * NND + lsrc[j]) * CW + c], 0.f) * lal[j];
        x[(size_t)(b * LMAX + (c >> 2)) * DTR + 4 * n + (c & 3)] = acc;
    }
}

// ---------------------------------------------------------------- qkv GEMM: 2 rows/block, 256 thr
__global__ __launch_bounds__(256) void k_qkv(const float* __restrict__ X, const float* __restrict__ W,
                                             const float* __restrict__ bias, float* __restrict__ Y) {
    int m0 = blockIdx.x * 2;
    int tid = threadIdx.x;
    __shared__ float xs[2 * DTR];
    for (int i = tid; i < 2 * DTR; i += 256) xs[i] = X[(size_t)m0 * DTR + i];
    __syncthreads();
    for (int n = tid; n < 480; n += 256) {
        const float* wr = W + (size_t)n * DTR;
        float4 a0 = {0.f, 0.f, 0.f, 0.f};
        float4 a1 = {0.f, 0.f, 0.f, 0.f};
#pragma unroll 8
        for (int d = 0; d < DTR; d += 4) {
            float4 w4 = *(const float4*)(wr + d);
            float4 x0 = *(const float4*)&xs[d];
            float4 x1 = *(const float4*)&xs[DTR + d];
            a0.x += x0.x * w4.x; a0.y += x0.y * w4.y; a0.z += x0.z * w4.z; a0.w += x0.w * w4.w;
            a1.x += x1.x * w4.x; a1.y += x1.y * w4.y; a1.z += x1.z * w4.z; a1.w += x1.w * w4.w;
        }
        float bv = bias[n];
        Y[(size_t)m0 * 480 + n]       = bv + (a0.x + a0.y) + (a0.z + a0.w);
        Y[(size_t)(m0 + 1) * 480 + n] = bv + (a1.x + a1.y) + (a1.z + a1.w);
    }
}

// ---------------------------------------------------------------- attention partials (flash 8-way k-split)
__global__ __launch_bounds__(256) void k_attn_part(const float* __restrict__ qkv,
                                                   const int* __restrict__ lens,
                                                   float* __restrict__ part) {
    int kq = blockIdx.x;           // 0..7
    int bh = blockIdx.y;           // 0..31
    int b = bh >> 2, h = bh & 3;
    int tid = threadIdx.x;         // 256
    int k0 = kq * KQLEN;
    int k1 = min(LMAX, k0 + KQLEN);
    int klen = max(k1 - k0, 0);
    __shared__ float sK[KQLEN * DH];
    __shared__ float sV[KQLEN * DH];
    for (int i = tid; i < klen * DH; i += 256) {
        int kk = i / DH, d = i - kk * DH;
        size_t base = (size_t)(b * LMAX + k0 + kk) * 480;
        sK[i] = qkv[base + DTR + h * DH + d];
        sV[i] = qkv[base + 2 * DTR + h * DH + d];
    }
    __syncthreads();
    int q = tid;
    if (q >= LMAX) return;
    float4 qv[10];
    const float4* qr = (const float4*)(qkv + (size_t)(b * LMAX + q) * 480 + h * DH);
#pragma unroll
    for (int i = 0; i < 10; ++i) qv[i] = qr[i];
    int len = lens[b];
    const float scale = 0.15811388300841898f;
    float m = -INFINITY, l = 0.f;
    float o[DH];
#pragma unroll
    for (int d = 0; d < DH; ++d) o[d] = 0.f;
    int kend = min(k1, len);
    for (int k = k0; k < kend; ++k) {
        const float4* kr = (const float4*)&sK[(k - k0) * DH];
        float s0 = 0.f, s1 = 0.f, s2 = 0.f, s3 = 0.f;
#pragma unroll
        for (int i = 0; i < 10; ++i) {
            float4 kv = kr[i];
            s0 += qv[i].x * kv.x; s1 += qv[i].y * kv.y;
            s2 += qv[i].z * kv.z; s3 += qv[i].w * kv.w;
        }
        float s = ((s0 + s1) + (s2 + s3)) * scale;
        float p;
        if (s <= m) {
            p = expf(s - m);
        } else {
            float c = expf(m - s);
#pragma unroll
            for (int d = 0; d < DH; ++d) o[d] *= c;
            l *= c;
            m = s;
            p = 1.0f;
        }
        l += p;
        const float* vr = &sV[(k - k0) * DH];
#pragma unroll
        for (int d = 0; d < DH; ++d) o[d] += p * vr[d];
    }
    float* pp = part + ((size_t)(bh * KSPLIT + kq) * LMAX + q) * 42;
#pragma unroll
    for (int d = 0; d < DH; ++d) pp[d] = o[d];
    pp[40] = l;
    pp[41] = m;
}

// ---------------------------------------------------------------- device LN helper
__device__ __forceinline__ void wave_ln_row(const float* __restrict__ row, int lane,
                                            const float* __restrict__ lnw, const float* __restrict__ lnb,
                                            float* __restrict__ dst) {
    float s = 0.f;
    for (int d = lane; d < DTR; d += 64) s += row[d];
    for (int off = 32; off > 0; off >>= 1) s += __shfl_xor(s, off);
    float mu = s / (float)DTR;
    float v = 0.f;
    for (int d = lane; d < DTR; d += 64) { float dd = row[d] - mu; v += dd * dd; }
    for (int off = 32; off > 0; off >>= 1) v += __shfl_xor(v, off);
    float rs = rsqrtf(v / (float)DTR + 1e-5f);
    for (int d = lane; d < DTR; d += 64)
        dst[d] = (row[d] - mu) * rs * lnw[d] + lnb[d];
}

// ---------------------------------------------------------------- fused merge + out-proj + residual + LN1 (2 rows)
__global__ __launch_bounds__(256) void k_projln(const float* __restrict__ part, const float* __restrict__ xres,
                                                const float* __restrict__ W, const float* __restrict__ bias,
                                                const float* __restrict__ lnw, const float* __restrict__ lnb,
                                                float* __restrict__ out) {
    int m0 = blockIdx.x * 2;
    int tid = threadIdx.x;  // 256
    __shared__ float xs[2 * DTR];
    __shared__ float ys[2 * DTR];
    int g = tid >> 6, lane = tid & 63;
    for (int pr = g; pr < 8; pr += 4) {       // merge 8 k-split partials -> ctx rows in LDS
        int r = pr >> 2, h = pr & 3;
        int row = m0 + r;
        int b = row / LMAX, q = row - b * LMAX;
        const float* pb = part + ((size_t)((b * NHEADS + h) * KSPLIT) * LMAX + q) * 42;
        const size_t st = (size_t)LMAX * 42;
        float ms = -INFINITY;
#pragma unroll
        for (int i = 0; i < KSPLIT; ++i) ms = fmaxf(ms, pb[i * st + 41]);
        float lsum = 0.f, acc = 0.f;
#pragma unroll
        for (int i = 0; i < KSPLIT; ++i) {
            float w = expf(pb[i * st + 41] - ms);
            lsum += w * pb[i * st + 40];
            if (lane < DH) acc += w * pb[i * st + lane];
        }
        if (lane < DH) xs[r * DTR + h * DH + lane] = acc / lsum;
    }
    __syncthreads();
    if (tid < DTR) {
        int n = tid;
        const float* wr = W + (size_t)n * DTR;
        float4 a0 = {0.f, 0.f, 0.f, 0.f};
        float4 a1 = {0.f, 0.f, 0.f, 0.f};
#pragma unroll 8
        for (int d = 0; d < DTR; d += 4) {
            float4 w4 = *(const float4*)(wr + d);
            float4 x0 = *(const float4*)&xs[d];
            float4 x1 = *(const float4*)&xs[DTR + d];
            a0.x += x0.x * w4.x; a0.y += x0.y * w4.y; a0.z += x0.z * w4.z; a0.w += x0.w * w4.w;
            a1.x += x1.x * w4.x; a1.y += x1.y * w4.y; a1.z += x1.z * w4.z; a1.w += x1.w * w4.w;
        }
        float bv = bias[n];
        ys[n]       = bv + (a0.x + a0.y) + (a0.z + a0.w) + xres[(size_t)m0 * DTR + n];
        ys[DTR + n] = bv + (a1.x + a1.y) + (a1.z + a1.w) + xres[(size_t)(m0 + 1) * DTR + n];
    }
    __syncthreads();
    int wid = tid >> 6;
    if (wid < 2)
        wave_ln_row(&ys[wid * DTR], lane, lnw, lnb, out + (size_t)(m0 + wid) * DTR);
}

// ---------------------------------------------------------------- fused FF1+relu+FF2+residual+LN2 (+pred epilogue on last layer)
__global__ __launch_bounds__(256) void k_ffln(const float* __restrict__ xin,
                                              const float* __restrict__ W1, const float* __restrict__ b1,
                                              const float* __restrict__ W2, const float* __restrict__ b2,
                                              const float* __restrict__ lnw, const float* __restrict__ lnb,
                                              float* __restrict__ out, int last,
                                              const float* __restrict__ wty, const float* __restrict__ wti,
                                              const int* __restrict__ lens) {
    int m0 = blockIdx.x * 2;
    int tid = threadIdx.x;  // 256
    __shared__ float xs[2 * DTR];
    __shared__ float hs[2 * NHID2];
    __shared__ float zs[2 * DTR];
    __shared__ float fin[2 * DTR];
    for (int i = tid; i < 2 * DTR; i += 256) xs[i] = xin[(size_t)m0 * DTR + i];
    __syncthreads();
    {
        int n = tid;
        const float* wr = W1 + (size_t)n * DTR;
        float4 a0 = {0.f, 0.f, 0.f, 0.f};
        float4 a1 = {0.f, 0.f, 0.f, 0.f};
#pragma unroll 8
        for (int d = 0; d < DTR; d += 4) {
            float4 w4 = *(const float4*)(wr + d);
            float4 x0 = *(const float4*)&xs[d];
            float4 x1 = *(const float4*)&xs[DTR + d];
            a0.x += x0.x * w4.x; a0.y += x0.y * w4.y; a0.z += x0.z * w4.z; a0.w += x0.w * w4.w;
            a1.x += x1.x * w4.x; a1.y += x1.y * w4.y; a1.z += x1.z * w4.z; a1.w += x1.w * w4.w;
        }
        float bv = b1[n];
        hs[n]         = fmaxf(bv + (a0.x + a0.y) + (a0.z + a0.w), 0.f);
        hs[NHID2 + n] = fmaxf(bv + (a1.x + a1.y) + (a1.z + a1.w), 0.f);
    }
    __syncthreads();
    if (tid < DTR) {
        int n = tid;
        const float* wr = W2 + (size_t)n * NHID2;
        float4 a0 = {0.f, 0.f, 0.f, 0.f};
        float4 a1 = {0.f, 0.f, 0.f, 0.f};
#pragma unroll 8
        for (int d = 0; d < NHID2; d += 4) {
            float4 w4 = *(const float4*)(wr + d);
            float4 h0 = *(const float4*)&hs[d];
            float4 h1v = *(const float4*)&hs[NHID2 + d];
            a0.x += h0.x * w4.x; a0.y += h0.y * w4.y; a0.z += h0.z * w4.z; a0.w += h0.w * w4.w;
            a1.x += h1v.x * w4.x; a1.y += h1v.y * w4.y; a1.z += h1v.z * w4.z; a1.w += h1v.w * w4.w;
        }
        float bv = b2[n];
        zs[n]       = bv + (a0.x + a0.y) + (a0.z + a0.w) + xs[n];
        zs[DTR + n] = bv + (a1.x + a1.y) + (a1.z + a1.w) + xs[DTR + n];
    }
    __syncthreads();
    int wid = tid >> 6, lane = tid & 63;
    if (!last) {
        if (wid < 2)
            wave_ln_row(&zs[wid * DTR], lane, lnw, lnb, out + (size_t)(m0 + wid) * DTR);
        return;
    }
    // last layer: LN into LDS, then write output rows + type/time preds
    if (wid < 2)
        wave_ln_row(&zs[wid * DTR], lane, lnw, lnb, &fin[wid * DTR]);
    __syncthreads();
    for (int i = tid; i < 2 * DTR; i += 256) out[(size_t)m0 * DTR + i] = fin[i];
    int r = tid >> 7, t2 = tid & 127;            // 2 groups of 128; t2<37 -> preds
    int row = m0 + r;
    int b = row / LMAX, l = row - b * LMAX;
    float np = (l < lens[b]) ? 1.f : 0.f;
    if (t2 < 37) {
        const float* w = (t2 < 36) ? (wty + t2 * DTR) : wti;
        const float* fr = &fin[r * DTR];
        float acc = 0.f;
#pragma unroll 8
        for (int d = 0; d < DTR; d += 4) {
            float4 w4 = *(const float4*)(w + d);
            acc += fr[d] * w4.x + fr[d + 1] * w4.y + fr[d + 2] * w4.z + fr[d + 3] * w4.w;
        }
        acc *= np;
        if (t2 < 36) out[OUT_TYPE + (size_t)row * NND + t2] = acc;
        else out[OUT_TIME + row] = acc;
    }
}

// ---------------------------------------------------------------- launch
extern "C" void kernel_launch(void* const* d_in, const int* in_sizes, int n_in,
                              void* d_out, int out_size, void* d_ws, size_t ws_size,
                              hipStream_t stream) {
    const int* et      = (const int*)d_in[0];
    const float* etime = (const float*)d_in[1];
    const float* Ru    = (const float*)d_in[2];
    const float* gs    = (const float*)d_in[3];
    const float* Winc  = (const float*)d_in[4];
    const float* binc  = (const float*)d_in[5];
    const float* mapw  = (const float*)d_in[6];
    const float* wtime = (const float*)d_in[7];
    const float* wtype = (const float*)d_in[8];

    float* ws   = (float*)d_ws;
    float* pe   = ws + OFF_PE;
    float* rr   = ws + OFF_RR;
    float* ew   = ws + OFF_EW;
    float* beta = ws + OFF_BETA;
    float* alpha= ws + OFF_ALPHA;
    float* h1   = ws + OFF_H1;
    float* x    = ws + OFF_X;
    float* x2   = ws + OFF_X2;
    float* qkvb = ws + OFF_QKV;
    float* part = ws + OFF_PART;
    int* topi   = (int*)(ws + OFF_TOPI);
    int* idxarr = (int*)(ws + OFF_IDX);
    int* lens   = (int*)(ws + OFF_LENS);
    int* csrc   = (int*)(ws + OFF_CSRC);
    int* csrl   = (int*)(ws + OFF_CSRL);
    float* outp = (float*)d_out;

    k_prep<<<73, 256, 0, stream>>>(et, etime, Ru, gs, pe, rr, ew, idxarr, lens, csrc, csrl, x);
    k_beta<<<LMAX, 256, 0, stream>>>(Winc, binc, mapw, pe, rr, idxarr, csrc, csrl, beta);
    k_topk<<<dim3(6, NBATCH), 256, 0, stream>>>(ew, beta, topi, alpha);
    k_h1<<<NBATCH * NND, 256, 0, stream>>>(topi, ew, beta, idxarr, rr, alpha, h1, outp + OUT_DIST);
    k_h2<<<NBATCH * NND, 256, 0, stream>>>(topi, alpha, h1, x);

    const int MB2 = NPAIR / 2;  // 860 two-row tiles
    for (int layer = 0; layer < 2; ++layer) {
        int base = 9 + layer * 12;
        const float* qkv_w = (const float*)d_in[base + 0];
        const float* qkv_b = (const float*)d_in[base + 1];
        const float* out_w = (const float*)d_in[base + 2];
        const float* out_b = (const float*)d_in[base + 3];
        const float* ff1_w = (const float*)d_in[base + 4];
        const float* ff1_b = (const float*)d_in[base + 5];
        const float* ff2_w = (const float*)d_in[base + 6];
        const float* ff2_b = (const float*)d_in[base + 7];
        const float* ln1_w = (const float*)d_in[base + 8];
        const float* ln1_b = (const float*)d_in[base + 9];
        const float* ln2_w = (const float*)d_in[base + 10];
        const float* ln2_b = (const float*)d_in[base + 11];

        k_qkv<<<MB2, 256, 0, stream>>>(x, qkv_w, qkv_b, qkvb);
        k_attn_part<<<dim3(KSPLIT, NBATCH * NHEADS), 256, 0, stream>>>(qkvb, lens, part);
        k_projln<<<MB2, 256, 0, stream>>>(part, x, out_w, out_b, ln1_w, ln1_b, x2);
        if (layer == 0)
            k_ffln<<<MB2, 256, 0, stream>>>(x2, ff1_w, ff1_b, ff2_w, ff2_b, ln2_w, ln2_b,
                                            x, 0, wtype, wtime, lens);
        else
            k_ffln<<<MB2, 256, 0, stream>>>(x2, ff1_w, ff1_b, ff2_w, ff2_b, ln2_w, ln2_b,
                                            outp, 1, wtype, wtime, lens);
    }
}

// Round 11
// 419.263 us; speedup vs baseline: 3.2682x; 1.2156x over previous
//
#include <hip/hip_runtime.h>
#include <math.h>

#define NBATCH 8
#define LMAX   215
#define NND    36
#define NE     1296
#define NK     648
#define CW     860      // C = LMAX*4
#define DPE    16
#define DTR    160
#define NHEADS 4
#define DH     40
#define NHID2  256
#define NPAIR  (NBATCH*LMAX)   // 1720
#define KSPLIT 8
#define KQLEN  27              // ceil(215/8)
#define ROWS   4               // rows per GEMM block

// output layout (floats)
#define OUT_TYPE (NBATCH*LMAX*DTR)              // 275200
#define OUT_TIME (OUT_TYPE + NBATCH*LMAX*NND)   // 337120
#define OUT_DIST (OUT_TIME + NBATCH*LMAX)       // 338840

// workspace layout (float offsets)
#define OFF_PE    0
#define OFF_RR    (OFF_PE + NBATCH*LMAX*DPE)
#define OFF_EW    (OFF_RR + 144)
#define OFF_BETA  (OFF_EW + NE)
#define OFF_ALPHA (OFF_BETA + NBATCH*NND*LMAX)
#define OFF_H1    (OFF_ALPHA + NBATCH*NK)
#define OFF_X     (OFF_H1 + NBATCH*NND*CW)
#define OFF_X2    (OFF_X + NBATCH*LMAX*DTR)
#define OFF_QKV   (OFF_X2 + NBATCH*LMAX*DTR)
#define OFF_TOPI  (OFF_QKV + NBATCH*LMAX*480)
#define OFF_IDX   (OFF_TOPI + NBATCH*NK)
#define OFF_LENS  (OFF_IDX + NBATCH*LMAX)
#define OFF_PART  (OFF_LENS + NBATCH)
#define OFF_CSRC  (OFF_PART + 32*KSPLIT*LMAX*42)
#define OFF_CSRL  (OFF_CSRC + NBATCH*NND)
#define OFF_WT    (OFF_CSRL + NBATCH*NND*LMAX)
// per layer: qkvT[160][480] @0, outT[160][160] @76800, ff1T[160][256] @102400, ff2T[256][160] @143360 ; stride 184320

// ---------------------------------------------------------------- weight transpose (once)
__global__ __launch_bounds__(256) void k_wt(
        const float* __restrict__ q0, const float* __restrict__ o0,
        const float* __restrict__ f10, const float* __restrict__ f20,
        const float* __restrict__ q1, const float* __restrict__ o1,
        const float* __restrict__ f11, const float* __restrict__ f21,
        float* __restrict__ wt) {
    int mat = blockIdx.y;
    const float* src; float* dst; int R, C;
    switch (mat) {
        case 0: src = q0;  dst = wt + 0;               R = 480; C = DTR;   break;
        case 1: src = o0;  dst = wt + 76800;           R = DTR; C = DTR;   break;
        case 2: src = f10; dst = wt + 102400;          R = NHID2; C = DTR; break;
        case 3: src = f20; dst = wt + 143360;          R = DTR; C = NHID2; break;
        case 4: src = q1;  dst = wt + 184320;          R = 480; C = DTR;   break;
        case 5: src = o1;  dst = wt + 184320 + 76800;  R = DTR; C = DTR;   break;
        case 6: src = f11; dst = wt + 184320 + 102400; R = NHID2; C = DTR; break;
        default: src = f21; dst = wt + 184320 + 143360; R = DTR; C = NHID2; break;
    }
    int total = R * C;
    for (int i = blockIdx.x * 256 + threadIdx.x; i < total; i += gridDim.x * 256) {
        int r = i / C, c = i - r * C;
        dst[c * R + r] = src[i];
    }
}

// ---------------------------------------------------------------- prep (parallel: 73 blocks)
__global__ __launch_bounds__(256) void k_prep(
        const int* __restrict__ et, const float* __restrict__ etime,
        const float* __restrict__ Ru, const float* __restrict__ gs,
        float* pe, float* rr, float* ew, int* idxarr, int* lens,
        int* csr_cnt, int* csr_list, float* __restrict__ x) {
    int blk = blockIdx.x, tid = threadIdx.x;
    if (blk == 0) {
        for (int c = tid; c < 144; c += 256) rr[c] = fmaxf(Ru[c], 0.f);
        for (int e = tid; e < NE; e += 256) {
            int r = e / NND, cc = e % NND;
            ew[e] = (r == cc) ? 1.0f : gs[e];
        }
    } else if (blk <= 8) {
        int b = blk - 1;
        __shared__ int red[256];
        __shared__ int sidx[LMAX];
        int cnt = 0;
        for (int l = tid; l < LMAX; l += 256) {
            int v = et[b * LMAX + l];
            cnt += (v != 0);
            int ix = max(v - 1, 0);
            idxarr[b * LMAX + l] = ix;
            sidx[l] = ix;
        }
        red[tid] = cnt;
        __syncthreads();
        for (int st = 128; st > 0; st >>= 1) { if (tid < st) red[tid] += red[tid + st]; __syncthreads(); }
        if (tid == 0) lens[b] = red[0];
        if (tid < NND) {
            int c = 0;
            int* lst = csr_list + (size_t)(b * NND + tid) * LMAX;
            for (int l = 0; l < LMAX; ++l)
                if (sidx[l] == tid) { lst[c] = l; ++c; }
            csr_cnt[b * NND + tid] = c;
        }
    } else {
        __shared__ float sts[8];
        if (tid < 8) sts[tid] = (float)pow(215.0, (double)tid / 7.0);
        __syncthreads();
        int i0 = (blk - 9) * 430;
        for (int i = i0 + tid; i < i0 + 430; i += 256) {
            int s = i & 15; int bl = i >> 4;
            float t = etime[bl];
            float sc = t / sts[s & 7];
            float v = (s < 8) ? sinf(sc) : cosf(sc);
            pe[i] = v;
            x[(size_t)bl * DTR + 144 + s] = v;
        }
    }
}

// ---------------------------------------------------------------- beta (thread-owns-l, b-loop in regs, CSR reduce)
__global__ __launch_bounds__(256) void k_beta(
        const float* __restrict__ Winc, const float* __restrict__ binc,
        const float* __restrict__ mapw, const float* __restrict__ pe,
        const float* __restrict__ rr, const int* __restrict__ idxarr,
        const int* __restrict__ csr_cnt, const int* __restrict__ csr_list,
        float* __restrict__ beta) {
    const int t = blockIdx.x;        // 0..214
    const int tid = threadIdx.x;     // 256

    __shared__ float s_rows[2][4 * CW];
    __shared__ float s_pair[NBATCH * LMAX];
    __shared__ int   s_idx[NPAIR];
    __shared__ float s_mapw[NND * 16];
    __shared__ float s_rr[144];
    __shared__ float s_pe[NBATCH * 16];
    __shared__ float s_binc[32];

    for (int i = tid; i < NPAIR; i += 256) s_idx[i] = idxarr[i];
    for (int i = tid; i < NND * 16; i += 256) s_mapw[i] = mapw[i];
    if (tid < 144) s_rr[tid] = rr[tid];
    if (tid < 128) { int b = tid >> 4, s = tid & 15; s_pe[tid] = pe[((size_t)(b * LMAX + t)) * DPE + s]; }
    if (tid < 32) s_binc[tid] = binc[32 * t + tid];

    float4 pre[4];
    {
        const float4* src = (const float4*)(Winc + (size_t)(32 * t) * CW);
#pragma unroll
        for (int i = 0; i < 4; ++i) { int k = tid + i * 256; if (k < CW) pre[i] = src[k]; }
    }
    __syncthreads();

    const int l = tid;
    int nb[NBATCH];
    float4 r4b[NBATCH];
    if (l < LMAX) {
#pragma unroll
        for (int b = 0; b < NBATCH; ++b) {
            nb[b] = s_idx[b * LMAX + l];
            r4b[b] = *(const float4*)&s_rr[4 * nb[b]];
        }
    }
    float acc[NBATCH];
#pragma unroll
    for (int b = 0; b < NBATCH; ++b) acc[b] = 0.f;

    int p = 0;
    for (int jc = 0; jc < 8; ++jc) {
        float4* buf = (float4*)&s_rows[p][0];
#pragma unroll
        for (int i = 0; i < 4; ++i) { int k = tid + i * 256; if (k < CW) buf[k] = pre[i]; }
        __syncthreads();
        if (jc < 7) {
            const float4* src = (const float4*)(Winc + (size_t)(32 * t + 4 * (jc + 1)) * CW);
#pragma unroll
            for (int i = 0; i < 4; ++i) { int k = tid + i * 256; if (k < CW) pre[i] = src[k]; }
        }
        if (l < LMAX) {
            if (jc < 4) {
#pragma unroll
                for (int jj = 0; jj < 4; ++jj) {
                    int j = 4 * jc + jj;
                    float4 w4 = *(const float4*)&s_rows[p][jj * CW + 4 * l];
#pragma unroll
                    for (int b = 0; b < NBATCH; ++b) {
                        float dv = r4b[b].x * w4.x + r4b[b].y * w4.y + r4b[b].z * w4.z + r4b[b].w * w4.w;
                        acc[b] += s_mapw[nb[b] * 16 + j] * dv;
                    }
                }
            } else {
#pragma unroll
                for (int jj = 0; jj < 4; ++jj) {
                    int j = 4 * jc + jj;
                    float4 w4 = *(const float4*)&s_rows[p][jj * CW + 4 * l];
#pragma unroll
                    for (int b = 0; b < NBATCH; ++b) {
                        float dv = r4b[b].x * w4.x + r4b[b].y * w4.y + r4b[b].z * w4.z + r4b[b].w * w4.w;
                        acc[b] += s_pe[(b << 4) + (j - 16)] * dv;
                    }
                }
            }
        }
        __syncthreads();
        p ^= 1;
    }

    if (l < LMAX) {
#pragma unroll
        for (int b = 0; b < NBATCH; ++b) s_pair[b * LMAX + l] = acc[b];
    }
    __syncthreads();

    for (int bn = tid; bn < NBATCH * NND; bn += 256) {
        int b = bn / NND, n = bn - b * NND;
        int cnt = csr_cnt[bn];
        const int* lst = csr_list + (size_t)bn * LMAX;
        float sum = 0.f;
        for (int i = 0; i < cnt; ++i) sum += s_pair[b * LMAX + lst[i]];
        float bias = 0.f;
#pragma unroll
        for (int s = 0; s < 16; ++s)
            bias += s_mapw[n * 16 + s] * s_binc[s] + s_pe[(b << 4) + s] * s_binc[16 + s];
        beta[(size_t)bn * LMAX + t] = (sum + bias) * (1.0f / 32.0f);
    }
}

// ---------------------------------------------------------------- top-K with fused meanb (bitwise-identical reduce)
__global__ __launch_bounds__(256) void k_topk(const float* __restrict__ ew,
                                              const float* __restrict__ beta,
                                              int* __restrict__ topi, float* __restrict__ alpha) {
    int chunk = blockIdx.x;    // 0..5
    int b = blockIdx.y;        // 0..7
    int tid = threadIdx.x;     // 256
    __shared__ float sv[NE];
    __shared__ float sm[NND];
    int wv = tid >> 6, lane = tid & 63;
    for (int n = wv; n < NND; n += 4) {
        const float* p = beta + (size_t)(b * NND + n) * LMAX;
        float s = 0.f;
        for (int t = lane; t < LMAX; t += 64) s += p[t];
        for (int off = 32; off > 0; off >>= 1) s += __shfl_xor(s, off);
        if (lane == 0) sm[n] = s / (float)LMAX;
    }
    __syncthreads();
    for (int e = tid; e < NE; e += 256) sv[e] = ew[e] * sm[e % NND];
    __syncthreads();
    int e = chunk * 216 + tid;
    if (tid < 216) {
        float v = sv[e];
        int rank = 0;
        for (int i = 0; i < NE; ++i) {
            float u = sv[i];
            rank += (u > v) || (u == v && i < e);
        }
        if (rank < NK) {
            topi[b * NK + rank] = e;
            alpha[b * NK + rank] = v;
        }
    }
}

// ---------------------------------------------------------------- message passing layer 1 (+ fused distance in block 0)
__global__ void k_h1(const int* __restrict__ topi, const float* __restrict__ ew,
                     const float* __restrict__ beta, const int* __restrict__ idxarr,
                     const float* __restrict__ rr, const float* __restrict__ alpha,
                     float* h1, float* __restrict__ outd) {
    int b = blockIdx.x / NND, n = blockIdx.x % NND;
    __shared__ int cnt;
    __shared__ int lsrc[40];
    __shared__ float lew[40];
    int tid = threadIdx.x;
    if (tid == 0) cnt = 0;
    __syncthreads();
    for (int k = tid; k < NK; k += 256) {
        int e = topi[b * NK + k];
        if (e % NND == n) {
            int p = atomicAdd(&cnt, 1);
            lsrc[p] = e / NND;
            lew[p] = ew[e];
        }
    }
    __syncthreads();
    int m = cnt;
    const float* bb = beta + ((size_t)b * NND + n) * LMAX;
    for (int c = tid; c < CW; c += 256) {
        int t = c >> 2, o = c & 3;
        float bt = bb[t];
        int id = idxarr[b * LMAX + t];
        float x = rr[id * 4 + o];
        float acc = 0.f;
        for (int j = 0; j < m; ++j) {
            float g = bt * lew[j];
            if (g > 0.f && lsrc[j] == id) acc += x * g;
        }
        h1[((size_t)b * NND + n) * CW + c] = acc;
    }
    if (blockIdx.x == 0) {
        __shared__ float sd[64];
        if (tid < 64) {
            int i = tid / 8, j = tid % 8;
            float d2 = 0.f;
            for (int k = 0; k < NK; ++k) {
                float d = alpha[i * NK + k] - alpha[j * NK + k];
                d2 += d * d;
            }
            sd[tid] = (d2 > 0.f) ? sqrtf(d2) : 0.f;
        }
        __syncthreads();
        for (int st = 32; st > 0; st >>= 1) { if (tid < st) sd[tid] += sd[tid + st]; __syncthreads(); }
        if (tid == 0) *outd = sd[0] / 64.0f;
    }
}

// ---------------------------------------------------------------- message passing layer 2 -> writes x directly
__global__ void k_h2(const int* __restrict__ topi, const float* __restrict__ alpha,
                     const float* __restrict__ h1, float* __restrict__ x) {
    int b = blockIdx.x / NND, n = blockIdx.x % NND;
    __shared__ int cnt;
    __shared__ int lsrc[40];
    __shared__ float lal[40];
    int tid = threadIdx.x;
    if (tid == 0) cnt = 0;
    __syncthreads();
    for (int k = tid; k < NK; k += 256) {
        int e = topi[b * NK + k];
        if (e % NND == n) {
            int p = atomicAdd(&cnt, 1);
            lsrc[p] = e / NND;
            lal[p] = fmaxf(alpha[b * NK + k], 0.f);
        }
    }
    __syncthreads();
    int m = cnt;
    for (int c = tid; c < CW; c += 256) {
        float acc = 0.f;
        for (int j = 0; j < m; ++j)
            acc += fmaxf(h1[((size_t)b * NND + lsrc[j]) * CW + c], 0.f) * lal[j];
        x[(size_t)(b * LMAX + (c >> 2)) * DTR + 4 * n + (c & 3)] = acc;
    }
}

// ---------------------------------------------------------------- qkv GEMM: 4 rows/block, transposed W, coalesced
__global__ __launch_bounds__(256) void k_qkv(const float* __restrict__ X, const float* __restrict__ WT,
                                             const float* __restrict__ bias, float* __restrict__ Y) {
    int m0 = blockIdx.x * ROWS;
    int tid = threadIdx.x;
    __shared__ float xs[ROWS * DTR];
    for (int i = tid; i < ROWS * DTR; i += 256) xs[i] = X[(size_t)m0 * DTR + i];
    __syncthreads();
    for (int n = tid; n < 480; n += 256) {
        float a[ROWS][4];
#pragma unroll
        for (int r = 0; r < ROWS; ++r) { a[r][0] = a[r][1] = a[r][2] = a[r][3] = 0.f; }
        for (int d = 0; d < DTR; d += 4) {
            float w0 = WT[(size_t)(d + 0) * 480 + n];
            float w1 = WT[(size_t)(d + 1) * 480 + n];
            float w2 = WT[(size_t)(d + 2) * 480 + n];
            float w3 = WT[(size_t)(d + 3) * 480 + n];
#pragma unroll
            for (int r = 0; r < ROWS; ++r) {
                a[r][0] += xs[r * DTR + d] * w0;
                a[r][1] += xs[r * DTR + d + 1] * w1;
                a[r][2] += xs[r * DTR + d + 2] * w2;
                a[r][3] += xs[r * DTR + d + 3] * w3;
            }
        }
        float bv = bias[n];
#pragma unroll
        for (int r = 0; r < ROWS; ++r)
            Y[(size_t)(m0 + r) * 480 + n] = bv + (a[r][0] + a[r][1]) + (a[r][2] + a[r][3]);
    }
}

// ---------------------------------------------------------------- attention partials (flash 8-way k-split)
__global__ __launch_bounds__(256) void k_attn_part(const float* __restrict__ qkv,
                                                   const int* __restrict__ lens,
                                                   float* __restrict__ part) {
    int kq = blockIdx.x;           // 0..7
    int bh = blockIdx.y;           // 0..31
    int b = bh >> 2, h = bh & 3;
    int tid = threadIdx.x;
    int k0 = kq * KQLEN;
    int k1 = min(LMAX, k0 + KQLEN);
    int klen = max(k1 - k0, 0);
    __shared__ float sK[KQLEN * DH];
    __shared__ float sV[KQLEN * DH];
    for (int i = tid; i < klen * DH; i += 256) {
        int kk = i / DH, d = i - kk * DH;
        size_t base = (size_t)(b * LMAX + k0 + kk) * 480;
        sK[i] = qkv[base + DTR + h * DH + d];
        sV[i] = qkv[base + 2 * DTR + h * DH + d];
    }
    __syncthreads();
    int q = tid;
    if (q >= LMAX) return;
    float4 qv[10];
    const float4* qr = (const float4*)(qkv + (size_t)(b * LMAX + q) * 480 + h * DH);
#pragma unroll
    for (int i = 0; i < 10; ++i) qv[i] = qr[i];
    int len = lens[b];
    const float scale = 0.15811388300841898f;
    float m = -INFINITY, l = 0.f;
    float o[DH];
#pragma unroll
    for (int d = 0; d < DH; ++d) o[d] = 0.f;
    int kend = min(k1, len);
    for (int k = k0; k < kend; ++k) {
        const float4* kr = (const float4*)&sK[(k - k0) * DH];
        float s0 = 0.f, s1 = 0.f, s2 = 0.f, s3 = 0.f;
#pragma unroll
        for (int i = 0; i < 10; ++i) {
            float4 kv = kr[i];
            s0 += qv[i].x * kv.x; s1 += qv[i].y * kv.y;
            s2 += qv[i].z * kv.z; s3 += qv[i].w * kv.w;
        }
        float s = ((s0 + s1) + (s2 + s3)) * scale;
        float p;
        if (s <= m) {
            p = expf(s - m);
        } else {
            float c = expf(m - s);
#pragma unroll
            for (int d = 0; d < DH; ++d) o[d] *= c;
            l *= c;
            m = s;
            p = 1.0f;
        }
        l += p;
        const float* vr = &sV[(k - k0) * DH];
#pragma unroll
        for (int d = 0; d < DH; ++d) o[d] += p * vr[d];
    }
    float* pp = part + ((size_t)(bh * KSPLIT + kq) * LMAX + q) * 42;
#pragma unroll
    for (int d = 0; d < DH; ++d) pp[d] = o[d];
    pp[40] = l;
    pp[41] = m;
}

// ---------------------------------------------------------------- device LN helper
__device__ __forceinline__ void wave_ln_row(const float* __restrict__ row, int lane,
                                            const float* __restrict__ lnw, const float* __restrict__ lnb,
                                            float* __restrict__ dst) {
    float s = 0.f;
    for (int d = lane; d < DTR; d += 64) s += row[d];
    for (int off = 32; off > 0; off >>= 1) s += __shfl_xor(s, off);
    float mu = s / (float)DTR;
    float v = 0.f;
    for (int d = lane; d < DTR; d += 64) { float dd = row[d] - mu; v += dd * dd; }
    for (int off = 32; off > 0; off >>= 1) v += __shfl_xor(v, off);
    float rs = rsqrtf(v / (float)DTR + 1e-5f);
    for (int d = lane; d < DTR; d += 64)
        dst[d] = (row[d] - mu) * rs * lnw[d] + lnb[d];
}

// ---------------------------------------------------------------- fused merge + out-proj + residual + LN1 (4 rows)
__global__ __launch_bounds__(256) void k_projln(const float* __restrict__ part, const float* __restrict__ xres,
                                                const float* __restrict__ WT, const float* __restrict__ bias,
                                                const float* __restrict__ lnw, const float* __restrict__ lnb,
                                                float* __restrict__ out) {
    int m0 = blockIdx.x * ROWS;
    int tid = threadIdx.x;
    __shared__ float xs[ROWS * DTR];
    __shared__ float ys[ROWS * DTR];
    int g = tid >> 6, lane = tid & 63;
    for (int pr = g; pr < ROWS * NHEADS; pr += 4) {   // merge partials -> ctx rows in LDS
        int r = pr >> 2, h = pr & 3;
        int row = m0 + r;
        int b = row / LMAX, q = row - b * LMAX;
        const float* pb = part + ((size_t)((b * NHEADS + h) * KSPLIT) * LMAX + q) * 42;
        const size_t st = (size_t)LMAX * 42;
        float ms = -INFINITY;
#pragma unroll
        for (int i = 0; i < KSPLIT; ++i) ms = fmaxf(ms, pb[i * st + 41]);
        float lsum = 0.f, acc = 0.f;
#pragma unroll
        for (int i = 0; i < KSPLIT; ++i) {
            float w = expf(pb[i * st + 41] - ms);
            lsum += w * pb[i * st + 40];
            if (lane < DH) acc += w * pb[i * st + lane];
        }
        if (lane < DH) xs[r * DTR + h * DH + lane] = acc / lsum;
    }
    __syncthreads();
    if (tid < DTR) {
        int n = tid;
        float a[ROWS][4];
#pragma unroll
        for (int r = 0; r < ROWS; ++r) { a[r][0] = a[r][1] = a[r][2] = a[r][3] = 0.f; }
        for (int d = 0; d < DTR; d += 4) {
            float w0 = WT[(size_t)(d + 0) * DTR + n];
            float w1 = WT[(size_t)(d + 1) * DTR + n];
            float w2 = WT[(size_t)(d + 2) * DTR + n];
            float w3 = WT[(size_t)(d + 3) * DTR + n];
#pragma unroll
            for (int r = 0; r < ROWS; ++r) {
                a[r][0] += xs[r * DTR + d] * w0;
                a[r][1] += xs[r * DTR + d + 1] * w1;
                a[r][2] += xs[r * DTR + d + 2] * w2;
                a[r][3] += xs[r * DTR + d + 3] * w3;
            }
        }
        float bv = bias[n];
#pragma unroll
        for (int r = 0; r < ROWS; ++r)
            ys[r * DTR + n] = bv + (a[r][0] + a[r][1]) + (a[r][2] + a[r][3])
                              + xres[(size_t)(m0 + r) * DTR + n];
    }
    __syncthreads();
    if (g < ROWS)
        wave_ln_row(&ys[g * DTR], lane, lnw, lnb, out + (size_t)(m0 + g) * DTR);
}

// ---------------------------------------------------------------- fused FF1+relu+FF2+residual+LN2 (+pred epilogue)
__global__ __launch_bounds__(256) void k_ffln(const float* __restrict__ xin,
                                              const float* __restrict__ W1T, const float* __restrict__ b1,
                                              const float* __restrict__ W2T, const float* __restrict__ b2,
                                              const float* __restrict__ lnw, const float* __restrict__ lnb,
                                              float* __restrict__ out, int last,
                                              const float* __restrict__ wty, const float* __restrict__ wti,
                                              const int* __restrict__ lens) {
    int m0 = blockIdx.x * ROWS;
    int tid = threadIdx.x;
    __shared__ float xs[ROWS * DTR];
    __shared__ float hs[ROWS * NHID2];
    __shared__ float zs[ROWS * DTR];
    __shared__ float fin[ROWS * DTR];
    for (int i = tid; i < ROWS * DTR; i += 256) xs[i] = xin[(size_t)m0 * DTR + i];
    __syncthreads();
    {
        int n = tid;   // all 256 active
        float a[ROWS][4];
#pragma unroll
        for (int r = 0; r < ROWS; ++r) { a[r][0] = a[r][1] = a[r][2] = a[r][3] = 0.f; }
        for (int d = 0; d < DTR; d += 4) {
            float w0 = W1T[(size_t)(d + 0) * NHID2 + n];
            float w1 = W1T[(size_t)(d + 1) * NHID2 + n];
            float w2 = W1T[(size_t)(d + 2) * NHID2 + n];
            float w3 = W1T[(size_t)(d + 3) * NHID2 + n];
#pragma unroll
            for (int r = 0; r < ROWS; ++r) {
                a[r][0] += xs[r * DTR + d] * w0;
                a[r][1] += xs[r * DTR + d + 1] * w1;
                a[r][2] += xs[r * DTR + d + 2] * w2;
                a[r][3] += xs[r * DTR + d + 3] * w3;
            }
        }
        float bv = b1[n];
#pragma unroll
        for (int r = 0; r < ROWS; ++r)
            hs[r * NHID2 + n] = fmaxf(bv + (a[r][0] + a[r][1]) + (a[r][2] + a[r][3]), 0.f);
    }
    __syncthreads();
    if (tid < DTR) {
        int n = tid;
        float a[ROWS][4];
#pragma unroll
        for (int r = 0; r < ROWS; ++r) { a[r][0] = a[r][1] = a[r][2] = a[r][3] = 0.f; }
        for (int d = 0; d < NHID2; d += 4) {
            float w0 = W2T[(size_t)(d + 0) * DTR + n];
            float w1 = W2T[(size_t)(d + 1) * DTR + n];
            float w2 = W2T[(size_t)(d + 2) * DTR + n];
            float w3 = W2T[(size_t)(d + 3) * DTR + n];
#pragma unroll
            for (int r = 0; r < ROWS; ++r) {
                a[r][0] += hs[r * NHID2 + d] * w0;
                a[r][1] += hs[r * NHID2 + d + 1] * w1;
                a[r][2] += hs[r * NHID2 + d + 2] * w2;
                a[r][3] += hs[r * NHID2 + d + 3] * w3;
            }
        }
        float bv = b2[n];
#pragma unroll
        for (int r = 0; r < ROWS; ++r)
            zs[r * DTR + n] = bv + (a[r][0] + a[r][1]) + (a[r][2] + a[r][3]) + xs[r * DTR + n];
    }
    __syncthreads();
    int wid = tid >> 6, lane = tid & 63;
    if (!last) {
        if (wid < ROWS)
            wave_ln_row(&zs[wid * DTR], lane, lnw, lnb, out + (size_t)(m0 + wid) * DTR);
        return;
    }
    if (wid < ROWS)
        wave_ln_row(&zs[wid * DTR], lane, lnw, lnb, &fin[wid * DTR]);
    __syncthreads();
    for (int i = tid; i < ROWS * DTR; i += 256) out[(size_t)m0 * DTR + i] = fin[i];
    {   // preds: wave wid handles row wid; lanes 0..36 compute 36 type + 1 time outputs
        int row = m0 + wid;
        int b = row / LMAX, l = row - b * LMAX;
        float np = (l < lens[b]) ? 1.f : 0.f;
        if (lane < 37) {
            const float* w = (lane < 36) ? (wty + lane * DTR) : wti;
            const float* fr = &fin[wid * DTR];
            float acc = 0.f;
#pragma unroll 8
            for (int d = 0; d < DTR; d += 4) {
                float4 w4 = *(const float4*)(w + d);
                acc += fr[d] * w4.x + fr[d + 1] * w4.y + fr[d + 2] * w4.z + fr[d + 3] * w4.w;
            }
            acc *= np;
            if (lane < 36) out[OUT_TYPE + (size_t)row * NND + lane] = acc;
            else out[OUT_TIME + row] = acc;
        }
    }
}

// ---------------------------------------------------------------- launch
extern "C" void kernel_launch(void* const* d_in, const int* in_sizes, int n_in,
                              void* d_out, int out_size, void* d_ws, size_t ws_size,
                              hipStream_t stream) {
    const int* et      = (const int*)d_in[0];
    const float* etime = (const float*)d_in[1];
    const float* Ru    = (const float*)d_in[2];
    const float* gs    = (const float*)d_in[3];
    const float* Winc  = (const float*)d_in[4];
    const float* binc  = (const float*)d_in[5];
    const float* mapw  = (const float*)d_in[6];
    const float* wtime = (const float*)d_in[7];
    const float* wtype = (const float*)d_in[8];

    float* ws   = (float*)d_ws;
    float* pe   = ws + OFF_PE;
    float* rr   = ws + OFF_RR;
    float* ew   = ws + OFF_EW;
    float* beta = ws + OFF_BETA;
    float* alpha= ws + OFF_ALPHA;
    float* h1   = ws + OFF_H1;
    float* x    = ws + OFF_X;
    float* x2   = ws + OFF_X2;
    float* qkvb = ws + OFF_QKV;
    float* part = ws + OFF_PART;
    float* wt   = ws + OFF_WT;
    int* topi   = (int*)(ws + OFF_TOPI);
    int* idxarr = (int*)(ws + OFF_IDX);
    int* lens   = (int*)(ws + OFF_LENS);
    int* csrc   = (int*)(ws + OFF_CSRC);
    int* csrl   = (int*)(ws + OFF_CSRL);
    float* outp = (float*)d_out;

    k_wt<<<dim3(32, 8), 256, 0, stream>>>(
        (const float*)d_in[9],  (const float*)d_in[11], (const float*)d_in[13], (const float*)d_in[15],
        (const float*)d_in[21], (const float*)d_in[23], (const float*)d_in[25], (const float*)d_in[27], wt);
    k_prep<<<73, 256, 0, stream>>>(et, etime, Ru, gs, pe, rr, ew, idxarr, lens, csrc, csrl, x);
    k_beta<<<LMAX, 256, 0, stream>>>(Winc, binc, mapw, pe, rr, idxarr, csrc, csrl, beta);
    k_topk<<<dim3(6, NBATCH), 256, 0, stream>>>(ew, beta, topi, alpha);
    k_h1<<<NBATCH * NND, 256, 0, stream>>>(topi, ew, beta, idxarr, rr, alpha, h1, outp + OUT_DIST);
    k_h2<<<NBATCH * NND, 256, 0, stream>>>(topi, alpha, h1, x);

    const int MB4 = NPAIR / ROWS;  // 430 four-row tiles
    for (int layer = 0; layer < 2; ++layer) {
        int base = 9 + layer * 12;
        const float* qkv_b = (const float*)d_in[base + 1];
        const float* out_b = (const float*)d_in[base + 3];
        const float* ff1_b = (const float*)d_in[base + 5];
        const float* ff2_b = (const float*)d_in[base + 7];
        const float* ln1_w = (const float*)d_in[base + 8];
        const float* ln1_b = (const float*)d_in[base + 9];
        const float* ln2_w = (const float*)d_in[base + 10];
        const float* ln2_b = (const float*)d_in[base + 11];
        const float* qkvT = wt + (size_t)layer * 184320;
        const float* outT = qkvT + 76800;
        const float* ff1T = qkvT + 102400;
        const float* ff2T = qkvT + 143360;

        k_qkv<<<MB4, 256, 0, stream>>>(x, qkvT, qkv_b, qkvb);
        k_attn_part<<<dim3(KSPLIT, NBATCH * NHEADS), 256, 0, stream>>>(qkvb, lens, part);
        k_projln<<<MB4, 256, 0, stream>>>(part, x, outT, out_b, ln1_w, ln1_b, x2);
        if (layer == 0)
            k_ffln<<<MB4, 256, 0, stream>>>(x2, ff1T, ff1_b, ff2T, ff2_b, ln2_w, ln2_b,
                                            x, 0, wtype, wtime, lens);
        else
            k_ffln<<<MB4, 256, 0, stream>>>(x2, ff1T, ff1_b, ff2T, ff2_b, ln2_w, ln2_b,
                                            outp, 1, wtype, wtime, lens);
    }
}